// Round 5
// baseline (285.225 us; speedup 1.0000x reference)
//
#include <hip/hip_runtime.h>
#include <math.h>

#define B_    2
#define L_    2048
#define D_    768
#define K_    12
#define KQ_   6
#define M_    4
#define H_    64
#define ZC_   780      // MEM + K
#define NTOK_ 4096     // B*L
#define NC_   64       // scan chunks per batch
#define LC_   32       // chunk length (L/NC)
#define QST_  3072     // q fp16 row stride
#define XPN_  4096     // merged projection N (exactly 16 x 256 tiles -> no grid tail)
#define ZOFF_ 3276     // z_pre column base in xpb

typedef __attribute__((ext_vector_type(8))) _Float16 half8;
typedef __attribute__((ext_vector_type(4))) float f32x4;

__device__ __forceinline__ float softplus_f(float x) {
  return (x > 20.f) ? x : log1pf(expf(x));
}

__device__ __forceinline__ float fast_tanh(float x) {
  float xx = fminf(fmaxf(x, -10.f), 10.f);
  float e = __expf(2.f * xx);
  return (e - 1.f) / (e + 1.f);
}

// async global->LDS 16B per lane (dest = wave-uniform base + lane*16)
__device__ __forceinline__ void async16(const _Float16* g, _Float16* l) {
  __builtin_amdgcn_global_load_lds(
      (const __attribute__((address_space(1))) unsigned int*)g,
      (__attribute__((address_space(3))) unsigned int*)l, 16, 0, 0);
}

// val/gate 16-interleave permutation for spec-B columns
__device__ __forceinline__ int permcol(int n) {
  int isg = (n >= 192) ? 1 : 0;
  int j = n - 192 * isg;
  return (j >> 4) * 32 + (isg << 4) + (j & 15);
}

#define FENCE() asm volatile("" ::: "memory")

// ---------------------------------------------------------------------------
// Transpose+convert body; optional perm + scale. Nst = store-row limit.
// ---------------------------------------------------------------------------
__device__ __forceinline__ void cvt_t_body(float (*tile)[33], int bx, int by, int kz,
                                           const float* src, long sKs, int srs,
                                           _Float16* dh, long dKs, int dst, int doff,
                                           int R, int Nact, int Nst, bool perm, float scale) {
  const float* s = src + (size_t)kz * sKs;
  _Float16* dhh = dh + (size_t)kz * dKs;
  const int kb = bx * 32;
  const int nb = by * 32;
  const int tx = threadIdx.x & 31, ty = threadIdx.x >> 5;
  for (int i = ty; i < 32; i += 8) {
    int kk = kb + i, n = nb + tx;
    tile[i][tx] = (kk < R && n < Nact) ? s[(size_t)kk * srs + n] : 0.f;
  }
  __syncthreads();
  for (int i = ty; i < 32; i += 8) {
    int n = nb + i, kk = kb + tx;
    if (kk < R && n < Nst) {
      float v = tile[tx][i] * scale;
      int dn = perm ? permcol(n) : n;
      dhh[(size_t)dn * dst + doff + kk] = (_Float16)v;
    }
  }
}

// ---------------------------------------------------------------------------
// Fused prologue, ONE dispatch:
//   blocks [0,3):          precomp (theta/w tables, slopes)
//   blocks [3,6363):       all weight conversions (incl. gate_W -> xpb cols)
//   blocks [6363,18651):   x f32->fp16
// xpb layout (rows x 768): [W_q^T 0:3072 | skd^T 3072:3264 | gate^T 3264:3276 |
//                           W_mem^T 3276:4056 | dead 4056:4096]
// ---------------------------------------------------------------------------
__global__ __launch_bounds__(256)
void prep_kernel(const float* __restrict__ x,
                 const float* __restrict__ W_mem, const float* __restrict__ W_q,
                 const float* __restrict__ skip_down_W, const float* __restrict__ out_W,
                 const float* __restrict__ W_re, const float* __restrict__ W_im,
                 const float* __restrict__ skip_up_W, const float* __restrict__ hs,
                 const float* __restrict__ gate_W,
                 const float* __restrict__ theta_d_raw, const float* __restrict__ decay,
                 _Float16* __restrict__ x_h,
                 _Float16* __restrict__ xpb_h, _Float16* __restrict__ outw_h,
                 _Float16* __restrict__ bsp_h,
                 float* __restrict__ theta_tab, float* __restrict__ w_tab,
                 float* __restrict__ slopes_sp) {
  __shared__ float tile[32][33];
  int b = blockIdx.x;
  if (b < 3) {
    int idx = b * 256 + threadIdx.x;
    if (idx < K_) slopes_sp[idx] = softplus_f(decay[idx]);
    if (idx >= K_ * H_) return;
    float td[M_], ta[M_];
#pragma unroll
    for (int m = 0; m < M_; ++m) td[m] = softplus_f(theta_d_raw[idx * M_ + m]) + 1e-4f;
    ta[0] = td[0];
#pragma unroll
    for (int m = 1; m < M_; ++m) ta[m] = ta[m - 1] + td[m];
    float total = ta[M_ - 1];
    float rs = 2.999f / total;
#pragma unroll
    for (int m = 0; m < M_; ++m) theta_tab[idx * M_ + m] = 0.001f + ta[m] * rs;
    float d0 = (ta[1] - ta[0]) * rs;
    float d1 = (ta[2] - ta[1]) * rs;
    float d2 = (ta[3] - ta[2]) * rs;
    w_tab[idx * M_ + 0] = 0.5f * d0;
    w_tab[idx * M_ + 1] = 0.5f * (d0 + d1);
    w_tab[idx * M_ + 2] = 0.5f * (d1 + d2);
    w_tab[idx * M_ + 3] = 0.5f * d2;
    return;
  }
  b -= 3;
  if (b < 6360) {
    if (b < 672) {           // W_mem -> xpb rows [3276,4056), 24x28
      cvt_t_body(tile, b % 24, b / 24, 0, W_mem, 0, ZC_, xpb_h + (size_t)ZOFF_ * 768,
                 0, 768, 0, 768, ZC_, ZC_, false, 1.f);
      return;
    }
    b -= 672;
    if (b < 2304) {          // W_q -> xpb rows [0,3072), 24x96
      cvt_t_body(tile, b % 24, b / 24, 0, W_q, 0, 3072, xpb_h, 0, 768, 0, 768,
                 3072, 3072, false, 1.f);
      return;
    }
    b -= 2304;
    if (b < 192) {           // skip_down -> xpb rows [3072,3264), 24x8
      cvt_t_body(tile, b % 24, b / 24, 0, skip_down_W, 0, 192, xpb_h + (size_t)3072 * 768,
                 0, 768, 0, 768, 192, 192, false, 1.f);
      return;
    }
    b -= 192;
    if (b < 1728) {          // out_W -> outw, 72x24
      cvt_t_body(tile, b % 72, b / 72, 0, out_W, 0, 768, outw_h, 0, 2304, 0, 2304,
                 768, 768, false, 1.f);
      return;
    }
    b -= 1728;
    if (b < 288) {           // W_re -> bsp[k][perm(n)][0:64], 2x12x12
      cvt_t_body(tile, b % 2, (b / 2) % 12, b / 24, W_re, 64L * 384, 384, bsp_h,
                 384L * 320, 320, 0, 64, 384, 384, true, 1.f);
      return;
    }
    b -= 288;
    if (b < 288) {           // W_im -> bsp[k][perm(n)][64:128]
      cvt_t_body(tile, b % 2, (b / 2) % 12, b / 24, W_im, 64L * 384, 384, bsp_h,
                 384L * 320, 320, 64, 64, 384, 384, true, 1.f);
      return;
    }
    b -= 288;
    if (b < 864) {           // skip_up slice -> bsp[k][perm(n)][128:320] scaled by hs[k]
      int kz = b / 72;
      cvt_t_body(tile, b % 6, (b / 6) % 12, kz, skip_up_W, 384, 4608, bsp_h,
                 384L * 320, 320, 128, 192, 384, 384, true, hs[kz]);
      return;
    }
    b -= 864;
    // gate_W (768x12) -> xpb rows [3264,3276), 24 blocks; store-limited to 12 rows
    cvt_t_body(tile, b, 0, 0, gate_W, 0, K_, xpb_h + (size_t)3264 * 768,
               0, 768, 0, 768, K_, K_, false, 1.f);
    return;
  }
  b -= 6360;
  size_t i = (size_t)b * 256 + threadIdx.x;
  if (i < (size_t)NTOK_ * D_) {
    x_h[i] = (_Float16)x[i];         // x -> fp16
  }
}

// ---------------------------------------------------------------------------
// 256x256-tile 8-phase deep-pipelined MFMA GEMM for the merged x-projection.
// M=4096, N=4096, K=768, BK=64, 12 K-tiles, 512 threads (8 waves 2Mx4N),
// 128 KiB dbuf LDS, two [128][32] subtiles per K-half (0-conflict swizzle).
// Grid = 256 blocks = exactly 1 block/CU.
// T4 counted-vmcnt schedule: stage B(t+2) at ph1, A(t+2) at ph2; the per-tile
// wait is vmcnt(4) (completes tile t+1's 8 loads, leaves B(t+2) in flight) --
// loads survive barriers, DMA never idles. vmcnt(0) only in the tail.
// WAR margin: stages write buffer bb whose last LDS reads completed a barrier
// earlier; DMA lands >=900cy after issue (m201-template margin).
// ---------------------------------------------------------------------------
__global__ __launch_bounds__(512, 2)
void xproj256_kernel(const _Float16* __restrict__ Ah, const _Float16* __restrict__ Bh,
                     float* __restrict__ C, _Float16* __restrict__ YH,
                     _Float16* __restrict__ QH, float* __restrict__ GL) {
  // [dbuf][Mhalf/Nhalf][Khalf][row][col32]
  __shared__ __align__(16) _Float16 sA[2][2][2][128][32];
  __shared__ __align__(16) _Float16 sB[2][2][2][128][32];

  const int bid = blockIdx.x;
  const int xcd = bid & 7, s = bid >> 3;        // s in [0,32)
  const int by = xcd * 2 + (s & 1);             // 0..15
  const int bx = s >> 1;                        // 0..15
  const int bm0 = by * 256, bn0 = bx * 256;

  const int tid = threadIdx.x;
  const int lane = tid & 63;
  const int wave = tid >> 6;
  const int m16 = lane & 15, quad = lane >> 4;
  const int wr = wave >> 2;          // 0..1 A-half
  const int wc = wave & 3;           // 0..3 B col group (64 cols)
  const int bhalf = wc >> 1;         // B LDS half
  const int brow0 = (wc & 1) * 64;   // row base within B half

  f32x4 acc[8][4];
#pragma unroll
  for (int i = 0; i < 8; ++i)
#pragma unroll
    for (int j = 0; j < 4; ++j) acc[i][j] = (f32x4){0.f, 0.f, 0.f, 0.f};

  const int sr = tid >> 2;           // 0..127
  const int lb = tid & 3;            // 16B block within 32-half subtile row
  const int ssw = (sr >> 1) & 3;     // row swizzle term

  auto stageA = [&](int t, int h) {
    const int bb = t & 1;
    const _Float16* g = Ah + (size_t)(bm0 + h * 128 + sr) * 768 + t * 64
                        + ((lb ^ ssw) << 3);
    async16(g,      &sA[bb][h][0][0][0] + (size_t)tid * 8);
    async16(g + 32, &sA[bb][h][1][0][0] + (size_t)tid * 8);
  };
  auto stageB = [&](int t, int h) {
    const int bb = t & 1;
    const _Float16* g = Bh + (size_t)(bn0 + h * 128 + sr) * 768 + t * 64
                        + ((lb ^ ssw) << 3);
    async16(g,      &sB[bb][h][0][0][0] + (size_t)tid * 8);
    async16(g + 32, &sB[bb][h][1][0][0] + (size_t)tid * 8);
  };

  auto ldA = [&](int bb, int r, int kk) -> half8 {
    return *(const half8*)&sA[bb][wr][kk][r][(quad ^ ((r >> 1) & 3)) << 3];
  };
  auto ldB = [&](int bb, int r, int kk) -> half8 {
    return *(const half8*)&sB[bb][bhalf][kk][r][(quad ^ ((r >> 1) & 3)) << 3];
  };

  half8 aLo[8], aHi[8], bLo[4], bHi[4];

  stageB(0, 0); stageB(0, 1); stageA(0, 0); stageA(0, 1);
  stageB(1, 0); stageB(1, 1); stageA(1, 0); stageA(1, 1);
  __builtin_amdgcn_s_waitcnt(0x0F78);   // vmcnt(8): K-tile 0 landed, tile 1 in flight
  FENCE(); __builtin_amdgcn_s_barrier(); FENCE();
#pragma unroll
  for (int m = 0; m < 4; ++m)
#pragma unroll
    for (int kk = 0; kk < 2; ++kk) aLo[m * 2 + kk] = ldA(0, m * 16 + m16, kk);
#pragma unroll
  for (int n = 0; n < 2; ++n)
#pragma unroll
    for (int kk = 0; kk < 2; ++kk) bLo[n * 2 + kk] = ldB(0, brow0 + n * 16 + m16, kk);

  for (int t = 0; t < 12; ++t) {
    const int bb = t & 1;
    const int nb = bb ^ 1;
    // ---------- phase 0: read bHi(t); MFMA lo-lo ----------
#pragma unroll
    for (int n = 0; n < 2; ++n)
#pragma unroll
      for (int kk = 0; kk < 2; ++kk)
        bHi[n * 2 + kk] = ldB(bb, brow0 + (n + 2) * 16 + m16, kk);
    FENCE(); __builtin_amdgcn_s_barrier(); FENCE();
    __builtin_amdgcn_s_setprio(1);
#pragma unroll
    for (int m = 0; m < 4; ++m)
#pragma unroll
      for (int n = 0; n < 2; ++n)
#pragma unroll
        for (int kk = 0; kk < 2; ++kk)
          acc[m][n] = __builtin_amdgcn_mfma_f32_16x16x32_f16(aLo[m * 2 + kk], bLo[n * 2 + kk],
                                                             acc[m][n], 0, 0, 0);
    __builtin_amdgcn_s_setprio(0);
    FENCE(); __builtin_amdgcn_s_barrier(); FENCE();
    // ---------- phase 1: read aHi(t); stage B(t+2); MFMA lo-hi; COUNTED wait ----------
#pragma unroll
    for (int m = 0; m < 4; ++m)
#pragma unroll
      for (int kk = 0; kk < 2; ++kk)
        aHi[m * 2 + kk] = ldA(bb, 64 + m * 16 + m16, kk);
    if (t < 10) { stageB(t + 2, 0); stageB(t + 2, 1); }
    FENCE(); __builtin_amdgcn_s_barrier(); FENCE();
    __builtin_amdgcn_s_setprio(1);
#pragma unroll
    for (int m = 0; m < 4; ++m)
#pragma unroll
      for (int n = 2; n < 4; ++n)
#pragma unroll
        for (int kk = 0; kk < 2; ++kk)
          acc[m][n] = __builtin_amdgcn_mfma_f32_16x16x32_f16(aLo[m * 2 + kk], bHi[(n - 2) * 2 + kk],
                                                             acc[m][n], 0, 0, 0);
    __builtin_amdgcn_s_setprio(0);
    if (t < 10)
      __builtin_amdgcn_s_waitcnt(0x0F74);   // vmcnt(4): tile t+1 landed, B(t+2) in flight
    else
      __builtin_amdgcn_s_waitcnt(0x0F70);   // tail: drain
    FENCE(); __builtin_amdgcn_s_barrier(); FENCE();
    // ---------- phase 2: read aLo(t+1); stage A(t+2); MFMA hi-lo ----------
    if (t < 11) {
#pragma unroll
      for (int m = 0; m < 4; ++m)
#pragma unroll
        for (int kk = 0; kk < 2; ++kk)
          aLo[m * 2 + kk] = ldA(nb, m * 16 + m16, kk);
    }
    if (t < 10) { stageA(t + 2, 0); stageA(t + 2, 1); }
    FENCE(); __builtin_amdgcn_s_barrier(); FENCE();
    __builtin_amdgcn_s_setprio(1);
#pragma unroll
    for (int m = 0; m < 4; ++m)
#pragma unroll
      for (int n = 0; n < 2; ++n)
#pragma unroll
        for (int kk = 0; kk < 2; ++kk)
          acc[m + 4][n] = __builtin_amdgcn_mfma_f32_16x16x32_f16(aHi[m * 2 + kk], bLo[n * 2 + kk],
                                                                 acc[m + 4][n], 0, 0, 0);
    __builtin_amdgcn_s_setprio(0);
    FENCE(); __builtin_amdgcn_s_barrier(); FENCE();
    // ---------- phase 3: read bLo(t+1); MFMA hi-hi ----------
    if (t < 11) {
#pragma unroll
      for (int n = 0; n < 2; ++n)
#pragma unroll
        for (int kk = 0; kk < 2; ++kk)
          bLo[n * 2 + kk] = ldB(nb, brow0 + n * 16 + m16, kk);
    }
    FENCE(); __builtin_amdgcn_s_barrier(); FENCE();
    __builtin_amdgcn_s_setprio(1);
#pragma unroll
    for (int m = 0; m < 4; ++m)
#pragma unroll
      for (int n = 2; n < 4; ++n)
#pragma unroll
        for (int kk = 0; kk < 2; ++kk)
          acc[m + 4][n] = __builtin_amdgcn_mfma_f32_16x16x32_f16(aHi[m * 2 + kk], bHi[(n - 2) * 2 + kk],
                                                                 acc[m + 4][n], 0, 0, 0);
    __builtin_amdgcn_s_setprio(0);
    FENCE(); __builtin_amdgcn_s_barrier(); FENCE();
  }

  // ---- epilogue (C/D layout: col=lane&15, row=quad*4+reg) ----
#pragma unroll
  for (int m = 0; m < 8; ++m) {
    const int row0 = bm0 + wr * 128 + m * 16 + quad * 4;
#pragma unroll
    for (int n = 0; n < 4; ++n) {
      const int col = bn0 + wc * 64 + n * 16 + m16;
      if (col < 3072) {
#pragma unroll
        for (int r = 0; r < 4; ++r)
          QH[(size_t)(row0 + r) * QST_ + col] = (_Float16)acc[m][n][r];
      } else if (col < 3264) {
        const int jj = col - 3072;
#pragma unroll
        for (int r = 0; r < 4; ++r)
          YH[(size_t)(row0 + r) * 192 + jj] = (_Float16)acc[m][n][r];
      } else if (col < 3276) {
        const int kk = col - 3264;
#pragma unroll
        for (int r = 0; r < 4; ++r)
          GL[(size_t)(row0 + r) * K_ + kk] = acc[m][n][r];
      } else if (col < 3276 + ZC_) {
        const int wz = col - ZOFF_;
#pragma unroll
        for (int r = 0; r < 4; ++r)
          C[(size_t)(row0 + r) * ZC_ + wz] = acc[m][n][r];
      }
    }
  }
}

// ---------------------------------------------------------------------------
// 256x256-tile 8-phase out-projection GEMM: out = y @ out_W.
// M=4096, N=768 (=3x256 exact), K=2304, split-K=4 (576 each = 9 BK-tiles).
// Grid 192 blocks x 512 thr, one round, NO atomics; same T4 counted-vmcnt
// schedule as xproj256 (stage B@ph1, A@ph2, vmcnt(4) steady / 0 tail).
// ---------------------------------------------------------------------------
__global__ __launch_bounds__(512, 2)
void outproj256_kernel(const _Float16* __restrict__ Ah, const _Float16* __restrict__ Bh,
                       float* __restrict__ out, float* __restrict__ part) {
  __shared__ __align__(16) _Float16 sA[2][2][2][128][32];
  __shared__ __align__(16) _Float16 sB[2][2][2][128][32];

  const int bid = blockIdx.x;
  const int xcd = bid & 7, s = bid >> 3;        // s in [0,24)
  const int g = xcd * 24 + s;                   // contiguous per XCD
  const int by = g & 15;
  const int c = g >> 4;                         // 0..11 ; c = kz*3 + bx
  const int kz_ = c / 3, bx = c - kz_ * 3;
  const int bm0 = by * 256, bn0 = bx * 256;
  const int kt0 = kz_ * 9;                      // first BK-tile for this split

  const int tid = threadIdx.x;
  const int lane = tid & 63;
  const int wave = tid >> 6;
  const int m16 = lane & 15, quad = lane >> 4;
  const int wr = wave >> 2;
  const int wc = wave & 3;
  const int bhalf = wc >> 1;
  const int brow0 = (wc & 1) * 64;

  f32x4 acc[8][4];
#pragma unroll
  for (int i = 0; i < 8; ++i)
#pragma unroll
    for (int j = 0; j < 4; ++j) acc[i][j] = (f32x4){0.f, 0.f, 0.f, 0.f};

  const int sr = tid >> 2;
  const int lbk = tid & 3;
  const int ssw = (sr >> 1) & 3;

  auto stageA = [&](int lt, int h) {
    const int bb = lt & 1;
    const _Float16* gp = Ah + (size_t)(bm0 + h * 128 + sr) * 2304 + (kt0 + lt) * 64
                         + ((lbk ^ ssw) << 3);
    async16(gp,      &sA[bb][h][0][0][0] + (size_t)tid * 8);
    async16(gp + 32, &sA[bb][h][1][0][0] + (size_t)tid * 8);
  };
  auto stageB = [&](int lt, int h) {
    const int bb = lt & 1;
    const _Float16* gp = Bh + (size_t)(bn0 + h * 128 + sr) * 2304 + (kt0 + lt) * 64
                         + ((lbk ^ ssw) << 3);
    async16(gp,      &sB[bb][h][0][0][0] + (size_t)tid * 8);
    async16(gp + 32, &sB[bb][h][1][0][0] + (size_t)tid * 8);
  };

  auto ldA = [&](int bb, int r, int kk) -> half8 {
    return *(const half8*)&sA[bb][wr][kk][r][(quad ^ ((r >> 1) & 3)) << 3];
  };
  auto ldB = [&](int bb, int r, int kk) -> half8 {
    return *(const half8*)&sB[bb][bhalf][kk][r][(quad ^ ((r >> 1) & 3)) << 3];
  };

  half8 aLo[8], aHi[8], bLo[4], bHi[4];

  stageB(0, 0); stageB(0, 1); stageA(0, 0); stageA(0, 1);
  stageB(1, 0); stageB(1, 1); stageA(1, 0); stageA(1, 1);
  __builtin_amdgcn_s_waitcnt(0x0F78);   // vmcnt(8)
  FENCE(); __builtin_amdgcn_s_barrier(); FENCE();
#pragma unroll
  for (int m = 0; m < 4; ++m)
#pragma unroll
    for (int kk = 0; kk < 2; ++kk) aLo[m * 2 + kk] = ldA(0, m * 16 + m16, kk);
#pragma unroll
  for (int n = 0; n < 2; ++n)
#pragma unroll
    for (int kk = 0; kk < 2; ++kk) bLo[n * 2 + kk] = ldB(0, brow0 + n * 16 + m16, kk);

  for (int t = 0; t < 9; ++t) {
    const int bb = t & 1;
    const int nb = bb ^ 1;
    // phase 0
#pragma unroll
    for (int n = 0; n < 2; ++n)
#pragma unroll
      for (int kk = 0; kk < 2; ++kk)
        bHi[n * 2 + kk] = ldB(bb, brow0 + (n + 2) * 16 + m16, kk);
    FENCE(); __builtin_amdgcn_s_barrier(); FENCE();
    __builtin_amdgcn_s_setprio(1);
#pragma unroll
    for (int m = 0; m < 4; ++m)
#pragma unroll
      for (int n = 0; n < 2; ++n)
#pragma unroll
        for (int kk = 0; kk < 2; ++kk)
          acc[m][n] = __builtin_amdgcn_mfma_f32_16x16x32_f16(aLo[m * 2 + kk], bLo[n * 2 + kk],
                                                             acc[m][n], 0, 0, 0);
    __builtin_amdgcn_s_setprio(0);
    FENCE(); __builtin_amdgcn_s_barrier(); FENCE();
    // phase 1: read aHi; stage B(t+2); MFMA; counted wait
#pragma unroll
    for (int m = 0; m < 4; ++m)
#pragma unroll
      for (int kk = 0; kk < 2; ++kk)
        aHi[m * 2 + kk] = ldA(bb, 64 + m * 16 + m16, kk);
    if (t < 7) { stageB(t + 2, 0); stageB(t + 2, 1); }
    FENCE(); __builtin_amdgcn_s_barrier(); FENCE();
    __builtin_amdgcn_s_setprio(1);
#pragma unroll
    for (int m = 0; m < 4; ++m)
#pragma unroll
      for (int n = 2; n < 4; ++n)
#pragma unroll
        for (int kk = 0; kk < 2; ++kk)
          acc[m][n] = __builtin_amdgcn_mfma_f32_16x16x32_f16(aLo[m * 2 + kk], bHi[(n - 2) * 2 + kk],
                                                             acc[m][n], 0, 0, 0);
    __builtin_amdgcn_s_setprio(0);
    if (t < 7)
      __builtin_amdgcn_s_waitcnt(0x0F74);   // vmcnt(4): tile t+1 landed
    else
      __builtin_amdgcn_s_waitcnt(0x0F70);   // tail: drain
    FENCE(); __builtin_amdgcn_s_barrier(); FENCE();
    // phase 2: read aLo(t+1); stage A(t+2); MFMA
    if (t < 8) {
#pragma unroll
      for (int m = 0; m < 4; ++m)
#pragma unroll
        for (int kk = 0; kk < 2; ++kk)
          aLo[m * 2 + kk] = ldA(nb, m * 16 + m16, kk);
    }
    if (t < 7) { stageA(t + 2, 0); stageA(t + 2, 1); }
    FENCE(); __builtin_amdgcn_s_barrier(); FENCE();
    __builtin_amdgcn_s_setprio(1);
#pragma unroll
    for (int m = 0; m < 4; ++m)
#pragma unroll
      for (int n = 0; n < 2; ++n)
#pragma unroll
        for (int kk = 0; kk < 2; ++kk)
          acc[m + 4][n] = __builtin_amdgcn_mfma_f32_16x16x32_f16(aHi[m * 2 + kk], bLo[n * 2 + kk],
                                                                 acc[m + 4][n], 0, 0, 0);
    __builtin_amdgcn_s_setprio(0);
    FENCE(); __builtin_amdgcn_s_barrier(); FENCE();
    // phase 3: read bLo(t+1); MFMA
    if (t < 8) {
#pragma unroll
      for (int n = 0; n < 2; ++n)
#pragma unroll
        for (int kk = 0; kk < 2; ++kk)
          bLo[n * 2 + kk] = ldB(nb, brow0 + n * 16 + m16, kk);
    }
    FENCE(); __builtin_amdgcn_s_barrier(); FENCE();
    __builtin_amdgcn_s_setprio(1);
#pragma unroll
    for (int m = 0; m < 4; ++m)
#pragma unroll
      for (int n = 2; n < 4; ++n)
#pragma unroll
        for (int kk = 0; kk < 2; ++kk)
          acc[m + 4][n] = __builtin_amdgcn_mfma_f32_16x16x32_f16(aHi[m * 2 + kk], bHi[(n - 2) * 2 + kk],
                                                                 acc[m + 4][n], 0, 0, 0);
    __builtin_amdgcn_s_setprio(0);
    FENCE(); __builtin_amdgcn_s_barrier(); FENCE();
  }

  // ---- epilogue: plain f32 stores (no atomics) ----
  float* dst = (kz_ == 0) ? out : part + (size_t)(kz_ - 1) * NTOK_ * 768;
#pragma unroll
  for (int m = 0; m < 8; ++m) {
    const int row0 = bm0 + wr * 128 + m * 16 + quad * 4;
#pragma unroll
    for (int n = 0; n < 4; ++n) {
      const int col = bn0 + wc * 64 + n * 16 + m16;
#pragma unroll
      for (int r = 0; r < 4; ++r)
        dst[(size_t)(row0 + r) * 768 + col] = acc[m][n][r];
    }
  }
}

// ---------------------------------------------------------------------------
// Fold the 3 split-K partials into out (float4 vectorized, one pass).
// ---------------------------------------------------------------------------
__global__ __launch_bounds__(256)
void redout_kernel(float* __restrict__ o, const float* __restrict__ p) {
  const size_t i = (size_t)blockIdx.x * 256 + threadIdx.x;
  const f32x4* pv = (const f32x4*)p;
  f32x4 v = ((const f32x4*)o)[i];
  v += pv[i];
  v += pv[i + 786432];
  v += pv[i + 2 * 786432];
  ((f32x4*)o)[i] = v;
}

// ---------------------------------------------------------------------------
// MFMA fp16 GEMM (128x128, 2-phase): spec GEMM.
// A from split source (asp per-k 128-stride k<128, lat shared 192-stride);
// fused val/gate SiLU -> YH; XCD-chunked 1D grid (3bx x 32by x 12kz).
// ---------------------------------------------------------------------------
__global__ __launch_bounds__(256)
void spec_gemm_kernel(const _Float16* __restrict__ Ah, const _Float16* __restrict__ Bh,
                      const _Float16* __restrict__ A2, _Float16* __restrict__ YH) {
  __shared__ __align__(16) _Float16 sA[2][128 * 32];
  __shared__ __align__(16) _Float16 sB[2][128 * 32];
  const int Kd = 320;
  int bid = blockIdx.x;
  int xcd = bid & 7, s = bid >> 3;        // s in [0,144)
  int kz = s / 12;
  int w = s % 12;
  int bx = w % 3;
  int by = (xcd << 2) + w / 3;
  const _Float16* A0 = Ah + (size_t)kz * ((size_t)NTOK_ * 128);
  const _Float16* B0 = Bh + (size_t)kz * (384L * 320);
  const int bm0 = by * 128;
  const int bn0 = bx * 128;
  const int tid = threadIdx.x;
  const int wave = tid >> 6, lane = tid & 63;
  const int m16 = lane & 15, quad = lane >> 4;
  const int wr = (wave & 1) * 64, wc = (wave >> 1) * 64;

  f32x4 acc[4][4];
#pragma unroll
  for (int i = 0; i < 4; ++i)
#pragma unroll
    for (int j = 0; j < 4; ++j) acc[i][j] = (f32x4){0.f, 0.f, 0.f, 0.f};

  const int lin = tid * 8;
  const int lrow = lin >> 5;
  const int lblk = (lin >> 3) & 3;
  const int csw = ((lblk ^ ((lrow >> 1) & 3)) << 3);

  auto stage = [&](int k0, int kb) {
    if (k0 < 128) {
      const _Float16* gA = A0 + (size_t)(bm0 + lrow) * 128 + (k0 + csw);
      async16(gA, &sA[kb][lin]);
      async16(gA + (size_t)64 * 128, &sA[kb][lin + 2048]);
    } else {
      const _Float16* gA = A2 + (size_t)(bm0 + lrow) * 192 + (k0 - 128 + csw);
      async16(gA, &sA[kb][lin]);
      async16(gA + (size_t)64 * 192, &sA[kb][lin + 2048]);
    }
    const _Float16* gB = B0 + (size_t)(bn0 + lrow) * Kd + (k0 + csw);
    async16(gB, &sB[kb][lin]);
    async16(gB + (size_t)64 * Kd, &sB[kb][lin + 2048]);
  };

  const int niter = Kd / 32;
  stage(0, 0);
  stage(32, 1);

  for (int it = 0; it < niter; ++it) {
    if (it == niter - 1)
      __builtin_amdgcn_s_waitcnt(0x0F70);   // vmcnt(0)
    else
      __builtin_amdgcn_s_waitcnt(0x0F74);   // vmcnt(4)
    __builtin_amdgcn_s_barrier();
    asm volatile("" ::: "memory");
    const int kb = it & 1;
    half8 a0[4], b0[4];
#pragma unroll
    for (int i = 0; i < 4; ++i) {
      const int rA = wr + i * 16 + m16;
      a0[i] = *(const half8*)&sA[kb][rA * 32 + ((quad ^ ((rA >> 1) & 3)) << 3)];
    }
#pragma unroll
    for (int j = 0; j < 4; ++j) {
      const int rB = wc + j * 16 + m16;
      b0[j] = *(const half8*)&sB[kb][rB * 32 + ((quad ^ ((rB >> 1) & 3)) << 3)];
    }
#pragma unroll
    for (int i = 0; i < 4; ++i)
#pragma unroll
      for (int j = 0; j < 4; ++j)
        acc[i][j] = __builtin_amdgcn_mfma_f32_16x16x32_f16(a0[i], b0[j], acc[i][j], 0, 0, 0);
    asm volatile("" ::: "memory");
    __builtin_amdgcn_s_barrier();
    asm volatile("" ::: "memory");
    if (it + 2 < niter) stage((it + 2) * 32, kb);
  }

#pragma unroll
  for (int i = 0; i < 4; ++i) {
    const int row0 = bm0 + wr + i * 16 + quad * 4;
#pragma unroll
    for (int j = 0; j < 4; j += 2) {
      const int colv = bn0 + wc + j * 16 + m16;
      const int jout = (colv >> 5) * 16 + m16;
#pragma unroll
      for (int r = 0; r < 4; ++r) {
        float val = acc[i][j][r];
        float gg = acc[i][j + 1][r];
        float sg = gg / (1.f + __expf(-gg));
        YH[(size_t)(row0 + r) * 2304 + kz * 192 + jout] = (_Float16)(val * sg);
      }
    }
  }
}

// ---------------------------------------------------------------------------
// Scan pass A with fused causal conv (sliding 4-tap window over z_pre)
// ---------------------------------------------------------------------------
__global__ void pass_a_kernel(const float* __restrict__ zp,
                              const float* __restrict__ ck,
                              const float* __restrict__ theta_tab,
                              const float* __restrict__ score_scale,
                              const float* __restrict__ tanh_scale,
                              const float* __restrict__ slopes_sp,
                              float* __restrict__ csums) {
  const int c = blockIdx.x, k = blockIdx.y, b = blockIdx.z;
  const int tid = threadIdx.x;
  const int m = tid & 3, h = tid >> 2;
  const int chk = k * H_ + h;
  const int chs = 768 + k;
  const float theta_v = theta_tab[chk * M_ + m];
  const float ts = tanh_scale[k], ss = score_scale[k], slope = slopes_sp[k];
  float ckv[4], cks[4];
#pragma unroll
  for (int w = 0; w < 4; ++w) { ckv[w] = ck[w * ZC_ + chk]; cks[w] = ck[w * ZC_ + chs]; }
  const int l0 = c * LC_;
  float zk3 = 0.f, zk2 = 0.f, zk1 = 0.f, zs3 = 0.f, zs2 = 0.f, zs1 = 0.f;
#pragma unroll
  for (int p = 0; p < 3; ++p) {
    int lp = l0 - 3 + p;
    if (lp >= 0) {
      size_t tp = (size_t)b * L_ + lp;
      float zk = zp[tp * ZC_ + chk], zs = zp[tp * ZC_ + chs];
      if (p == 0) { zk3 = zk; zs3 = zs; }
      else if (p == 1) { zk2 = zk; zs2 = zs; }
      else { zk1 = zk; zs1 = zs; }
    }
  }
  float sre = 0.f, sim = 0.f, dacc = 0.f;
  for (int ll = 0; ll < LC_; ++ll) {
    int l = l0 + ll;
    size_t t = (size_t)b * L_ + l;
    float zk0 = zp[t * ZC_ + chk];
    float zs0 = zp[t * ZC_ + chs];
    float kv = zk3 * ckv[0] + zk2 * ckv[1] + zk1 * ckv[2] + zk0 * ckv[3];
    float sraw = zs3 * cks[0] + zs2 * cks[1] + zs1 * cks[2] + zs0 * cks[3];
    zk3 = zk2; zk2 = zk1; zk1 = zk0;
    zs3 = zs2; zs2 = zs1; zs1 = zs0;
    float lp = fminf(fmaxf(ss * sraw, -20.f), 20.f);
    float pw = __expf(lp - slope * (float)(L_ - 1 - l));
    float ph = fast_tanh(ts * kv) * theta_v;
    float kvp = kv * pw;
    sre += kvp * __cosf(ph);
    sim += kvp * __sinf(ph);
    dacc += pw;
  }
  size_t base = (((size_t)b * K_ + k) * NC_ + c) * 513;
  if (tid == 0) csums[base] = dacc;
  csums[base + 1 + h * 4 + m] = sre;
  csums[base + 1 + 256 + h * 4 + m] = sim;
}

// ---------------------------------------------------------------------------
__global__ void pass_b_kernel(const float* __restrict__ csums,
                              float* __restrict__ cpre) {
  int bk = blockIdx.y;
  int comp = blockIdx.x * 64 + threadIdx.x;
  if (comp >= 513) return;
  float run = 0.f;
  size_t base = (size_t)bk * NC_ * 513 + comp;
  for (int c = 0; c < NC_; ++c) {
    cpre[base + (size_t)c * 513] = run;
    run += csums[base + (size_t)c * 513];
  }
}

// ---------------------------------------------------------------------------
// Scan pass C: fused conv replay, contract with fp16 q, apply ns*gate,
// write fp16 into asp2[k][t][0:128] (128-stride)
// ---------------------------------------------------------------------------
__global__ void pass_c_kernel(const float* __restrict__ zp,
                              const float* __restrict__ ck,
                              const _Float16* __restrict__ qh,
                              const float* __restrict__ theta_tab,
                              const float* __restrict__ w_tab,
                              const float* __restrict__ score_scale,
                              const float* __restrict__ tanh_scale,
                              const float* __restrict__ slopes_sp,
                              const float* __restrict__ cpre,
                              const float* __restrict__ gatelin,
                              const float* __restrict__ gate_b,
                              const float* __restrict__ ns,
                              _Float16* __restrict__ asp) {
  const int c = blockIdx.x, k = blockIdx.y, b = blockIdx.z;
  const int tid = threadIdx.x;
  const int m = tid & 3, h = tid >> 2;
  const int chk = k * H_ + h;
  const int chs = 768 + k;
  size_t base = (((size_t)b * K_ + k) * NC_ + c) * 513;
  float den = cpre[base];
  float sre = cpre[base + 1 + h * 4 + m];
  float sim = cpre[base + 1 + 256 + h * 4 + m];
  const float theta_v = theta_tab[chk * M_ + m];
  const float w = w_tab[chk * M_ + m];
  const float ts = tanh_scale[k], ss = score_scale[k], slope = slopes_sp[k];
  const float nsv = ns[chk];
  const float gb = gate_b[k];
  const int kq = k >> 1;   // NREP = 2
  float ckv[4], cks[4];
#pragma unroll
  for (int ww = 0; ww < 4; ++ww) { ckv[ww] = ck[ww * ZC_ + chk]; cks[ww] = ck[ww * ZC_ + chs]; }
  const int l0 = c * LC_;
  float zk3 = 0.f, zk2 = 0.f, zk1 = 0.f, zs3 = 0.f, zs2 = 0.f, zs1 = 0.f;
#pragma unroll
  for (int p = 0; p < 3; ++p) {
    int lp = l0 - 3 + p;
    if (lp >= 0) {
      size_t tp = (size_t)b * L_ + lp;
      float zk = zp[tp * ZC_ + chk], zs = zp[tp * ZC_ + chs];
      if (p == 0) { zk3 = zk; zs3 = zs; }
      else if (p == 1) { zk2 = zk; zs2 = zs; }
      else { zk1 = zk; zs1 = zs; }
    }
  }
  const int qidx = ((kq * H_ + h) * M_ + m) * 2;
  for (int ll = 0; ll < LC_; ++ll) {
    int l = l0 + ll;
    size_t t = (size_t)b * L_ + l;
    float zk0 = zp[t * ZC_ + chk];
    float zs0 = zp[t * ZC_ + chs];
    float kv = zk3 * ckv[0] + zk2 * ckv[1] + zk1 * ckv[2] + zk0 * ckv[3];
    float sraw = zs3 * cks[0] + zs2 * cks[1] + zs1 * cks[2] + zs0 * cks[3];
    zk3 = zk2; zk2 = zk1; zk1 = zk0;
    zs3 = zs2; zs2 = zs1; zs1 = zs0;
    float lp = fminf(fmaxf(ss * sraw, -20.f), 20.f);
    float pw = __expf(lp - slope * (float)(L_ - 1 - l));
    float ph = fast_tanh(ts * kv) * theta_v;
    float kvp = kv * pw;
    sre += kvp * __cosf(ph);
    sim += kvp * __sinf(ph);
    den += pw;
    float inv = 1.f / fmaxf(den, 1e-4f);
    float s_re = sre * inv, s_im = sim * inv;
    size_t qb = t * QST_ + qidx;
    float qr = (float)qh[qb], qi = (float)qh[qb + 1];
    float tr = (s_re * qr + s_im * qi) * w;
    float ti = (s_im * qr - s_re * qi) * w;
    tr += __shfl_xor(tr, 1); tr += __shfl_xor(tr, 2);
    ti += __shfl_xor(ti, 1); ti += __shfl_xor(ti, 2);
    if (m == 0) {
      float g = 1.f / (1.f + __expf(-(gatelin[t * K_ + k] + gb))) * nsv;
      size_t ab = ((size_t)k * NTOK_ + t) * 128;
      asp[ab + h] = (_Float16)(tr * g);
      asp[ab + 64 + h] = (_Float16)(ti * g);
    }
  }
}

// ---------------------------------------------------------------------------
extern "C" void kernel_launch(void* const* d_in, const int* in_sizes, int n_in,
                              void* d_out, int out_size, void* d_ws, size_t ws_size,
                              hipStream_t stream) {
  const float* x            = (const float*)d_in[0];
  const float* W_mem        = (const float*)d_in[1];
  const float* conv_k       = (const float*)d_in[2];
  const float* W_q          = (const float*)d_in[3];
  const float* theta_d_raw  = (const float*)d_in[4];
  const float* decay_slopes = (const float*)d_in[5];
  const float* score_scale  = (const float*)d_in[6];
  const float* tanh_scale   = (const float*)d_in[7];
  const float* W_re         = (const float*)d_in[8];
  const float* W_im         = (const float*)d_in[9];
  const float* norm_scale   = (const float*)d_in[10];
  const float* gate_W       = (const float*)d_in[11];
  const float* gate_b       = (const float*)d_in[12];
  const float* skip_down_W  = (const float*)d_in[13];
  const float* skip_up_W    = (const float*)d_in[14];
  const float* highway_scale= (const float*)d_in[15];
  const float* out_W        = (const float*)d_in[16];
  float* out = (float*)d_out;
  float* ws = (float*)d_ws;

  // ---- f32 region ----
  float* theta_tab = ws;                                  // 3072
  float* w_tab     = theta_tab + 3072;                    // 3072
  float* slopes_sp = w_tab + 3072;                        // 16
  float* z_pre     = slopes_sp + 16;                      // 3,194,880
  float* gatelin   = z_pre + (size_t)NTOK_ * ZC_;         // 49,152
  float* csums     = gatelin + (size_t)NTOK_ * K_;        // 787,968
  float* cpre      = csums + (size_t)B_ * K_ * NC_ * 513; // 787,968
  _Float16* q_h    = (_Float16*)(cpre + (size_t)B_ * K_ * NC_ * 513); // 4096x3072
  _Float16* y_h    = q_h + (size_t)NTOK_ * QST_;          // 4096x2304
  float* f32_end   = (float*)(y_h + (size_t)NTOK_ * 2304);

  // split-K partials (3 x 4096 x 768 f32 = 9.44M floats) OVERLAY the dead
  // scan workspace (z_pre..q_h = 11.1M floats, consumed before outproj runs)
  float* part = z_pre;

  // ---- fp16 region ----
  _Float16* fp = (_Float16*)f32_end;
  _Float16* x_h    = fp;                fp += (size_t)NTOK_ * D_;
  _Float16* xpb_h  = fp;                fp += (size_t)XPN_ * 768;   // merged proj B (4096 rows)
  _Float16* outw_h = fp;                fp += (size_t)768 * 2304;
  _Float16* asp2_h = fp;                fp += (size_t)K_ * NTOK_ * 128;
  _Float16* bsp_h  = fp;                fp += (size_t)K_ * 384 * 320;
  _Float16* lat_h  = fp;                fp += (size_t)NTOK_ * 192;

  // fused prologue: precomp + all weight conversions (incl gate_W) + x->fp16
  prep_kernel<<<18651, 256, 0, stream>>>(x, W_mem, W_q, skip_down_W, out_W, W_re, W_im,
                                         skip_up_W, highway_scale, gate_W,
                                         theta_d_raw, decay_slopes,
                                         x_h, xpb_h, outw_h, bsp_h,
                                         theta_tab, w_tab, slopes_sp);

  // merged x-projection (256-tile 8-phase, counted vmcnt): q + lat + gate + z_pre
  xproj256_kernel<<<256, 512, 0, stream>>>(x_h, xpb_h, z_pre, lat_h, q_h, gatelin);

  // chunked scan (f32) with fused causal conv
  pass_a_kernel<<<dim3(NC_, K_, B_), 256, 0, stream>>>(z_pre, conv_k, theta_tab, score_scale,
                                                       tanh_scale, slopes_sp, csums);
  pass_b_kernel<<<dim3(9, B_ * K_), 64, 0, stream>>>(csums, cpre);
  pass_c_kernel<<<dim3(NC_, K_, B_), 256, 0, stream>>>(z_pre, conv_k, q_h, theta_tab, w_tab,
                                                       score_scale, tanh_scale, slopes_sp, cpre,
                                                       gatelin, gate_b, norm_scale, asp2_h);

  // batched spec GEMM (A = [asp2 per-k | lat_h shared], hs folded into bsp)
  // with fused SiLU -> y_h fp16; XCD-chunked 1D grid (3x32x12 blocks)
  spec_gemm_kernel<<<1152, 256, 0, stream>>>(asp2_h, bsp_h, lat_h, y_h);

  // out = y @ out_W: 256-tile 8-phase counted-vmcnt, split-K=4 partials (no atomics)
  outproj256_kernel<<<192, 512, 0, stream>>>(y_h, outw_h, out, part);
  // fold partials into out
  redout_kernel<<<3072, 256, 0, stream>>>(out, part);
}

// Round 6
// 278.831 us; speedup vs baseline: 1.0229x; 1.0229x over previous
//
#include <hip/hip_runtime.h>
#include <math.h>

#define B_    2
#define L_    2048
#define D_    768
#define K_    12
#define KQ_   6
#define M_    4
#define H_    64
#define ZC_   780      // MEM + K
#define NTOK_ 4096     // B*L
#define NC_   64       // scan chunks per batch
#define LC_   32       // chunk length (L/NC)
#define QST_  3072     // q fp16 row stride
#define XPN_  4096     // merged projection N (exactly 16 x 256 tiles -> no grid tail)
#define ZOFF_ 3276     // z_pre column base in xpb

typedef __attribute__((ext_vector_type(8))) _Float16 half8;
typedef __attribute__((ext_vector_type(4))) float f32x4;

__device__ __forceinline__ float softplus_f(float x) {
  return (x > 20.f) ? x : log1pf(expf(x));
}

__device__ __forceinline__ float fast_tanh(float x) {
  float xx = fminf(fmaxf(x, -10.f), 10.f);
  float e = __expf(2.f * xx);
  return (e - 1.f) / (e + 1.f);
}

// async global->LDS 16B per lane (dest = wave-uniform base + lane*16)
__device__ __forceinline__ void async16(const _Float16* g, _Float16* l) {
  __builtin_amdgcn_global_load_lds(
      (const __attribute__((address_space(1))) unsigned int*)g,
      (__attribute__((address_space(3))) unsigned int*)l, 16, 0, 0);
}

// val/gate 16-interleave permutation for spec-B columns
__device__ __forceinline__ int permcol(int n) {
  int isg = (n >= 192) ? 1 : 0;
  int j = n - 192 * isg;
  return (j >> 4) * 32 + (isg << 4) + (j & 15);
}

#define FENCE() asm volatile("" ::: "memory")

// ---------------------------------------------------------------------------
// Transpose+convert body; optional perm + scale. Nst = store-row limit.
// ---------------------------------------------------------------------------
__device__ __forceinline__ void cvt_t_body(float (*tile)[33], int bx, int by, int kz,
                                           const float* src, long sKs, int srs,
                                           _Float16* dh, long dKs, int dst, int doff,
                                           int R, int Nact, int Nst, bool perm, float scale) {
  const float* s = src + (size_t)kz * sKs;
  _Float16* dhh = dh + (size_t)kz * dKs;
  const int kb = bx * 32;
  const int nb = by * 32;
  const int tx = threadIdx.x & 31, ty = threadIdx.x >> 5;
  for (int i = ty; i < 32; i += 8) {
    int kk = kb + i, n = nb + tx;
    tile[i][tx] = (kk < R && n < Nact) ? s[(size_t)kk * srs + n] : 0.f;
  }
  __syncthreads();
  for (int i = ty; i < 32; i += 8) {
    int n = nb + i, kk = kb + tx;
    if (kk < R && n < Nst) {
      float v = tile[tx][i] * scale;
      int dn = perm ? permcol(n) : n;
      dhh[(size_t)dn * dst + doff + kk] = (_Float16)v;
    }
  }
}

// ---------------------------------------------------------------------------
// Fused prologue, ONE dispatch:
//   blocks [0,3):          precomp (theta/w tables, slopes)
//   blocks [3,6363):       all weight conversions (incl. gate_W -> xpb cols)
//   blocks [6363,18651):   x f32->fp16
// xpb layout (rows x 768): [W_q^T 0:3072 | skd^T 3072:3264 | gate^T 3264:3276 |
//                           W_mem^T 3276:4056 | dead 4056:4096]
// ---------------------------------------------------------------------------
__global__ __launch_bounds__(256)
void prep_kernel(const float* __restrict__ x,
                 const float* __restrict__ W_mem, const float* __restrict__ W_q,
                 const float* __restrict__ skip_down_W, const float* __restrict__ out_W,
                 const float* __restrict__ W_re, const float* __restrict__ W_im,
                 const float* __restrict__ skip_up_W, const float* __restrict__ hs,
                 const float* __restrict__ gate_W,
                 const float* __restrict__ theta_d_raw, const float* __restrict__ decay,
                 _Float16* __restrict__ x_h,
                 _Float16* __restrict__ xpb_h, _Float16* __restrict__ outw_h,
                 _Float16* __restrict__ bsp_h,
                 float* __restrict__ theta_tab, float* __restrict__ w_tab,
                 float* __restrict__ slopes_sp) {
  __shared__ float tile[32][33];
  int b = blockIdx.x;
  if (b < 3) {
    int idx = b * 256 + threadIdx.x;
    if (idx < K_) slopes_sp[idx] = softplus_f(decay[idx]);
    if (idx >= K_ * H_) return;
    float td[M_], ta[M_];
#pragma unroll
    for (int m = 0; m < M_; ++m) td[m] = softplus_f(theta_d_raw[idx * M_ + m]) + 1e-4f;
    ta[0] = td[0];
#pragma unroll
    for (int m = 1; m < M_; ++m) ta[m] = ta[m - 1] + td[m];
    float total = ta[M_ - 1];
    float rs = 2.999f / total;
#pragma unroll
    for (int m = 0; m < M_; ++m) theta_tab[idx * M_ + m] = 0.001f + ta[m] * rs;
    float d0 = (ta[1] - ta[0]) * rs;
    float d1 = (ta[2] - ta[1]) * rs;
    float d2 = (ta[3] - ta[2]) * rs;
    w_tab[idx * M_ + 0] = 0.5f * d0;
    w_tab[idx * M_ + 1] = 0.5f * (d0 + d1);
    w_tab[idx * M_ + 2] = 0.5f * (d1 + d2);
    w_tab[idx * M_ + 3] = 0.5f * d2;
    return;
  }
  b -= 3;
  if (b < 6360) {
    if (b < 672) {           // W_mem -> xpb rows [3276,4056), 24x28
      cvt_t_body(tile, b % 24, b / 24, 0, W_mem, 0, ZC_, xpb_h + (size_t)ZOFF_ * 768,
                 0, 768, 0, 768, ZC_, ZC_, false, 1.f);
      return;
    }
    b -= 672;
    if (b < 2304) {          // W_q -> xpb rows [0,3072), 24x96
      cvt_t_body(tile, b % 24, b / 24, 0, W_q, 0, 3072, xpb_h, 0, 768, 0, 768,
                 3072, 3072, false, 1.f);
      return;
    }
    b -= 2304;
    if (b < 192) {           // skip_down -> xpb rows [3072,3264), 24x8
      cvt_t_body(tile, b % 24, b / 24, 0, skip_down_W, 0, 192, xpb_h + (size_t)3072 * 768,
                 0, 768, 0, 768, 192, 192, false, 1.f);
      return;
    }
    b -= 192;
    if (b < 1728) {          // out_W -> outw, 72x24
      cvt_t_body(tile, b % 72, b / 72, 0, out_W, 0, 768, outw_h, 0, 2304, 0, 2304,
                 768, 768, false, 1.f);
      return;
    }
    b -= 1728;
    if (b < 288) {           // W_re -> bsp[k][perm(n)][0:64], 2x12x12
      cvt_t_body(tile, b % 2, (b / 2) % 12, b / 24, W_re, 64L * 384, 384, bsp_h,
                 384L * 320, 320, 0, 64, 384, 384, true, 1.f);
      return;
    }
    b -= 288;
    if (b < 288) {           // W_im -> bsp[k][perm(n)][64:128]
      cvt_t_body(tile, b % 2, (b / 2) % 12, b / 24, W_im, 64L * 384, 384, bsp_h,
                 384L * 320, 320, 64, 64, 384, 384, true, 1.f);
      return;
    }
    b -= 288;
    if (b < 864) {           // skip_up slice -> bsp[k][perm(n)][128:320] scaled by hs[k]
      int kz = b / 72;
      cvt_t_body(tile, b % 6, (b / 6) % 12, kz, skip_up_W, 384, 4608, bsp_h,
                 384L * 320, 320, 128, 192, 384, 384, true, hs[kz]);
      return;
    }
    b -= 864;
    // gate_W (768x12) -> xpb rows [3264,3276), 24 blocks; store-limited to 12 rows
    cvt_t_body(tile, b, 0, 0, gate_W, 0, K_, xpb_h + (size_t)3264 * 768,
               0, 768, 0, 768, K_, K_, false, 1.f);
    return;
  }
  b -= 6360;
  size_t i = (size_t)b * 256 + threadIdx.x;
  if (i < (size_t)NTOK_ * D_) {
    x_h[i] = (_Float16)x[i];         // x -> fp16
  }
}

// ---------------------------------------------------------------------------
// 256x256-tile deep-pipelined MFMA GEMM for the merged x-projection.
// M=4096, N=4096, K=768, BK=64, 12 K-tiles, 512 threads (8 waves 2Mx4N),
// 128 KiB dbuf LDS, two [128][32] subtiles per K-half (0-conflict swizzle).
// Grid = 256 blocks = exactly 1 block/CU.
// 2-BARRIER/K-tile schedule: barriers exist only to order bb-reads vs DMA
// stages into bb. Per tile: R1 reads (bHi,aHi) -> BARRIER1 -> stage(t+2) ->
// counted vmcnt(8) -> BARRIER2 -> 32 MFMAs with next-tile reg reads (aLo/bLo
// of t+1 from nb) interleaved, NO further syncs. Hazards: all bb reads precede
// BARRIER1; stage DMA lands >=900cy later; MFMA clusters touch registers only;
// bLo(t) consumed by hi-lo before bLo(t+1) overwrite. vmcnt: 8 stage-instr/
// tile/wave -> steady wait vmcnt(8); tail drains with vmcnt(0).
// ---------------------------------------------------------------------------
__global__ __launch_bounds__(512, 2)
void xproj256_kernel(const _Float16* __restrict__ Ah, const _Float16* __restrict__ Bh,
                     float* __restrict__ C, _Float16* __restrict__ YH,
                     _Float16* __restrict__ QH, float* __restrict__ GL) {
  // [dbuf][Mhalf/Nhalf][Khalf][row][col32]
  __shared__ __align__(16) _Float16 sA[2][2][2][128][32];
  __shared__ __align__(16) _Float16 sB[2][2][2][128][32];

  const int bid = blockIdx.x;
  const int xcd = bid & 7, s = bid >> 3;        // s in [0,32)
  const int by = xcd * 2 + (s & 1);             // 0..15
  const int bx = s >> 1;                        // 0..15
  const int bm0 = by * 256, bn0 = bx * 256;

  const int tid = threadIdx.x;
  const int lane = tid & 63;
  const int wave = tid >> 6;
  const int m16 = lane & 15, quad = lane >> 4;
  const int wr = wave >> 2;          // 0..1 A-half
  const int wc = wave & 3;           // 0..3 B col group (64 cols)
  const int bhalf = wc >> 1;         // B LDS half
  const int brow0 = (wc & 1) * 64;   // row base within B half

  f32x4 acc[8][4];
#pragma unroll
  for (int i = 0; i < 8; ++i)
#pragma unroll
    for (int j = 0; j < 4; ++j) acc[i][j] = (f32x4){0.f, 0.f, 0.f, 0.f};

  const int sr = tid >> 2;           // 0..127
  const int lb = tid & 3;            // 16B block within 32-half subtile row
  const int ssw = (sr >> 1) & 3;     // row swizzle term

  auto stageA = [&](int t, int h) {
    const int bb = t & 1;
    const _Float16* g = Ah + (size_t)(bm0 + h * 128 + sr) * 768 + t * 64
                        + ((lb ^ ssw) << 3);
    async16(g,      &sA[bb][h][0][0][0] + (size_t)tid * 8);
    async16(g + 32, &sA[bb][h][1][0][0] + (size_t)tid * 8);
  };
  auto stageB = [&](int t, int h) {
    const int bb = t & 1;
    const _Float16* g = Bh + (size_t)(bn0 + h * 128 + sr) * 768 + t * 64
                        + ((lb ^ ssw) << 3);
    async16(g,      &sB[bb][h][0][0][0] + (size_t)tid * 8);
    async16(g + 32, &sB[bb][h][1][0][0] + (size_t)tid * 8);
  };

  auto ldA = [&](int bb, int r, int kk) -> half8 {
    return *(const half8*)&sA[bb][wr][kk][r][(quad ^ ((r >> 1) & 3)) << 3];
  };
  auto ldB = [&](int bb, int r, int kk) -> half8 {
    return *(const half8*)&sB[bb][bhalf][kk][r][(quad ^ ((r >> 1) & 3)) << 3];
  };

  half8 aLo[8], aHi[8], bLo[4], bHi[4];

  stageB(0, 0); stageB(0, 1); stageA(0, 0); stageA(0, 1);
  stageB(1, 0); stageB(1, 1); stageA(1, 0); stageA(1, 1);
  __builtin_amdgcn_s_waitcnt(0x0F78);   // vmcnt(8): K-tile 0 landed, tile 1 in flight
  FENCE(); __builtin_amdgcn_s_barrier(); FENCE();
#pragma unroll
  for (int m = 0; m < 4; ++m)
#pragma unroll
    for (int kk = 0; kk < 2; ++kk) aLo[m * 2 + kk] = ldA(0, m * 16 + m16, kk);
#pragma unroll
  for (int n = 0; n < 2; ++n)
#pragma unroll
    for (int kk = 0; kk < 2; ++kk) bLo[n * 2 + kk] = ldB(0, brow0 + n * 16 + m16, kk);

  for (int t = 0; t < 12; ++t) {
    const int bb = t & 1;
    const int nb = bb ^ 1;
    // ---- R1: read bHi(t), aHi(t) from bb (last bb reads of this tile) ----
#pragma unroll
    for (int n = 0; n < 2; ++n)
#pragma unroll
      for (int kk = 0; kk < 2; ++kk)
        bHi[n * 2 + kk] = ldB(bb, brow0 + (n + 2) * 16 + m16, kk);
#pragma unroll
    for (int m = 0; m < 4; ++m)
#pragma unroll
      for (int kk = 0; kk < 2; ++kk)
        aHi[m * 2 + kk] = ldA(bb, 64 + m * 16 + m16, kk);
    FENCE(); __builtin_amdgcn_s_barrier(); FENCE();   // BARRIER1: all bb reads issued
    if (t < 10) { stageB(t + 2, 0); stageB(t + 2, 1); stageA(t + 2, 0); stageA(t + 2, 1); }
    FENCE();
    if (t < 10)
      __builtin_amdgcn_s_waitcnt(0x0F78);   // vmcnt(8): tile t+1 landed, t+2 in flight
    else
      __builtin_amdgcn_s_waitcnt(0x0F70);   // tail: drain
    FENCE(); __builtin_amdgcn_s_barrier(); FENCE();   // BARRIER2: t+1 visible block-wide
    // ---- 32 MFMAs, no further syncs; next-tile reg reads interleave ----
    __builtin_amdgcn_s_setprio(1);
#pragma unroll
    for (int kk = 0; kk < 2; ++kk)
#pragma unroll
      for (int m = 0; m < 4; ++m)
#pragma unroll
        for (int n = 0; n < 2; ++n)
          acc[m][n] = __builtin_amdgcn_mfma_f32_16x16x32_f16(aLo[m * 2 + kk], bLo[n * 2 + kk],
                                                             acc[m][n], 0, 0, 0);
#pragma unroll
    for (int kk = 0; kk < 2; ++kk)
#pragma unroll
      for (int m = 0; m < 4; ++m)
#pragma unroll
        for (int n = 2; n < 4; ++n)
          acc[m][n] = __builtin_amdgcn_mfma_f32_16x16x32_f16(aLo[m * 2 + kk], bHi[(n - 2) * 2 + kk],
                                                             acc[m][n], 0, 0, 0);
    __builtin_amdgcn_s_setprio(0);
    if (t < 11) {                          // aLo(t+1) from nb (staged, vmcnt'd)
#pragma unroll
      for (int m = 0; m < 4; ++m)
#pragma unroll
        for (int kk = 0; kk < 2; ++kk)
          aLo[m * 2 + kk] = ldA(nb, m * 16 + m16, kk);
    }
    __builtin_amdgcn_s_setprio(1);
#pragma unroll
    for (int kk = 0; kk < 2; ++kk)
#pragma unroll
      for (int m = 0; m < 4; ++m)
#pragma unroll
        for (int n = 0; n < 2; ++n)
          acc[m + 4][n] = __builtin_amdgcn_mfma_f32_16x16x32_f16(aHi[m * 2 + kk], bLo[n * 2 + kk],
                                                                 acc[m + 4][n], 0, 0, 0);
    __builtin_amdgcn_s_setprio(0);
    if (t < 11) {                          // bLo(t+1) from nb (bLo(t) consumed above)
#pragma unroll
      for (int n = 0; n < 2; ++n)
#pragma unroll
        for (int kk = 0; kk < 2; ++kk)
          bLo[n * 2 + kk] = ldB(nb, brow0 + n * 16 + m16, kk);
    }
    __builtin_amdgcn_s_setprio(1);
#pragma unroll
    for (int kk = 0; kk < 2; ++kk)
#pragma unroll
      for (int m = 0; m < 4; ++m)
#pragma unroll
        for (int n = 2; n < 4; ++n)
          acc[m + 4][n] = __builtin_amdgcn_mfma_f32_16x16x32_f16(aHi[m * 2 + kk], bHi[(n - 2) * 2 + kk],
                                                                 acc[m + 4][n], 0, 0, 0);
    __builtin_amdgcn_s_setprio(0);
  }

  // ---- epilogue (C/D layout: col=lane&15, row=quad*4+reg) ----
#pragma unroll
  for (int m = 0; m < 8; ++m) {
    const int row0 = bm0 + wr * 128 + m * 16 + quad * 4;
#pragma unroll
    for (int n = 0; n < 4; ++n) {
      const int col = bn0 + wc * 64 + n * 16 + m16;
      if (col < 3072) {
#pragma unroll
        for (int r = 0; r < 4; ++r)
          QH[(size_t)(row0 + r) * QST_ + col] = (_Float16)acc[m][n][r];
      } else if (col < 3264) {
        const int jj = col - 3072;
#pragma unroll
        for (int r = 0; r < 4; ++r)
          YH[(size_t)(row0 + r) * 192 + jj] = (_Float16)acc[m][n][r];
      } else if (col < 3276) {
        const int kk = col - 3264;
#pragma unroll
        for (int r = 0; r < 4; ++r)
          GL[(size_t)(row0 + r) * K_ + kk] = acc[m][n][r];
      } else if (col < 3276 + ZC_) {
        const int wz = col - ZOFF_;
#pragma unroll
        for (int r = 0; r < 4; ++r)
          C[(size_t)(row0 + r) * ZC_ + wz] = acc[m][n][r];
      }
    }
  }
}

// ---------------------------------------------------------------------------
// 256x256-tile out-projection GEMM: out = y @ out_W.
// M=4096, N=768 (=3x256 exact), K=2304, split-K=4 (576 each = 9 BK-tiles).
// Grid 192 blocks x 512 thr, one round, NO atomics. Same 2-barrier/K-tile
// counted-vmcnt schedule as xproj256 (TS=7 stage guard, TL=8 read guard).
// ---------------------------------------------------------------------------
__global__ __launch_bounds__(512, 2)
void outproj256_kernel(const _Float16* __restrict__ Ah, const _Float16* __restrict__ Bh,
                       float* __restrict__ out, float* __restrict__ part) {
  __shared__ __align__(16) _Float16 sA[2][2][2][128][32];
  __shared__ __align__(16) _Float16 sB[2][2][2][128][32];

  const int bid = blockIdx.x;
  const int xcd = bid & 7, s = bid >> 3;        // s in [0,24)
  const int g = xcd * 24 + s;                   // contiguous per XCD
  const int by = g & 15;
  const int c = g >> 4;                         // 0..11 ; c = kz*3 + bx
  const int kz_ = c / 3, bx = c - kz_ * 3;
  const int bm0 = by * 256, bn0 = bx * 256;
  const int kt0 = kz_ * 9;                      // first BK-tile for this split

  const int tid = threadIdx.x;
  const int lane = tid & 63;
  const int wave = tid >> 6;
  const int m16 = lane & 15, quad = lane >> 4;
  const int wr = wave >> 2;
  const int wc = wave & 3;
  const int bhalf = wc >> 1;
  const int brow0 = (wc & 1) * 64;

  f32x4 acc[8][4];
#pragma unroll
  for (int i = 0; i < 8; ++i)
#pragma unroll
    for (int j = 0; j < 4; ++j) acc[i][j] = (f32x4){0.f, 0.f, 0.f, 0.f};

  const int sr = tid >> 2;
  const int lbk = tid & 3;
  const int ssw = (sr >> 1) & 3;

  auto stageA = [&](int lt, int h) {
    const int bb = lt & 1;
    const _Float16* gp = Ah + (size_t)(bm0 + h * 128 + sr) * 2304 + (kt0 + lt) * 64
                         + ((lbk ^ ssw) << 3);
    async16(gp,      &sA[bb][h][0][0][0] + (size_t)tid * 8);
    async16(gp + 32, &sA[bb][h][1][0][0] + (size_t)tid * 8);
  };
  auto stageB = [&](int lt, int h) {
    const int bb = lt & 1;
    const _Float16* gp = Bh + (size_t)(bn0 + h * 128 + sr) * 2304 + (kt0 + lt) * 64
                         + ((lbk ^ ssw) << 3);
    async16(gp,      &sB[bb][h][0][0][0] + (size_t)tid * 8);
    async16(gp + 32, &sB[bb][h][1][0][0] + (size_t)tid * 8);
  };

  auto ldA = [&](int bb, int r, int kk) -> half8 {
    return *(const half8*)&sA[bb][wr][kk][r][(quad ^ ((r >> 1) & 3)) << 3];
  };
  auto ldB = [&](int bb, int r, int kk) -> half8 {
    return *(const half8*)&sB[bb][bhalf][kk][r][(quad ^ ((r >> 1) & 3)) << 3];
  };

  half8 aLo[8], aHi[8], bLo[4], bHi[4];

  stageB(0, 0); stageB(0, 1); stageA(0, 0); stageA(0, 1);
  stageB(1, 0); stageB(1, 1); stageA(1, 0); stageA(1, 1);
  __builtin_amdgcn_s_waitcnt(0x0F78);   // vmcnt(8)
  FENCE(); __builtin_amdgcn_s_barrier(); FENCE();
#pragma unroll
  for (int m = 0; m < 4; ++m)
#pragma unroll
    for (int kk = 0; kk < 2; ++kk) aLo[m * 2 + kk] = ldA(0, m * 16 + m16, kk);
#pragma unroll
  for (int n = 0; n < 2; ++n)
#pragma unroll
    for (int kk = 0; kk < 2; ++kk) bLo[n * 2 + kk] = ldB(0, brow0 + n * 16 + m16, kk);

  for (int t = 0; t < 9; ++t) {
    const int bb = t & 1;
    const int nb = bb ^ 1;
    // R1
#pragma unroll
    for (int n = 0; n < 2; ++n)
#pragma unroll
      for (int kk = 0; kk < 2; ++kk)
        bHi[n * 2 + kk] = ldB(bb, brow0 + (n + 2) * 16 + m16, kk);
#pragma unroll
    for (int m = 0; m < 4; ++m)
#pragma unroll
      for (int kk = 0; kk < 2; ++kk)
        aHi[m * 2 + kk] = ldA(bb, 64 + m * 16 + m16, kk);
    FENCE(); __builtin_amdgcn_s_barrier(); FENCE();   // BARRIER1
    if (t < 7) { stageB(t + 2, 0); stageB(t + 2, 1); stageA(t + 2, 0); stageA(t + 2, 1); }
    FENCE();
    if (t < 7)
      __builtin_amdgcn_s_waitcnt(0x0F78);   // vmcnt(8)
    else
      __builtin_amdgcn_s_waitcnt(0x0F70);   // tail: drain
    FENCE(); __builtin_amdgcn_s_barrier(); FENCE();   // BARRIER2
    __builtin_amdgcn_s_setprio(1);
#pragma unroll
    for (int kk = 0; kk < 2; ++kk)
#pragma unroll
      for (int m = 0; m < 4; ++m)
#pragma unroll
        for (int n = 0; n < 2; ++n)
          acc[m][n] = __builtin_amdgcn_mfma_f32_16x16x32_f16(aLo[m * 2 + kk], bLo[n * 2 + kk],
                                                             acc[m][n], 0, 0, 0);
#pragma unroll
    for (int kk = 0; kk < 2; ++kk)
#pragma unroll
      for (int m = 0; m < 4; ++m)
#pragma unroll
        for (int n = 2; n < 4; ++n)
          acc[m][n] = __builtin_amdgcn_mfma_f32_16x16x32_f16(aLo[m * 2 + kk], bHi[(n - 2) * 2 + kk],
                                                             acc[m][n], 0, 0, 0);
    __builtin_amdgcn_s_setprio(0);
    if (t < 8) {
#pragma unroll
      for (int m = 0; m < 4; ++m)
#pragma unroll
        for (int kk = 0; kk < 2; ++kk)
          aLo[m * 2 + kk] = ldA(nb, m * 16 + m16, kk);
    }
    __builtin_amdgcn_s_setprio(1);
#pragma unroll
    for (int kk = 0; kk < 2; ++kk)
#pragma unroll
      for (int m = 0; m < 4; ++m)
#pragma unroll
        for (int n = 0; n < 2; ++n)
          acc[m + 4][n] = __builtin_amdgcn_mfma_f32_16x16x32_f16(aHi[m * 2 + kk], bLo[n * 2 + kk],
                                                                 acc[m + 4][n], 0, 0, 0);
    __builtin_amdgcn_s_setprio(0);
    if (t < 8) {
#pragma unroll
      for (int n = 0; n < 2; ++n)
#pragma unroll
        for (int kk = 0; kk < 2; ++kk)
          bLo[n * 2 + kk] = ldB(nb, brow0 + n * 16 + m16, kk);
    }
    __builtin_amdgcn_s_setprio(1);
#pragma unroll
    for (int kk = 0; kk < 2; ++kk)
#pragma unroll
      for (int m = 0; m < 4; ++m)
#pragma unroll
        for (int n = 2; n < 4; ++n)
          acc[m + 4][n] = __builtin_amdgcn_mfma_f32_16x16x32_f16(aHi[m * 2 + kk], bHi[(n - 2) * 2 + kk],
                                                                 acc[m + 4][n], 0, 0, 0);
    __builtin_amdgcn_s_setprio(0);
  }

  // ---- epilogue: plain f32 stores (no atomics) ----
  float* dst = (kz_ == 0) ? out : part + (size_t)(kz_ - 1) * NTOK_ * 768;
#pragma unroll
  for (int m = 0; m < 8; ++m) {
    const int row0 = bm0 + wr * 128 + m * 16 + quad * 4;
#pragma unroll
    for (int n = 0; n < 4; ++n) {
      const int col = bn0 + wc * 64 + n * 16 + m16;
#pragma unroll
      for (int r = 0; r < 4; ++r)
        dst[(size_t)(row0 + r) * 768 + col] = acc[m][n][r];
    }
  }
}

// ---------------------------------------------------------------------------
// Fold the 3 split-K partials into out (float4 vectorized, one pass).
// ---------------------------------------------------------------------------
__global__ __launch_bounds__(256)
void redout_kernel(float* __restrict__ o, const float* __restrict__ p) {
  const size_t i = (size_t)blockIdx.x * 256 + threadIdx.x;
  const f32x4* pv = (const f32x4*)p;
  f32x4 v = ((const f32x4*)o)[i];
  v += pv[i];
  v += pv[i + 786432];
  v += pv[i + 2 * 786432];
  ((f32x4*)o)[i] = v;
}

// ---------------------------------------------------------------------------
// MFMA fp16 GEMM (128x128, 2-phase): spec GEMM.
// A from split source (asp per-k 128-stride k<128, lat shared 192-stride);
// fused val/gate SiLU -> YH; XCD-chunked 1D grid (3bx x 32by x 12kz).
// ---------------------------------------------------------------------------
__global__ __launch_bounds__(256)
void spec_gemm_kernel(const _Float16* __restrict__ Ah, const _Float16* __restrict__ Bh,
                      const _Float16* __restrict__ A2, _Float16* __restrict__ YH) {
  __shared__ __align__(16) _Float16 sA[2][128 * 32];
  __shared__ __align__(16) _Float16 sB[2][128 * 32];
  const int Kd = 320;
  int bid = blockIdx.x;
  int xcd = bid & 7, s = bid >> 3;        // s in [0,144)
  int kz = s / 12;
  int w = s % 12;
  int bx = w % 3;
  int by = (xcd << 2) + w / 3;
  const _Float16* A0 = Ah + (size_t)kz * ((size_t)NTOK_ * 128);
  const _Float16* B0 = Bh + (size_t)kz * (384L * 320);
  const int bm0 = by * 128;
  const int bn0 = bx * 128;
  const int tid = threadIdx.x;
  const int wave = tid >> 6, lane = tid & 63;
  const int m16 = lane & 15, quad = lane >> 4;
  const int wr = (wave & 1) * 64, wc = (wave >> 1) * 64;

  f32x4 acc[4][4];
#pragma unroll
  for (int i = 0; i < 4; ++i)
#pragma unroll
    for (int j = 0; j < 4; ++j) acc[i][j] = (f32x4){0.f, 0.f, 0.f, 0.f};

  const int lin = tid * 8;
  const int lrow = lin >> 5;
  const int lblk = (lin >> 3) & 3;
  const int csw = ((lblk ^ ((lrow >> 1) & 3)) << 3);

  auto stage = [&](int k0, int kb) {
    if (k0 < 128) {
      const _Float16* gA = A0 + (size_t)(bm0 + lrow) * 128 + (k0 + csw);
      async16(gA, &sA[kb][lin]);
      async16(gA + (size_t)64 * 128, &sA[kb][lin + 2048]);
    } else {
      const _Float16* gA = A2 + (size_t)(bm0 + lrow) * 192 + (k0 - 128 + csw);
      async16(gA, &sA[kb][lin]);
      async16(gA + (size_t)64 * 192, &sA[kb][lin + 2048]);
    }
    const _Float16* gB = B0 + (size_t)(bn0 + lrow) * Kd + (k0 + csw);
    async16(gB, &sB[kb][lin]);
    async16(gB + (size_t)64 * Kd, &sB[kb][lin + 2048]);
  };

  const int niter = Kd / 32;
  stage(0, 0);
  stage(32, 1);

  for (int it = 0; it < niter; ++it) {
    if (it == niter - 1)
      __builtin_amdgcn_s_waitcnt(0x0F70);   // vmcnt(0)
    else
      __builtin_amdgcn_s_waitcnt(0x0F74);   // vmcnt(4)
    __builtin_amdgcn_s_barrier();
    asm volatile("" ::: "memory");
    const int kb = it & 1;
    half8 a0[4], b0[4];
#pragma unroll
    for (int i = 0; i < 4; ++i) {
      const int rA = wr + i * 16 + m16;
      a0[i] = *(const half8*)&sA[kb][rA * 32 + ((quad ^ ((rA >> 1) & 3)) << 3)];
    }
#pragma unroll
    for (int j = 0; j < 4; ++j) {
      const int rB = wc + j * 16 + m16;
      b0[j] = *(const half8*)&sB[kb][rB * 32 + ((quad ^ ((rB >> 1) & 3)) << 3)];
    }
#pragma unroll
    for (int i = 0; i < 4; ++i)
#pragma unroll
      for (int j = 0; j < 4; ++j)
        acc[i][j] = __builtin_amdgcn_mfma_f32_16x16x32_f16(a0[i], b0[j], acc[i][j], 0, 0, 0);
    asm volatile("" ::: "memory");
    __builtin_amdgcn_s_barrier();
    asm volatile("" ::: "memory");
    if (it + 2 < niter) stage((it + 2) * 32, kb);
  }

#pragma unroll
  for (int i = 0; i < 4; ++i) {
    const int row0 = bm0 + wr + i * 16 + quad * 4;
#pragma unroll
    for (int j = 0; j < 4; j += 2) {
      const int colv = bn0 + wc + j * 16 + m16;
      const int jout = (colv >> 5) * 16 + m16;
#pragma unroll
      for (int r = 0; r < 4; ++r) {
        float val = acc[i][j][r];
        float gg = acc[i][j + 1][r];
        float sg = gg / (1.f + __expf(-gg));
        YH[(size_t)(row0 + r) * 2304 + kz * 192 + jout] = (_Float16)(val * sg);
      }
    }
  }
}

// ---------------------------------------------------------------------------
// Scan pass A with fused causal conv (sliding 4-tap window over z_pre)
// ---------------------------------------------------------------------------
__global__ void pass_a_kernel(const float* __restrict__ zp,
                              const float* __restrict__ ck,
                              const float* __restrict__ theta_tab,
                              const float* __restrict__ score_scale,
                              const float* __restrict__ tanh_scale,
                              const float* __restrict__ slopes_sp,
                              float* __restrict__ csums) {
  const int c = blockIdx.x, k = blockIdx.y, b = blockIdx.z;
  const int tid = threadIdx.x;
  const int m = tid & 3, h = tid >> 2;
  const int chk = k * H_ + h;
  const int chs = 768 + k;
  const float theta_v = theta_tab[chk * M_ + m];
  const float ts = tanh_scale[k], ss = score_scale[k], slope = slopes_sp[k];
  float ckv[4], cks[4];
#pragma unroll
  for (int w = 0; w < 4; ++w) { ckv[w] = ck[w * ZC_ + chk]; cks[w] = ck[w * ZC_ + chs]; }
  const int l0 = c * LC_;
  float zk3 = 0.f, zk2 = 0.f, zk1 = 0.f, zs3 = 0.f, zs2 = 0.f, zs1 = 0.f;
#pragma unroll
  for (int p = 0; p < 3; ++p) {
    int lp = l0 - 3 + p;
    if (lp >= 0) {
      size_t tp = (size_t)b * L_ + lp;
      float zk = zp[tp * ZC_ + chk], zs = zp[tp * ZC_ + chs];
      if (p == 0) { zk3 = zk; zs3 = zs; }
      else if (p == 1) { zk2 = zk; zs2 = zs; }
      else { zk1 = zk; zs1 = zs; }
    }
  }
  float sre = 0.f, sim = 0.f, dacc = 0.f;
  for (int ll = 0; ll < LC_; ++ll) {
    int l = l0 + ll;
    size_t t = (size_t)b * L_ + l;
    float zk0 = zp[t * ZC_ + chk];
    float zs0 = zp[t * ZC_ + chs];
    float kv = zk3 * ckv[0] + zk2 * ckv[1] + zk1 * ckv[2] + zk0 * ckv[3];
    float sraw = zs3 * cks[0] + zs2 * cks[1] + zs1 * cks[2] + zs0 * cks[3];
    zk3 = zk2; zk2 = zk1; zk1 = zk0;
    zs3 = zs2; zs2 = zs1; zs1 = zs0;
    float lp = fminf(fmaxf(ss * sraw, -20.f), 20.f);
    float pw = __expf(lp - slope * (float)(L_ - 1 - l));
    float ph = fast_tanh(ts * kv) * theta_v;
    float kvp = kv * pw;
    sre += kvp * __cosf(ph);
    sim += kvp * __sinf(ph);
    dacc += pw;
  }
  size_t base = (((size_t)b * K_ + k) * NC_ + c) * 513;
  if (tid == 0) csums[base] = dacc;
  csums[base + 1 + h * 4 + m] = sre;
  csums[base + 1 + 256 + h * 4 + m] = sim;
}

// ---------------------------------------------------------------------------
__global__ void pass_b_kernel(const float* __restrict__ csums,
                              float* __restrict__ cpre) {
  int bk = blockIdx.y;
  int comp = blockIdx.x * 64 + threadIdx.x;
  if (comp >= 513) return;
  float run = 0.f;
  size_t base = (size_t)bk * NC_ * 513 + comp;
  for (int c = 0; c < NC_; ++c) {
    cpre[base + (size_t)c * 513] = run;
    run += csums[base + (size_t)c * 513];
  }
}

// ---------------------------------------------------------------------------
// Scan pass C: fused conv replay, contract with fp16 q, apply ns*gate,
// write fp16 into asp2[k][t][0:128] (128-stride)
// ---------------------------------------------------------------------------
__global__ void pass_c_kernel(const float* __restrict__ zp,
                              const float* __restrict__ ck,
                              const _Float16* __restrict__ qh,
                              const float* __restrict__ theta_tab,
                              const float* __restrict__ w_tab,
                              const float* __restrict__ score_scale,
                              const float* __restrict__ tanh_scale,
                              const float* __restrict__ slopes_sp,
                              const float* __restrict__ cpre,
                              const float* __restrict__ gatelin,
                              const float* __restrict__ gate_b,
                              const float* __restrict__ ns,
                              _Float16* __restrict__ asp) {
  const int c = blockIdx.x, k = blockIdx.y, b = blockIdx.z;
  const int tid = threadIdx.x;
  const int m = tid & 3, h = tid >> 2;
  const int chk = k * H_ + h;
  const int chs = 768 + k;
  size_t base = (((size_t)b * K_ + k) * NC_ + c) * 513;
  float den = cpre[base];
  float sre = cpre[base + 1 + h * 4 + m];
  float sim = cpre[base + 1 + 256 + h * 4 + m];
  const float theta_v = theta_tab[chk * M_ + m];
  const float w = w_tab[chk * M_ + m];
  const float ts = tanh_scale[k], ss = score_scale[k], slope = slopes_sp[k];
  const float nsv = ns[chk];
  const float gb = gate_b[k];
  const int kq = k >> 1;   // NREP = 2
  float ckv[4], cks[4];
#pragma unroll
  for (int ww = 0; ww < 4; ++ww) { ckv[ww] = ck[ww * ZC_ + chk]; cks[ww] = ck[ww * ZC_ + chs]; }
  const int l0 = c * LC_;
  float zk3 = 0.f, zk2 = 0.f, zk1 = 0.f, zs3 = 0.f, zs2 = 0.f, zs1 = 0.f;
#pragma unroll
  for (int p = 0; p < 3; ++p) {
    int lp = l0 - 3 + p;
    if (lp >= 0) {
      size_t tp = (size_t)b * L_ + lp;
      float zk = zp[tp * ZC_ + chk], zs = zp[tp * ZC_ + chs];
      if (p == 0) { zk3 = zk; zs3 = zs; }
      else if (p == 1) { zk2 = zk; zs2 = zs; }
      else { zk1 = zk; zs1 = zs; }
    }
  }
  const int qidx = ((kq * H_ + h) * M_ + m) * 2;
  for (int ll = 0; ll < LC_; ++ll) {
    int l = l0 + ll;
    size_t t = (size_t)b * L_ + l;
    float zk0 = zp[t * ZC_ + chk];
    float zs0 = zp[t * ZC_ + chs];
    float kv = zk3 * ckv[0] + zk2 * ckv[1] + zk1 * ckv[2] + zk0 * ckv[3];
    float sraw = zs3 * cks[0] + zs2 * cks[1] + zs1 * cks[2] + zs0 * cks[3];
    zk3 = zk2; zk2 = zk1; zk1 = zk0;
    zs3 = zs2; zs2 = zs1; zs1 = zs0;
    float lp = fminf(fmaxf(ss * sraw, -20.f), 20.f);
    float pw = __expf(lp - slope * (float)(L_ - 1 - l));
    float ph = fast_tanh(ts * kv) * theta_v;
    float kvp = kv * pw;
    sre += kvp * __cosf(ph);
    sim += kvp * __sinf(ph);
    den += pw;
    float inv = 1.f / fmaxf(den, 1e-4f);
    float s_re = sre * inv, s_im = sim * inv;
    size_t qb = t * QST_ + qidx;
    float qr = (float)qh[qb], qi = (float)qh[qb + 1];
    float tr = (s_re * qr + s_im * qi) * w;
    float ti = (s_im * qr - s_re * qi) * w;
    tr += __shfl_xor(tr, 1); tr += __shfl_xor(tr, 2);
    ti += __shfl_xor(ti, 1); ti += __shfl_xor(ti, 2);
    if (m == 0) {
      float g = 1.f / (1.f + __expf(-(gatelin[t * K_ + k] + gb))) * nsv;
      size_t ab = ((size_t)k * NTOK_ + t) * 128;
      asp[ab + h] = (_Float16)(tr * g);
      asp[ab + 64 + h] = (_Float16)(ti * g);
    }
  }
}

// ---------------------------------------------------------------------------
extern "C" void kernel_launch(void* const* d_in, const int* in_sizes, int n_in,
                              void* d_out, int out_size, void* d_ws, size_t ws_size,
                              hipStream_t stream) {
  const float* x            = (const float*)d_in[0];
  const float* W_mem        = (const float*)d_in[1];
  const float* conv_k       = (const float*)d_in[2];
  const float* W_q          = (const float*)d_in[3];
  const float* theta_d_raw  = (const float*)d_in[4];
  const float* decay_slopes = (const float*)d_in[5];
  const float* score_scale  = (const float*)d_in[6];
  const float* tanh_scale   = (const float*)d_in[7];
  const float* W_re         = (const float*)d_in[8];
  const float* W_im         = (const float*)d_in[9];
  const float* norm_scale   = (const float*)d_in[10];
  const float* gate_W       = (const float*)d_in[11];
  const float* gate_b       = (const float*)d_in[12];
  const float* skip_down_W  = (const float*)d_in[13];
  const float* skip_up_W    = (const float*)d_in[14];
  const float* highway_scale= (const float*)d_in[15];
  const float* out_W        = (const float*)d_in[16];
  float* out = (float*)d_out;
  float* ws = (float*)d_ws;

  // ---- f32 region ----
  float* theta_tab = ws;                                  // 3072
  float* w_tab     = theta_tab + 3072;                    // 3072
  float* slopes_sp = w_tab + 3072;                        // 16
  float* z_pre     = slopes_sp + 16;                      // 3,194,880
  float* gatelin   = z_pre + (size_t)NTOK_ * ZC_;         // 49,152
  float* csums     = gatelin + (size_t)NTOK_ * K_;        // 787,968
  float* cpre      = csums + (size_t)B_ * K_ * NC_ * 513; // 787,968
  _Float16* q_h    = (_Float16*)(cpre + (size_t)B_ * K_ * NC_ * 513); // 4096x3072
  _Float16* y_h    = q_h + (size_t)NTOK_ * QST_;          // 4096x2304
  float* f32_end   = (float*)(y_h + (size_t)NTOK_ * 2304);

  // split-K partials (3 x 4096 x 768 f32 = 9.44M floats) OVERLAY the dead
  // scan workspace (z_pre..q_h = 11.1M floats, consumed before outproj runs)
  float* part = z_pre;

  // ---- fp16 region ----
  _Float16* fp = (_Float16*)f32_end;
  _Float16* x_h    = fp;                fp += (size_t)NTOK_ * D_;
  _Float16* xpb_h  = fp;                fp += (size_t)XPN_ * 768;   // merged proj B (4096 rows)
  _Float16* outw_h = fp;                fp += (size_t)768 * 2304;
  _Float16* asp2_h = fp;                fp += (size_t)K_ * NTOK_ * 128;
  _Float16* bsp_h  = fp;                fp += (size_t)K_ * 384 * 320;
  _Float16* lat_h  = fp;                fp += (size_t)NTOK_ * 192;

  // fused prologue: precomp + all weight conversions (incl gate_W) + x->fp16
  prep_kernel<<<18651, 256, 0, stream>>>(x, W_mem, W_q, skip_down_W, out_W, W_re, W_im,
                                         skip_up_W, highway_scale, gate_W,
                                         theta_d_raw, decay_slopes,
                                         x_h, xpb_h, outw_h, bsp_h,
                                         theta_tab, w_tab, slopes_sp);

  // merged x-projection (256-tile, 2-barrier counted-vmcnt): q + lat + gate + z_pre
  xproj256_kernel<<<256, 512, 0, stream>>>(x_h, xpb_h, z_pre, lat_h, q_h, gatelin);

  // chunked scan (f32) with fused causal conv
  pass_a_kernel<<<dim3(NC_, K_, B_), 256, 0, stream>>>(z_pre, conv_k, theta_tab, score_scale,
                                                       tanh_scale, slopes_sp, csums);
  pass_b_kernel<<<dim3(9, B_ * K_), 64, 0, stream>>>(csums, cpre);
  pass_c_kernel<<<dim3(NC_, K_, B_), 256, 0, stream>>>(z_pre, conv_k, q_h, theta_tab, w_tab,
                                                       score_scale, tanh_scale, slopes_sp, cpre,
                                                       gatelin, gate_b, norm_scale, asp2_h);

  // batched spec GEMM (A = [asp2 per-k | lat_h shared], hs folded into bsp)
  // with fused SiLU -> y_h fp16; XCD-chunked 1D grid (3x32x12 blocks)
  spec_gemm_kernel<<<1152, 256, 0, stream>>>(asp2_h, bsp_h, lat_h, y_h);

  // out = y @ out_W: 256-tile 2-barrier counted-vmcnt, split-K=4 partials (no atomics)
  outproj256_kernel<<<192, 512, 0, stream>>>(y_h, outw_h, out, part);
  // fold partials into out
  redout_kernel<<<3072, 256, 0, stream>>>(out, part);
}

// Round 7
// 252.995 us; speedup vs baseline: 1.1274x; 1.1021x over previous
//
#include <hip/hip_runtime.h>
#include <math.h>

#define B_    2
#define L_    2048
#define D_    768
#define K_    12
#define KQ_   6
#define M_    4
#define H_    64
#define ZC_   780      // MEM + K
#define NTOK_ 4096     // B*L
#define NC_   64       // scan chunks per batch
#define LC_   32       // chunk length (L/NC)
#define QST_  3072     // q fp16 row stride
#define XPN_  4096     // merged projection N (exactly 16 x 256 tiles -> no grid tail)
#define ZOFF_ 3276     // z_pre column base in xpb

typedef __attribute__((ext_vector_type(8))) _Float16 half8;
typedef __attribute__((ext_vector_type(4))) float f32x4;

__device__ __forceinline__ float softplus_f(float x) {
  return (x > 20.f) ? x : log1pf(expf(x));
}

__device__ __forceinline__ float fast_tanh(float x) {
  float xx = fminf(fmaxf(x, -10.f), 10.f);
  float e = __expf(2.f * xx);
  return (e - 1.f) / (e + 1.f);
}

// async global->LDS 16B per lane (dest = wave-uniform base + lane*16)
__device__ __forceinline__ void async16(const _Float16* g, _Float16* l) {
  __builtin_amdgcn_global_load_lds(
      (const __attribute__((address_space(1))) unsigned int*)g,
      (__attribute__((address_space(3))) unsigned int*)l, 16, 0, 0);
}

// val/gate 16-interleave permutation for spec-B columns
__device__ __forceinline__ int permcol(int n) {
  int isg = (n >= 192) ? 1 : 0;
  int j = n - 192 * isg;
  return (j >> 4) * 32 + (isg << 4) + (j & 15);
}

#define FENCE() asm volatile("" ::: "memory")

// ---------------------------------------------------------------------------
// Transpose+convert body; optional perm + scale. Nst = store-row limit.
// ---------------------------------------------------------------------------
__device__ __forceinline__ void cvt_t_body(float (*tile)[33], int bx, int by, int kz,
                                           const float* src, long sKs, int srs,
                                           _Float16* dh, long dKs, int dst, int doff,
                                           int R, int Nact, int Nst, bool perm, float scale) {
  const float* s = src + (size_t)kz * sKs;
  _Float16* dhh = dh + (size_t)kz * dKs;
  const int kb = bx * 32;
  const int nb = by * 32;
  const int tx = threadIdx.x & 31, ty = threadIdx.x >> 5;
  for (int i = ty; i < 32; i += 8) {
    int kk = kb + i, n = nb + tx;
    tile[i][tx] = (kk < R && n < Nact) ? s[(size_t)kk * srs + n] : 0.f;
  }
  __syncthreads();
  for (int i = ty; i < 32; i += 8) {
    int n = nb + i, kk = kb + tx;
    if (kk < R && n < Nst) {
      float v = tile[tx][i] * scale;
      int dn = perm ? permcol(n) : n;
      dhh[(size_t)dn * dst + doff + kk] = (_Float16)v;
    }
  }
}

// ---------------------------------------------------------------------------
// Fused prologue, ONE dispatch:
//   blocks [0,3):          precomp (theta/w tables, slopes)
//   blocks [3,6363):       all weight conversions (incl. gate_W -> xpb cols)
//   blocks [6363,18651):   x f32->fp16
// xpb layout (rows x 768): [W_q^T 0:3072 | skd^T 3072:3264 | gate^T 3264:3276 |
//                           W_mem^T 3276:4056 | dead 4056:4096]
// ---------------------------------------------------------------------------
__global__ __launch_bounds__(256)
void prep_kernel(const float* __restrict__ x,
                 const float* __restrict__ W_mem, const float* __restrict__ W_q,
                 const float* __restrict__ skip_down_W, const float* __restrict__ out_W,
                 const float* __restrict__ W_re, const float* __restrict__ W_im,
                 const float* __restrict__ skip_up_W, const float* __restrict__ hs,
                 const float* __restrict__ gate_W,
                 const float* __restrict__ theta_d_raw, const float* __restrict__ decay,
                 _Float16* __restrict__ x_h,
                 _Float16* __restrict__ xpb_h, _Float16* __restrict__ outw_h,
                 _Float16* __restrict__ bsp_h,
                 float* __restrict__ theta_tab, float* __restrict__ w_tab,
                 float* __restrict__ slopes_sp) {
  __shared__ float tile[32][33];
  int b = blockIdx.x;
  if (b < 3) {
    int idx = b * 256 + threadIdx.x;
    if (idx < K_) slopes_sp[idx] = softplus_f(decay[idx]);
    if (idx >= K_ * H_) return;
    float td[M_], ta[M_];
#pragma unroll
    for (int m = 0; m < M_; ++m) td[m] = softplus_f(theta_d_raw[idx * M_ + m]) + 1e-4f;
    ta[0] = td[0];
#pragma unroll
    for (int m = 1; m < M_; ++m) ta[m] = ta[m - 1] + td[m];
    float total = ta[M_ - 1];
    float rs = 2.999f / total;
#pragma unroll
    for (int m = 0; m < M_; ++m) theta_tab[idx * M_ + m] = 0.001f + ta[m] * rs;
    float d0 = (ta[1] - ta[0]) * rs;
    float d1 = (ta[2] - ta[1]) * rs;
    float d2 = (ta[3] - ta[2]) * rs;
    w_tab[idx * M_ + 0] = 0.5f * d0;
    w_tab[idx * M_ + 1] = 0.5f * (d0 + d1);
    w_tab[idx * M_ + 2] = 0.5f * (d1 + d2);
    w_tab[idx * M_ + 3] = 0.5f * d2;
    return;
  }
  b -= 3;
  if (b < 6360) {
    if (b < 672) {           // W_mem -> xpb rows [3276,4056), 24x28
      cvt_t_body(tile, b % 24, b / 24, 0, W_mem, 0, ZC_, xpb_h + (size_t)ZOFF_ * 768,
                 0, 768, 0, 768, ZC_, ZC_, false, 1.f);
      return;
    }
    b -= 672;
    if (b < 2304) {          // W_q -> xpb rows [0,3072), 24x96
      cvt_t_body(tile, b % 24, b / 24, 0, W_q, 0, 3072, xpb_h, 0, 768, 0, 768,
                 3072, 3072, false, 1.f);
      return;
    }
    b -= 2304;
    if (b < 192) {           // skip_down -> xpb rows [3072,3264), 24x8
      cvt_t_body(tile, b % 24, b / 24, 0, skip_down_W, 0, 192, xpb_h + (size_t)3072 * 768,
                 0, 768, 0, 768, 192, 192, false, 1.f);
      return;
    }
    b -= 192;
    if (b < 1728) {          // out_W -> outw, 72x24
      cvt_t_body(tile, b % 72, b / 72, 0, out_W, 0, 768, outw_h, 0, 2304, 0, 2304,
                 768, 768, false, 1.f);
      return;
    }
    b -= 1728;
    if (b < 288) {           // W_re -> bsp[k][perm(n)][0:64], 2x12x12
      cvt_t_body(tile, b % 2, (b / 2) % 12, b / 24, W_re, 64L * 384, 384, bsp_h,
                 384L * 320, 320, 0, 64, 384, 384, true, 1.f);
      return;
    }
    b -= 288;
    if (b < 288) {           // W_im -> bsp[k][perm(n)][64:128]
      cvt_t_body(tile, b % 2, (b / 2) % 12, b / 24, W_im, 64L * 384, 384, bsp_h,
                 384L * 320, 320, 64, 64, 384, 384, true, 1.f);
      return;
    }
    b -= 288;
    if (b < 864) {           // skip_up slice -> bsp[k][perm(n)][128:320] scaled by hs[k]
      int kz = b / 72;
      cvt_t_body(tile, b % 6, (b / 6) % 12, kz, skip_up_W, 384, 4608, bsp_h,
                 384L * 320, 320, 128, 192, 384, 384, true, hs[kz]);
      return;
    }
    b -= 864;
    // gate_W (768x12) -> xpb rows [3264,3276), 24 blocks; store-limited to 12 rows
    cvt_t_body(tile, b, 0, 0, gate_W, 0, K_, xpb_h + (size_t)3264 * 768,
               0, 768, 0, 768, K_, K_, false, 1.f);
    return;
  }
  b -= 6360;
  size_t i = (size_t)b * 256 + threadIdx.x;
  if (i < (size_t)NTOK_ * D_) {
    x_h[i] = (_Float16)x[i];         // x -> fp16
  }
}

// ---------------------------------------------------------------------------
// 256x256-tile deep-pipelined MFMA GEMM for the merged x-projection.
// 2-barrier/K-tile counted-vmcnt schedule (see R5 notes). Grid 256 = 1/CU.
// ---------------------------------------------------------------------------
__global__ __launch_bounds__(512, 2)
void xproj256_kernel(const _Float16* __restrict__ Ah, const _Float16* __restrict__ Bh,
                     float* __restrict__ C, _Float16* __restrict__ YH,
                     _Float16* __restrict__ QH, float* __restrict__ GL) {
  // [dbuf][Mhalf/Nhalf][Khalf][row][col32]
  __shared__ __align__(16) _Float16 sA[2][2][2][128][32];
  __shared__ __align__(16) _Float16 sB[2][2][2][128][32];

  const int bid = blockIdx.x;
  const int xcd = bid & 7, s = bid >> 3;        // s in [0,32)
  const int by = xcd * 2 + (s & 1);             // 0..15
  const int bx = s >> 1;                        // 0..15
  const int bm0 = by * 256, bn0 = bx * 256;

  const int tid = threadIdx.x;
  const int lane = tid & 63;
  const int wave = tid >> 6;
  const int m16 = lane & 15, quad = lane >> 4;
  const int wr = wave >> 2;          // 0..1 A-half
  const int wc = wave & 3;           // 0..3 B col group (64 cols)
  const int bhalf = wc >> 1;         // B LDS half
  const int brow0 = (wc & 1) * 64;   // row base within B half

  f32x4 acc[8][4];
#pragma unroll
  for (int i = 0; i < 8; ++i)
#pragma unroll
    for (int j = 0; j < 4; ++j) acc[i][j] = (f32x4){0.f, 0.f, 0.f, 0.f};

  const int sr = tid >> 2;           // 0..127
  const int lb = tid & 3;            // 16B block within 32-half subtile row
  const int ssw = (sr >> 1) & 3;     // row swizzle term

  auto stageA = [&](int t, int h) {
    const int bb = t & 1;
    const _Float16* g = Ah + (size_t)(bm0 + h * 128 + sr) * 768 + t * 64
                        + ((lb ^ ssw) << 3);
    async16(g,      &sA[bb][h][0][0][0] + (size_t)tid * 8);
    async16(g + 32, &sA[bb][h][1][0][0] + (size_t)tid * 8);
  };
  auto stageB = [&](int t, int h) {
    const int bb = t & 1;
    const _Float16* g = Bh + (size_t)(bn0 + h * 128 + sr) * 768 + t * 64
                        + ((lb ^ ssw) << 3);
    async16(g,      &sB[bb][h][0][0][0] + (size_t)tid * 8);
    async16(g + 32, &sB[bb][h][1][0][0] + (size_t)tid * 8);
  };

  auto ldA = [&](int bb, int r, int kk) -> half8 {
    return *(const half8*)&sA[bb][wr][kk][r][(quad ^ ((r >> 1) & 3)) << 3];
  };
  auto ldB = [&](int bb, int r, int kk) -> half8 {
    return *(const half8*)&sB[bb][bhalf][kk][r][(quad ^ ((r >> 1) & 3)) << 3];
  };

  half8 aLo[8], aHi[8], bLo[4], bHi[4];

  stageB(0, 0); stageB(0, 1); stageA(0, 0); stageA(0, 1);
  stageB(1, 0); stageB(1, 1); stageA(1, 0); stageA(1, 1);
  __builtin_amdgcn_s_waitcnt(0x0F78);   // vmcnt(8): K-tile 0 landed, tile 1 in flight
  FENCE(); __builtin_amdgcn_s_barrier(); FENCE();
#pragma unroll
  for (int m = 0; m < 4; ++m)
#pragma unroll
    for (int kk = 0; kk < 2; ++kk) aLo[m * 2 + kk] = ldA(0, m * 16 + m16, kk);
#pragma unroll
  for (int n = 0; n < 2; ++n)
#pragma unroll
    for (int kk = 0; kk < 2; ++kk) bLo[n * 2 + kk] = ldB(0, brow0 + n * 16 + m16, kk);

  for (int t = 0; t < 12; ++t) {
    const int bb = t & 1;
    const int nb = bb ^ 1;
    // ---- R1: read bHi(t), aHi(t) from bb (last bb reads of this tile) ----
#pragma unroll
    for (int n = 0; n < 2; ++n)
#pragma unroll
      for (int kk = 0; kk < 2; ++kk)
        bHi[n * 2 + kk] = ldB(bb, brow0 + (n + 2) * 16 + m16, kk);
#pragma unroll
    for (int m = 0; m < 4; ++m)
#pragma unroll
      for (int kk = 0; kk < 2; ++kk)
        aHi[m * 2 + kk] = ldA(bb, 64 + m * 16 + m16, kk);
    FENCE(); __builtin_amdgcn_s_barrier(); FENCE();   // BARRIER1: all bb reads issued
    if (t < 10) { stageB(t + 2, 0); stageB(t + 2, 1); stageA(t + 2, 0); stageA(t + 2, 1); }
    FENCE();
    if (t < 10)
      __builtin_amdgcn_s_waitcnt(0x0F78);   // vmcnt(8): tile t+1 landed, t+2 in flight
    else
      __builtin_amdgcn_s_waitcnt(0x0F70);   // tail: drain
    FENCE(); __builtin_amdgcn_s_barrier(); FENCE();   // BARRIER2: t+1 visible block-wide
    // ---- 32 MFMAs, no further syncs; next-tile reg reads interleave ----
    __builtin_amdgcn_s_setprio(1);
#pragma unroll
    for (int kk = 0; kk < 2; ++kk)
#pragma unroll
      for (int m = 0; m < 4; ++m)
#pragma unroll
        for (int n = 0; n < 2; ++n)
          acc[m][n] = __builtin_amdgcn_mfma_f32_16x16x32_f16(aLo[m * 2 + kk], bLo[n * 2 + kk],
                                                             acc[m][n], 0, 0, 0);
#pragma unroll
    for (int kk = 0; kk < 2; ++kk)
#pragma unroll
      for (int m = 0; m < 4; ++m)
#pragma unroll
        for (int n = 2; n < 4; ++n)
          acc[m][n] = __builtin_amdgcn_mfma_f32_16x16x32_f16(aLo[m * 2 + kk], bHi[(n - 2) * 2 + kk],
                                                             acc[m][n], 0, 0, 0);
    __builtin_amdgcn_s_setprio(0);
    if (t < 11) {                          // aLo(t+1) from nb (staged, vmcnt'd)
#pragma unroll
      for (int m = 0; m < 4; ++m)
#pragma unroll
        for (int kk = 0; kk < 2; ++kk)
          aLo[m * 2 + kk] = ldA(nb, m * 16 + m16, kk);
    }
    __builtin_amdgcn_s_setprio(1);
#pragma unroll
    for (int kk = 0; kk < 2; ++kk)
#pragma unroll
      for (int m = 0; m < 4; ++m)
#pragma unroll
        for (int n = 0; n < 2; ++n)
          acc[m + 4][n] = __builtin_amdgcn_mfma_f32_16x16x32_f16(aHi[m * 2 + kk], bLo[n * 2 + kk],
                                                                 acc[m + 4][n], 0, 0, 0);
    __builtin_amdgcn_s_setprio(0);
    if (t < 11) {                          // bLo(t+1) from nb (bLo(t) consumed above)
#pragma unroll
      for (int n = 0; n < 2; ++n)
#pragma unroll
        for (int kk = 0; kk < 2; ++kk)
          bLo[n * 2 + kk] = ldB(nb, brow0 + n * 16 + m16, kk);
    }
    __builtin_amdgcn_s_setprio(1);
#pragma unroll
    for (int kk = 0; kk < 2; ++kk)
#pragma unroll
      for (int m = 0; m < 4; ++m)
#pragma unroll
        for (int n = 2; n < 4; ++n)
          acc[m + 4][n] = __builtin_amdgcn_mfma_f32_16x16x32_f16(aHi[m * 2 + kk], bHi[(n - 2) * 2 + kk],
                                                                 acc[m + 4][n], 0, 0, 0);
    __builtin_amdgcn_s_setprio(0);
  }

  // ---- epilogue (C/D layout: col=lane&15, row=quad*4+reg) ----
#pragma unroll
  for (int m = 0; m < 8; ++m) {
    const int row0 = bm0 + wr * 128 + m * 16 + quad * 4;
#pragma unroll
    for (int n = 0; n < 4; ++n) {
      const int col = bn0 + wc * 64 + n * 16 + m16;
      if (col < 3072) {
#pragma unroll
        for (int r = 0; r < 4; ++r)
          QH[(size_t)(row0 + r) * QST_ + col] = (_Float16)acc[m][n][r];
      } else if (col < 3264) {
        const int jj = col - 3072;
#pragma unroll
        for (int r = 0; r < 4; ++r)
          YH[(size_t)(row0 + r) * 192 + jj] = (_Float16)acc[m][n][r];
      } else if (col < 3276) {
        const int kk = col - 3264;
#pragma unroll
        for (int r = 0; r < 4; ++r)
          GL[(size_t)(row0 + r) * K_ + kk] = acc[m][n][r];
      } else if (col < 3276 + ZC_) {
        const int wz = col - ZOFF_;
#pragma unroll
        for (int r = 0; r < 4; ++r)
          C[(size_t)(row0 + r) * ZC_ + wz] = acc[m][n][r];
      }
    }
  }
}

// ---------------------------------------------------------------------------
// 256x256-tile out-projection GEMM: out = y @ out_W.
// Split-K=4 via partial buffers (no atomics); 2-barrier counted-vmcnt.
// ---------------------------------------------------------------------------
__global__ __launch_bounds__(512, 2)
void outproj256_kernel(const _Float16* __restrict__ Ah, const _Float16* __restrict__ Bh,
                       float* __restrict__ out, float* __restrict__ part) {
  __shared__ __align__(16) _Float16 sA[2][2][2][128][32];
  __shared__ __align__(16) _Float16 sB[2][2][2][128][32];

  const int bid = blockIdx.x;
  const int xcd = bid & 7, s = bid >> 3;        // s in [0,24)
  const int g = xcd * 24 + s;                   // contiguous per XCD
  const int by = g & 15;
  const int c = g >> 4;                         // 0..11 ; c = kz*3 + bx
  const int kz_ = c / 3, bx = c - kz_ * 3;
  const int bm0 = by * 256, bn0 = bx * 256;
  const int kt0 = kz_ * 9;                      // first BK-tile for this split

  const int tid = threadIdx.x;
  const int lane = tid & 63;
  const int wave = tid >> 6;
  const int m16 = lane & 15, quad = lane >> 4;
  const int wr = wave >> 2;
  const int wc = wave & 3;
  const int bhalf = wc >> 1;
  const int brow0 = (wc & 1) * 64;

  f32x4 acc[8][4];
#pragma unroll
  for (int i = 0; i < 8; ++i)
#pragma unroll
    for (int j = 0; j < 4; ++j) acc[i][j] = (f32x4){0.f, 0.f, 0.f, 0.f};

  const int sr = tid >> 2;
  const int lbk = tid & 3;
  const int ssw = (sr >> 1) & 3;

  auto stageA = [&](int lt, int h) {
    const int bb = lt & 1;
    const _Float16* gp = Ah + (size_t)(bm0 + h * 128 + sr) * 2304 + (kt0 + lt) * 64
                         + ((lbk ^ ssw) << 3);
    async16(gp,      &sA[bb][h][0][0][0] + (size_t)tid * 8);
    async16(gp + 32, &sA[bb][h][1][0][0] + (size_t)tid * 8);
  };
  auto stageB = [&](int lt, int h) {
    const int bb = lt & 1;
    const _Float16* gp = Bh + (size_t)(bn0 + h * 128 + sr) * 2304 + (kt0 + lt) * 64
                         + ((lbk ^ ssw) << 3);
    async16(gp,      &sB[bb][h][0][0][0] + (size_t)tid * 8);
    async16(gp + 32, &sB[bb][h][1][0][0] + (size_t)tid * 8);
  };

  auto ldA = [&](int bb, int r, int kk) -> half8 {
    return *(const half8*)&sA[bb][wr][kk][r][(quad ^ ((r >> 1) & 3)) << 3];
  };
  auto ldB = [&](int bb, int r, int kk) -> half8 {
    return *(const half8*)&sB[bb][bhalf][kk][r][(quad ^ ((r >> 1) & 3)) << 3];
  };

  half8 aLo[8], aHi[8], bLo[4], bHi[4];

  stageB(0, 0); stageB(0, 1); stageA(0, 0); stageA(0, 1);
  stageB(1, 0); stageB(1, 1); stageA(1, 0); stageA(1, 1);
  __builtin_amdgcn_s_waitcnt(0x0F78);   // vmcnt(8)
  FENCE(); __builtin_amdgcn_s_barrier(); FENCE();
#pragma unroll
  for (int m = 0; m < 4; ++m)
#pragma unroll
    for (int kk = 0; kk < 2; ++kk) aLo[m * 2 + kk] = ldA(0, m * 16 + m16, kk);
#pragma unroll
  for (int n = 0; n < 2; ++n)
#pragma unroll
    for (int kk = 0; kk < 2; ++kk) bLo[n * 2 + kk] = ldB(0, brow0 + n * 16 + m16, kk);

  for (int t = 0; t < 9; ++t) {
    const int bb = t & 1;
    const int nb = bb ^ 1;
    // R1
#pragma unroll
    for (int n = 0; n < 2; ++n)
#pragma unroll
      for (int kk = 0; kk < 2; ++kk)
        bHi[n * 2 + kk] = ldB(bb, brow0 + (n + 2) * 16 + m16, kk);
#pragma unroll
    for (int m = 0; m < 4; ++m)
#pragma unroll
      for (int kk = 0; kk < 2; ++kk)
        aHi[m * 2 + kk] = ldA(bb, 64 + m * 16 + m16, kk);
    FENCE(); __builtin_amdgcn_s_barrier(); FENCE();   // BARRIER1
    if (t < 7) { stageB(t + 2, 0); stageB(t + 2, 1); stageA(t + 2, 0); stageA(t + 2, 1); }
    FENCE();
    if (t < 7)
      __builtin_amdgcn_s_waitcnt(0x0F78);   // vmcnt(8)
    else
      __builtin_amdgcn_s_waitcnt(0x0F70);   // tail: drain
    FENCE(); __builtin_amdgcn_s_barrier(); FENCE();   // BARRIER2
    __builtin_amdgcn_s_setprio(1);
#pragma unroll
    for (int kk = 0; kk < 2; ++kk)
#pragma unroll
      for (int m = 0; m < 4; ++m)
#pragma unroll
        for (int n = 0; n < 2; ++n)
          acc[m][n] = __builtin_amdgcn_mfma_f32_16x16x32_f16(aLo[m * 2 + kk], bLo[n * 2 + kk],
                                                             acc[m][n], 0, 0, 0);
#pragma unroll
    for (int kk = 0; kk < 2; ++kk)
#pragma unroll
      for (int m = 0; m < 4; ++m)
#pragma unroll
        for (int n = 2; n < 4; ++n)
          acc[m][n] = __builtin_amdgcn_mfma_f32_16x16x32_f16(aLo[m * 2 + kk], bHi[(n - 2) * 2 + kk],
                                                             acc[m][n], 0, 0, 0);
    __builtin_amdgcn_s_setprio(0);
    if (t < 8) {
#pragma unroll
      for (int m = 0; m < 4; ++m)
#pragma unroll
        for (int kk = 0; kk < 2; ++kk)
          aLo[m * 2 + kk] = ldA(nb, m * 16 + m16, kk);
    }
    __builtin_amdgcn_s_setprio(1);
#pragma unroll
    for (int kk = 0; kk < 2; ++kk)
#pragma unroll
      for (int m = 0; m < 4; ++m)
#pragma unroll
        for (int n = 0; n < 2; ++n)
          acc[m + 4][n] = __builtin_amdgcn_mfma_f32_16x16x32_f16(aHi[m * 2 + kk], bLo[n * 2 + kk],
                                                                 acc[m + 4][n], 0, 0, 0);
    __builtin_amdgcn_s_setprio(0);
    if (t < 8) {
#pragma unroll
      for (int n = 0; n < 2; ++n)
#pragma unroll
        for (int kk = 0; kk < 2; ++kk)
          bLo[n * 2 + kk] = ldB(nb, brow0 + n * 16 + m16, kk);
    }
    __builtin_amdgcn_s_setprio(1);
#pragma unroll
    for (int kk = 0; kk < 2; ++kk)
#pragma unroll
      for (int m = 0; m < 4; ++m)
#pragma unroll
        for (int n = 2; n < 4; ++n)
          acc[m + 4][n] = __builtin_amdgcn_mfma_f32_16x16x32_f16(aHi[m * 2 + kk], bHi[(n - 2) * 2 + kk],
                                                                 acc[m + 4][n], 0, 0, 0);
    __builtin_amdgcn_s_setprio(0);
  }

  // ---- epilogue: plain f32 stores (no atomics) ----
  float* dst = (kz_ == 0) ? out : part + (size_t)(kz_ - 1) * NTOK_ * 768;
#pragma unroll
  for (int m = 0; m < 8; ++m) {
    const int row0 = bm0 + wr * 128 + m * 16 + quad * 4;
#pragma unroll
    for (int n = 0; n < 4; ++n) {
      const int col = bn0 + wc * 64 + n * 16 + m16;
#pragma unroll
      for (int r = 0; r < 4; ++r)
        dst[(size_t)(row0 + r) * 768 + col] = acc[m][n][r];
    }
  }
}

// ---------------------------------------------------------------------------
// Fold the 3 split-K partials into out (float4 vectorized, one pass).
// ---------------------------------------------------------------------------
__global__ __launch_bounds__(256)
void redout_kernel(float* __restrict__ o, const float* __restrict__ p) {
  const size_t i = (size_t)blockIdx.x * 256 + threadIdx.x;
  const f32x4* pv = (const f32x4*)p;
  f32x4 v = ((const f32x4*)o)[i];
  v += pv[i];
  v += pv[i + 786432];
  v += pv[i + 2 * 786432];
  ((f32x4*)o)[i] = v;
}

// ---------------------------------------------------------------------------
// MFMA fp16 GEMM (128x128, 2-phase): spec GEMM.
// A from split source (asp per-k 128-stride k<128, lat shared 192-stride);
// fused val/gate SiLU -> YH; XCD-chunked 1D grid (3bx x 32by x 12kz).
// ---------------------------------------------------------------------------
__global__ __launch_bounds__(256)
void spec_gemm_kernel(const _Float16* __restrict__ Ah, const _Float16* __restrict__ Bh,
                      const _Float16* __restrict__ A2, _Float16* __restrict__ YH) {
  __shared__ __align__(16) _Float16 sA[2][128 * 32];
  __shared__ __align__(16) _Float16 sB[2][128 * 32];
  const int Kd = 320;
  int bid = blockIdx.x;
  int xcd = bid & 7, s = bid >> 3;        // s in [0,144)
  int kz = s / 12;
  int w = s % 12;
  int bx = w % 3;
  int by = (xcd << 2) + w / 3;
  const _Float16* A0 = Ah + (size_t)kz * ((size_t)NTOK_ * 128);
  const _Float16* B0 = Bh + (size_t)kz * (384L * 320);
  const int bm0 = by * 128;
  const int bn0 = bx * 128;
  const int tid = threadIdx.x;
  const int wave = tid >> 6, lane = tid & 63;
  const int m16 = lane & 15, quad = lane >> 4;
  const int wr = (wave & 1) * 64, wc = (wave >> 1) * 64;

  f32x4 acc[4][4];
#pragma unroll
  for (int i = 0; i < 4; ++i)
#pragma unroll
    for (int j = 0; j < 4; ++j) acc[i][j] = (f32x4){0.f, 0.f, 0.f, 0.f};

  const int lin = tid * 8;
  const int lrow = lin >> 5;
  const int lblk = (lin >> 3) & 3;
  const int csw = ((lblk ^ ((lrow >> 1) & 3)) << 3);

  auto stage = [&](int k0, int kb) {
    if (k0 < 128) {
      const _Float16* gA = A0 + (size_t)(bm0 + lrow) * 128 + (k0 + csw);
      async16(gA, &sA[kb][lin]);
      async16(gA + (size_t)64 * 128, &sA[kb][lin + 2048]);
    } else {
      const _Float16* gA = A2 + (size_t)(bm0 + lrow) * 192 + (k0 - 128 + csw);
      async16(gA, &sA[kb][lin]);
      async16(gA + (size_t)64 * 192, &sA[kb][lin + 2048]);
    }
    const _Float16* gB = B0 + (size_t)(bn0 + lrow) * Kd + (k0 + csw);
    async16(gB, &sB[kb][lin]);
    async16(gB + (size_t)64 * Kd, &sB[kb][lin + 2048]);
  };

  const int niter = Kd / 32;
  stage(0, 0);
  stage(32, 1);

  for (int it = 0; it < niter; ++it) {
    if (it == niter - 1)
      __builtin_amdgcn_s_waitcnt(0x0F70);   // vmcnt(0)
    else
      __builtin_amdgcn_s_waitcnt(0x0F74);   // vmcnt(4)
    __builtin_amdgcn_s_barrier();
    asm volatile("" ::: "memory");
    const int kb = it & 1;
    half8 a0[4], b0[4];
#pragma unroll
    for (int i = 0; i < 4; ++i) {
      const int rA = wr + i * 16 + m16;
      a0[i] = *(const half8*)&sA[kb][rA * 32 + ((quad ^ ((rA >> 1) & 3)) << 3)];
    }
#pragma unroll
    for (int j = 0; j < 4; ++j) {
      const int rB = wc + j * 16 + m16;
      b0[j] = *(const half8*)&sB[kb][rB * 32 + ((quad ^ ((rB >> 1) & 3)) << 3)];
    }
#pragma unroll
    for (int i = 0; i < 4; ++i)
#pragma unroll
      for (int j = 0; j < 4; ++j)
        acc[i][j] = __builtin_amdgcn_mfma_f32_16x16x32_f16(a0[i], b0[j], acc[i][j], 0, 0, 0);
    asm volatile("" ::: "memory");
    __builtin_amdgcn_s_barrier();
    asm volatile("" ::: "memory");
    if (it + 2 < niter) stage((it + 2) * 32, kb);
  }

#pragma unroll
  for (int i = 0; i < 4; ++i) {
    const int row0 = bm0 + wr + i * 16 + quad * 4;
#pragma unroll
    for (int j = 0; j < 4; j += 2) {
      const int colv = bn0 + wc + j * 16 + m16;
      const int jout = (colv >> 5) * 16 + m16;
#pragma unroll
      for (int r = 0; r < 4; ++r) {
        float val = acc[i][j][r];
        float gg = acc[i][j + 1][r];
        float sg = gg / (1.f + __expf(-gg));
        YH[(size_t)(row0 + r) * 2304 + kz * 192 + jout] = (_Float16)(val * sg);
      }
    }
  }
}

// ---------------------------------------------------------------------------
// Scan pass A, wave-cooperative dedup:
//  phase A (lanes 0-31): sraw conv -> pw[l] (32 exp, was 8192); tree-sum -> dacc
//  phase B (all 256):    kv conv + tanh for 2048 (l,h) pairs, 8/thread -> LDS
//  phase C (all 256):    per-(h,m) irreducible cos/sin + accumulate
// Math per element identical to the serial version; only Σpw is tree-
// reassociated (f32, 32 positive terms: ~1e-7 rel).
// ---------------------------------------------------------------------------
__global__ __launch_bounds__(256)
void pass_a_kernel(const float* __restrict__ zp,
                   const float* __restrict__ ck,
                   const float* __restrict__ theta_tab,
                   const float* __restrict__ score_scale,
                   const float* __restrict__ tanh_scale,
                   const float* __restrict__ slopes_sp,
                   float* __restrict__ csums) {
  const int c = blockIdx.x, k = blockIdx.y, b = blockIdx.z;
  const int tid = threadIdx.x;
  const int m = tid & 3, h = tid >> 2;
  const int l0 = c * LC_;
  const size_t base = (((size_t)b * K_ + k) * NC_ + c) * 513;

  __shared__ float s_pw[LC_];
  __shared__ float s_kv[LC_][H_];
  __shared__ float s_th[LC_][H_];

  // ---- phase A: pw per token (lanes 0-31) ----
  if (tid < 32) {
    const int chs = 768 + k;
    const float ss = score_scale[k], slope = slopes_sp[k];
    float cks[4];
#pragma unroll
    for (int w = 0; w < 4; ++w) cks[w] = ck[w * ZC_ + chs];
    float sraw = 0.f;
#pragma unroll
    for (int j = 0; j < 4; ++j) {
      int lp_ = l0 + tid - 3 + j;
      float zs = (lp_ >= 0) ? zp[((size_t)b * L_ + lp_) * ZC_ + chs] : 0.f;
      sraw += zs * cks[j];
    }
    float lp = fminf(fmaxf(ss * sraw, -20.f), 20.f);
    int l = l0 + tid;
    float pw = __expf(lp - slope * (float)(L_ - 1 - l));
    s_pw[tid] = pw;
    float tot = pw;
    tot += __shfl_xor(tot, 1);
    tot += __shfl_xor(tot, 2);
    tot += __shfl_xor(tot, 4);
    tot += __shfl_xor(tot, 8);
    tot += __shfl_xor(tot, 16);
    if (tid == 0) csums[base] = tot;   // dacc
  }

  // ---- phase B: kv + tanh, 8 (l) per thread for one h ----
  {
    const int hh = tid >> 2, g = tid & 3;
    const int chkh = k * H_ + hh;
    const float ts = tanh_scale[k];
    float ckv[4];
#pragma unroll
    for (int w = 0; w < 4; ++w) ckv[w] = ck[w * ZC_ + chkh];
    const int lbase = l0 + g * 8;
    float z3 = 0.f, z2 = 0.f, z1 = 0.f;
#pragma unroll
    for (int p = 0; p < 3; ++p) {
      int lp_ = lbase - 3 + p;
      if (lp_ >= 0) {
        float z = zp[((size_t)b * L_ + lp_) * ZC_ + chkh];
        if (p == 0) z3 = z; else if (p == 1) z2 = z; else z1 = z;
      }
    }
#pragma unroll
    for (int j = 0; j < 8; ++j) {
      float z0 = zp[((size_t)b * L_ + lbase + j) * ZC_ + chkh];
      float kv = z3 * ckv[0] + z2 * ckv[1] + z1 * ckv[2] + z0 * ckv[3];
      z3 = z2; z2 = z1; z1 = z0;
      s_kv[g * 8 + j][hh] = kv;
      s_th[g * 8 + j][hh] = fast_tanh(ts * kv);
    }
  }
  __syncthreads();

  // ---- phase C: irreducible per-(h,m) work ----
  const int chk = k * H_ + h;
  const float theta_v = theta_tab[chk * M_ + m];
  float sre = 0.f, sim = 0.f;
#pragma unroll 8
  for (int ll = 0; ll < LC_; ++ll) {
    float kvp = s_kv[ll][h] * s_pw[ll];
    float ph = s_th[ll][h] * theta_v;
    sre += kvp * __cosf(ph);
    sim += kvp * __sinf(ph);
  }
  csums[base + 1 + h * 4 + m] = sre;
  csums[base + 1 + 256 + h * 4 + m] = sim;
}

// ---------------------------------------------------------------------------
__global__ void pass_b_kernel(const float* __restrict__ csums,
                              float* __restrict__ cpre) {
  int bk = blockIdx.y;
  int comp = blockIdx.x * 64 + threadIdx.x;
  if (comp >= 513) return;
  float run = 0.f;
  size_t base = (size_t)bk * NC_ * 513 + comp;
#pragma unroll 4
  for (int c = 0; c < NC_; ++c) {
    cpre[base + (size_t)c * 513] = run;
    run += csums[base + (size_t)c * 513];
  }
}

// ---------------------------------------------------------------------------
// Scan pass C, wave-cooperative dedup (same phases as pass_a) plus:
//  phase A also computes inclusive den prefix (shfl_up) -> inv[l], and the
//  sigmoid gate sg[l] (both per-(t,k), were 256x/64x redundant).
//  phase C adds the q contract + shfl reduce + gated fp16 store.
// sre/sim accumulation order identical to serial version; den prefix is
// tree-reassociated only.
// ---------------------------------------------------------------------------
__global__ __launch_bounds__(256)
void pass_c_kernel(const float* __restrict__ zp,
                   const float* __restrict__ ck,
                   const _Float16* __restrict__ qh,
                   const float* __restrict__ theta_tab,
                   const float* __restrict__ w_tab,
                   const float* __restrict__ score_scale,
                   const float* __restrict__ tanh_scale,
                   const float* __restrict__ slopes_sp,
                   const float* __restrict__ cpre,
                   const float* __restrict__ gatelin,
                   const float* __restrict__ gate_b,
                   const float* __restrict__ ns,
                   _Float16* __restrict__ asp) {
  const int c = blockIdx.x, k = blockIdx.y, b = blockIdx.z;
  const int tid = threadIdx.x;
  const int m = tid & 3, h = tid >> 2;
  const int l0 = c * LC_;
  const size_t base = (((size_t)b * K_ + k) * NC_ + c) * 513;

  __shared__ float s_pw[LC_];
  __shared__ float s_inv[LC_];
  __shared__ float s_sg[LC_];
  __shared__ float s_kv[LC_][H_];
  __shared__ float s_th[LC_][H_];

  // ---- phase A: pw, den-prefix inv, sigmoid gate (lanes 0-31) ----
  if (tid < 32) {
    const int chs = 768 + k;
    const float ss = score_scale[k], slope = slopes_sp[k];
    const float gb = gate_b[k];
    float cks[4];
#pragma unroll
    for (int w = 0; w < 4; ++w) cks[w] = ck[w * ZC_ + chs];
    float sraw = 0.f;
#pragma unroll
    for (int j = 0; j < 4; ++j) {
      int lp_ = l0 + tid - 3 + j;
      float zs = (lp_ >= 0) ? zp[((size_t)b * L_ + lp_) * ZC_ + chs] : 0.f;
      sraw += zs * cks[j];
    }
    float lp = fminf(fmaxf(ss * sraw, -20.f), 20.f);
    int l = l0 + tid;
    float pw = __expf(lp - slope * (float)(L_ - 1 - l));
    s_pw[tid] = pw;
    // inclusive prefix of pw across lanes 0..31
    float pref = pw;
#pragma unroll
    for (int off = 1; off < 32; off <<= 1) {
      float nv = __shfl_up(pref, off);
      if (tid >= off) pref += nv;
    }
    float den = cpre[base] + pref;
    s_inv[tid] = 1.f / fmaxf(den, 1e-4f);
    float gl = gatelin[((size_t)b * L_ + l) * K_ + k];
    s_sg[tid] = 1.f / (1.f + __expf(-(gl + gb)));
  }

  // ---- phase B: kv + tanh, 8 (l) per thread for one h ----
  {
    const int hh = tid >> 2, g = tid & 3;
    const int chkh = k * H_ + hh;
    const float ts = tanh_scale[k];
    float ckv[4];
#pragma unroll
    for (int w = 0; w < 4; ++w) ckv[w] = ck[w * ZC_ + chkh];
    const int lbase = l0 + g * 8;
    float z3 = 0.f, z2 = 0.f, z1 = 0.f;
#pragma unroll
    for (int p = 0; p < 3; ++p) {
      int lp_ = lbase - 3 + p;
      if (lp_ >= 0) {
        float z = zp[((size_t)b * L_ + lp_) * ZC_ + chkh];
        if (p == 0) z3 = z; else if (p == 1) z2 = z; else z1 = z;
      }
    }
#pragma unroll
    for (int j = 0; j < 8; ++j) {
      float z0 = zp[((size_t)b * L_ + lbase + j) * ZC_ + chkh];
      float kv = z3 * ckv[0] + z2 * ckv[1] + z1 * ckv[2] + z0 * ckv[3];
      z3 = z2; z2 = z1; z1 = z0;
      s_kv[g * 8 + j][hh] = kv;
      s_th[g * 8 + j][hh] = fast_tanh(ts * kv);
    }
  }
  __syncthreads();

  // ---- phase C: accumulate + contract with q ----
  const int chk = k * H_ + h;
  const float theta_v = theta_tab[chk * M_ + m];
  const float w = w_tab[chk * M_ + m];
  const float nsv = ns[chk];
  const int kq = k >> 1;   // NREP = 2
  const int qidx = ((kq * H_ + h) * M_ + m) * 2;
  float sre = cpre[base + 1 + h * 4 + m];
  float sim = cpre[base + 1 + 256 + h * 4 + m];
#pragma unroll 4
  for (int ll = 0; ll < LC_; ++ll) {
    float kvp = s_kv[ll][h] * s_pw[ll];
    float ph = s_th[ll][h] * theta_v;
    sre += kvp * __cosf(ph);
    sim += kvp * __sinf(ph);
    float inv = s_inv[ll];
    float s_re = sre * inv, s_im = sim * inv;
    size_t t = (size_t)b * L_ + l0 + ll;
    size_t qb = t * QST_ + qidx;
    float qr = (float)qh[qb], qi = (float)qh[qb + 1];
    float tr = (s_re * qr + s_im * qi) * w;
    float ti = (s_im * qr - s_re * qi) * w;
    tr += __shfl_xor(tr, 1); tr += __shfl_xor(tr, 2);
    ti += __shfl_xor(ti, 1); ti += __shfl_xor(ti, 2);
    if (m == 0) {
      float g = s_sg[ll] * nsv;
      size_t ab = ((size_t)k * NTOK_ + t) * 128;
      asp[ab + h] = (_Float16)(tr * g);
      asp[ab + 64 + h] = (_Float16)(ti * g);
    }
  }
}

// ---------------------------------------------------------------------------
extern "C" void kernel_launch(void* const* d_in, const int* in_sizes, int n_in,
                              void* d_out, int out_size, void* d_ws, size_t ws_size,
                              hipStream_t stream) {
  const float* x            = (const float*)d_in[0];
  const float* W_mem        = (const float*)d_in[1];
  const float* conv_k       = (const float*)d_in[2];
  const float* W_q          = (const float*)d_in[3];
  const float* theta_d_raw  = (const float*)d_in[4];
  const float* decay_slopes = (const float*)d_in[5];
  const float* score_scale  = (const float*)d_in[6];
  const float* tanh_scale   = (const float*)d_in[7];
  const float* W_re         = (const float*)d_in[8];
  const float* W_im         = (const float*)d_in[9];
  const float* norm_scale   = (const float*)d_in[10];
  const float* gate_W       = (const float*)d_in[11];
  const float* gate_b       = (const float*)d_in[12];
  const float* skip_down_W  = (const float*)d_in[13];
  const float* skip_up_W    = (const float*)d_in[14];
  const float* highway_scale= (const float*)d_in[15];
  const float* out_W        = (const float*)d_in[16];
  float* out = (float*)d_out;
  float* ws = (float*)d_ws;

  // ---- f32 region ----
  float* theta_tab = ws;                                  // 3072
  float* w_tab     = theta_tab + 3072;                    // 3072
  float* slopes_sp = w_tab + 3072;                        // 16
  float* z_pre     = slopes_sp + 16;                      // 3,194,880
  float* gatelin   = z_pre + (size_t)NTOK_ * ZC_;         // 49,152
  float* csums     = gatelin + (size_t)NTOK_ * K_;        // 787,968
  float* cpre      = csums + (size_t)B_ * K_ * NC_ * 513; // 787,968
  _Float16* q_h    = (_Float16*)(cpre + (size_t)B_ * K_ * NC_ * 513); // 4096x3072
  _Float16* y_h    = q_h + (size_t)NTOK_ * QST_;          // 4096x2304
  float* f32_end   = (float*)(y_h + (size_t)NTOK_ * 2304);

  // split-K partials (3 x 4096 x 768 f32 = 9.44M floats) OVERLAY the dead
  // scan workspace (z_pre..q_h = 11.1M floats, consumed before outproj runs)
  float* part = z_pre;

  // ---- fp16 region ----
  _Float16* fp = (_Float16*)f32_end;
  _Float16* x_h    = fp;                fp += (size_t)NTOK_ * D_;
  _Float16* xpb_h  = fp;                fp += (size_t)XPN_ * 768;   // merged proj B (4096 rows)
  _Float16* outw_h = fp;                fp += (size_t)768 * 2304;
  _Float16* asp2_h = fp;                fp += (size_t)K_ * NTOK_ * 128;
  _Float16* bsp_h  = fp;                fp += (size_t)K_ * 384 * 320;
  _Float16* lat_h  = fp;                fp += (size_t)NTOK_ * 192;

  // fused prologue: precomp + all weight conversions (incl gate_W) + x->fp16
  prep_kernel<<<18651, 256, 0, stream>>>(x, W_mem, W_q, skip_down_W, out_W, W_re, W_im,
                                         skip_up_W, highway_scale, gate_W,
                                         theta_d_raw, decay_slopes,
                                         x_h, xpb_h, outw_h, bsp_h,
                                         theta_tab, w_tab, slopes_sp);

  // merged x-projection (256-tile, 2-barrier counted-vmcnt): q + lat + gate + z_pre
  xproj256_kernel<<<256, 512, 0, stream>>>(x_h, xpb_h, z_pre, lat_h, q_h, gatelin);

  // chunked scan (f32), wave-cooperative dedup
  pass_a_kernel<<<dim3(NC_, K_, B_), 256, 0, stream>>>(z_pre, conv_k, theta_tab, score_scale,
                                                       tanh_scale, slopes_sp, csums);
  pass_b_kernel<<<dim3(9, B_ * K_), 64, 0, stream>>>(csums, cpre);
  pass_c_kernel<<<dim3(NC_, K_, B_), 256, 0, stream>>>(z_pre, conv_k, q_h, theta_tab, w_tab,
                                                       score_scale, tanh_scale, slopes_sp, cpre,
                                                       gatelin, gate_b, norm_scale, asp2_h);

  // batched spec GEMM (A = [asp2 per-k | lat_h shared], hs folded into bsp)
  // with fused SiLU -> y_h fp16; XCD-chunked 1D grid (3x32x12 blocks)
  spec_gemm_kernel<<<1152, 256, 0, stream>>>(asp2_h, bsp_h, lat_h, y_h);

  // out = y @ out_W: 256-tile 2-barrier counted-vmcnt, split-K=4 partials (no atomics)
  outproj256_kernel<<<192, 512, 0, stream>>>(y_h, outw_h, out, part);
  // fold partials into out
  redout_kernel<<<3072, 256, 0, stream>>>(out, part);
}

// Round 8
// 249.303 us; speedup vs baseline: 1.1441x; 1.0148x over previous
//
#include <hip/hip_runtime.h>
#include <math.h>

#define B_    2
#define L_    2048
#define D_    768
#define K_    12
#define KQ_   6
#define M_    4
#define H_    64
#define ZC_   780      // MEM + K
#define NTOK_ 4096     // B*L
#define NC_   64       // scan chunks per batch
#define LC_   32       // chunk length (L/NC)
#define QST_  3072     // q fp16 row stride
#define XPN_  4096     // merged projection N
#define ZOFF_ 3276     // z_pre column base in xpb

typedef __attribute__((ext_vector_type(8))) _Float16 half8;
typedef __attribute__((ext_vector_type(4))) float f32x4;

__device__ __forceinline__ float softplus_f(float x) {
  return (x > 20.f) ? x : log1pf(expf(x));
}

__device__ __forceinline__ float fast_tanh(float x) {
  float xx = fminf(fmaxf(x, -10.f), 10.f);
  float e = __expf(2.f * xx);
  return (e - 1.f) / (e + 1.f);
}

// async global->LDS 16B per lane (dest = wave-uniform base + lane*16)
__device__ __forceinline__ void async16(const _Float16* g, _Float16* l) {
  __builtin_amdgcn_global_load_lds(
      (const __attribute__((address_space(1))) unsigned int*)g,
      (__attribute__((address_space(3))) unsigned int*)l, 16, 0, 0);
}

// val/gate 16-interleave permutation for spec-B columns
__device__ __forceinline__ int permcol(int n) {
  int isg = (n >= 192) ? 1 : 0;
  int j = n - 192 * isg;
  return (j >> 4) * 32 + (isg << 4) + (j & 15);
}

#define FENCE() asm volatile("" ::: "memory")

// ---------------------------------------------------------------------------
// Transpose+convert body; optional perm + scale. Nst = store-row limit.
// ---------------------------------------------------------------------------
__device__ __forceinline__ void cvt_t_body(float (*tile)[33], int bx, int by, int kz,
                                           const float* src, long sKs, int srs,
                                           _Float16* dh, long dKs, int dst, int doff,
                                           int R, int Nact, int Nst, bool perm, float scale) {
  const float* s = src + (size_t)kz * sKs;
  _Float16* dhh = dh + (size_t)kz * dKs;
  const int kb = bx * 32;
  const int nb = by * 32;
  const int tx = threadIdx.x & 31, ty = threadIdx.x >> 5;
  for (int i = ty; i < 32; i += 8) {
    int kk = kb + i, n = nb + tx;
    tile[i][tx] = (kk < R && n < Nact) ? s[(size_t)kk * srs + n] : 0.f;
  }
  __syncthreads();
  for (int i = ty; i < 32; i += 8) {
    int n = nb + i, kk = kb + tx;
    if (kk < R && n < Nst) {
      float v = tile[tx][i] * scale;
      int dn = perm ? permcol(n) : n;
      dhh[(size_t)dn * dst + doff + kk] = (_Float16)v;
    }
  }
}

// ---------------------------------------------------------------------------
// Fused prologue, ONE dispatch:
//   blocks [0,3):          precomp (theta/w tables, slopes)
//   blocks [3,6363):       all weight conversions (incl. gate_W -> xpb cols)
//   blocks [6363,18651):   x f32->fp16
// xpb layout (rows x 768): [W_q^T 0:3072 | skd^T 3072:3264 | gate^T 3264:3276 |
//                           W_mem^T 3276:4056 | dead 4056:4096]
// ---------------------------------------------------------------------------
__global__ __launch_bounds__(256)
void prep_kernel(const float* __restrict__ x,
                 const float* __restrict__ W_mem, const float* __restrict__ W_q,
                 const float* __restrict__ skip_down_W, const float* __restrict__ out_W,
                 const float* __restrict__ W_re, const float* __restrict__ W_im,
                 const float* __restrict__ skip_up_W, const float* __restrict__ hs,
                 const float* __restrict__ gate_W,
                 const float* __restrict__ theta_d_raw, const float* __restrict__ decay,
                 _Float16* __restrict__ x_h,
                 _Float16* __restrict__ xpb_h, _Float16* __restrict__ outw_h,
                 _Float16* __restrict__ bsp_h,
                 float* __restrict__ theta_tab, float* __restrict__ w_tab,
                 float* __restrict__ slopes_sp) {
  __shared__ float tile[32][33];
  int b = blockIdx.x;
  if (b < 3) {
    int idx = b * 256 + threadIdx.x;
    if (idx < K_) slopes_sp[idx] = softplus_f(decay[idx]);
    if (idx >= K_ * H_) return;
    float td[M_], ta[M_];
#pragma unroll
    for (int m = 0; m < M_; ++m) td[m] = softplus_f(theta_d_raw[idx * M_ + m]) + 1e-4f;
    ta[0] = td[0];
#pragma unroll
    for (int m = 1; m < M_; ++m) ta[m] = ta[m - 1] + td[m];
    float total = ta[M_ - 1];
    float rs = 2.999f / total;
#pragma unroll
    for (int m = 0; m < M_; ++m) theta_tab[idx * M_ + m] = 0.001f + ta[m] * rs;
    float d0 = (ta[1] - ta[0]) * rs;
    float d1 = (ta[2] - ta[1]) * rs;
    float d2 = (ta[3] - ta[2]) * rs;
    w_tab[idx * M_ + 0] = 0.5f * d0;
    w_tab[idx * M_ + 1] = 0.5f * (d0 + d1);
    w_tab[idx * M_ + 2] = 0.5f * (d1 + d2);
    w_tab[idx * M_ + 3] = 0.5f * d2;
    return;
  }
  b -= 3;
  if (b < 6360) {
    if (b < 672) {           // W_mem -> xpb rows [3276,4056), 24x28
      cvt_t_body(tile, b % 24, b / 24, 0, W_mem, 0, ZC_, xpb_h + (size_t)ZOFF_ * 768,
                 0, 768, 0, 768, ZC_, ZC_, false, 1.f);
      return;
    }
    b -= 672;
    if (b < 2304) {          // W_q -> xpb rows [0,3072), 24x96
      cvt_t_body(tile, b % 24, b / 24, 0, W_q, 0, 3072, xpb_h, 0, 768, 0, 768,
                 3072, 3072, false, 1.f);
      return;
    }
    b -= 2304;
    if (b < 192) {           // skip_down -> xpb rows [3072,3264), 24x8
      cvt_t_body(tile, b % 24, b / 24, 0, skip_down_W, 0, 192, xpb_h + (size_t)3072 * 768,
                 0, 768, 0, 768, 192, 192, false, 1.f);
      return;
    }
    b -= 192;
    if (b < 1728) {          // out_W -> outw, 72x24
      cvt_t_body(tile, b % 72, b / 72, 0, out_W, 0, 768, outw_h, 0, 2304, 0, 2304,
                 768, 768, false, 1.f);
      return;
    }
    b -= 1728;
    if (b < 288) {           // W_re -> bsp[k][perm(n)][0:64], 2x12x12
      cvt_t_body(tile, b % 2, (b / 2) % 12, b / 24, W_re, 64L * 384, 384, bsp_h,
                 384L * 320, 320, 0, 64, 384, 384, true, 1.f);
      return;
    }
    b -= 288;
    if (b < 288) {           // W_im -> bsp[k][perm(n)][64:128]
      cvt_t_body(tile, b % 2, (b / 2) % 12, b / 24, W_im, 64L * 384, 384, bsp_h,
                 384L * 320, 320, 64, 64, 384, 384, true, 1.f);
      return;
    }
    b -= 288;
    if (b < 864) {           // skip_up slice -> bsp[k][perm(n)][128:320] scaled by hs[k]
      int kz = b / 72;
      cvt_t_body(tile, b % 6, (b / 6) % 12, kz, skip_up_W, 384, 4608, bsp_h,
                 384L * 320, 320, 128, 192, 384, 384, true, hs[kz]);
      return;
    }
    b -= 864;
    // gate_W (768x12) -> xpb rows [3264,3276), 24 blocks; store-limited to 12 rows
    cvt_t_body(tile, b, 0, 0, gate_W, 0, K_, xpb_h + (size_t)3264 * 768,
               0, 768, 0, 768, K_, K_, false, 1.f);
    return;
  }
  b -= 6360;
  size_t i = (size_t)b * 256 + threadIdx.x;
  if (i < (size_t)NTOK_ * D_) {
    x_h[i] = (_Float16)x[i];         // x -> fp16
  }
}

// ---------------------------------------------------------------------------
// x-projection GEMM, 256x128 tile, BK=32, 48 KiB LDS -> 2 blocks/CU
// co-resident (grid 512 = one round). Mechanism: restore inter-block wave
// overlap (m114) -- during one block's barrier/vmcnt stalls the other block's
// waves feed the MFMA pipe. 8 waves 4Mx2N, acc 4x4/wave, <=128 VGPR enforced.
// 2-barrier/K-tile counted-vmcnt: per tile {BARRIER1 -> stage(t+2): 3 async16
// -> vmcnt(3) -> BARRIER2 -> 16 MFMA interleaved with t+1 frag reads}.
// Frags single-set: b[0,1] reloaded after MFMA n=0,1; a[*],b[2,3] after rest.
// ---------------------------------------------------------------------------
__global__ __launch_bounds__(512, 4)
void xprojk_kernel(const _Float16* __restrict__ Ah, const _Float16* __restrict__ Bh,
                   float* __restrict__ C, _Float16* __restrict__ YH,
                   _Float16* __restrict__ QH, float* __restrict__ GL) {
  __shared__ __align__(16) _Float16 sA[2][2][128][32];   // [dbuf][Mhalf][row][32]
  __shared__ __align__(16) _Float16 sB[2][128][32];      // [dbuf][row][32]

  // XCD chunking: 512 = 8 xcd x 64; xcd owns by in {2x,2x+1} for all 32 bx
  const int bid = blockIdx.x;
  const int xcd = bid & 7, s = bid >> 3;    // s in [0,64)
  const int by = xcd * 2 + (s & 1);         // 0..15
  const int bx = s >> 1;                    // 0..31
  const int bm0 = by * 256, bn0 = bx * 128;

  const int tid = threadIdx.x;
  const int lane = tid & 63;
  const int wave = tid >> 6;
  const int m16 = lane & 15, quad = lane >> 4;
  const int wr = wave >> 1;     // 0..3 (64-row group)
  const int wc = wave & 1;      // 0..1 (64-col group)

  f32x4 acc[4][4];
#pragma unroll
  for (int i = 0; i < 4; ++i)
#pragma unroll
    for (int j = 0; j < 4; ++j) acc[i][j] = (f32x4){0.f, 0.f, 0.f, 0.f};

  const int sr4 = tid >> 2;        // 0..127 staging row
  const int lb = tid & 3;          // 16B block within 32-half row
  const int ssw = (sr4 >> 1) & 3;  // row swizzle term

  auto stageA = [&](int t) {       // 2 async16: both M-halves
    const int bb = t & 1;
    const _Float16* g = Ah + (size_t)(bm0 + sr4) * 768 + t * 32 + ((lb ^ ssw) << 3);
    async16(g,                     &sA[bb][0][0][0] + (size_t)tid * 8);
    async16(g + (size_t)128 * 768, &sA[bb][1][0][0] + (size_t)tid * 8);
  };
  auto stageB = [&](int t) {       // 1 async16
    const int bb = t & 1;
    const _Float16* g = Bh + (size_t)(bn0 + sr4) * 768 + t * 32 + ((lb ^ ssw) << 3);
    async16(g, &sB[bb][0][0] + (size_t)tid * 8);
  };

  auto ldA = [&](int bb, int r) -> half8 {   // r in [0,256)
    return *(const half8*)&sA[bb][r >> 7][r & 127][(quad ^ ((r >> 1) & 3)) << 3];
  };
  auto ldB = [&](int bb, int r) -> half8 {   // r in [0,128)
    return *(const half8*)&sB[bb][r][(quad ^ ((r >> 1) & 3)) << 3];
  };

  half8 a[4], b[4];

  // prologue: stage tiles 0,1 (issue order B,A,A per tile -> 3 loads/tile)
  stageB(0); stageA(0);
  stageB(1); stageA(1);
  __builtin_amdgcn_s_waitcnt(0x0F73);   // vmcnt(3): tile0 landed, tile1 in flight
  FENCE(); __builtin_amdgcn_s_barrier(); FENCE();
#pragma unroll
  for (int m = 0; m < 4; ++m) a[m] = ldA(0, wr * 64 + m * 16 + m16);
#pragma unroll
  for (int n = 0; n < 4; ++n) b[n] = ldB(0, wc * 64 + n * 16 + m16);

  for (int t = 0; t < 24; ++t) {
    const int bb = t & 1;
    const int nb = bb ^ 1;
    FENCE(); __builtin_amdgcn_s_barrier(); FENCE();   // BARRIER1: bb reads (t's frags) done
    if (t < 22) { stageB(t + 2); stageA(t + 2); }     // into bb
    FENCE();
    if (t < 22)
      __builtin_amdgcn_s_waitcnt(0x0F73);   // vmcnt(3): tile t+1 landed, t+2 in flight
    else
      __builtin_amdgcn_s_waitcnt(0x0F70);   // tail: drain
    FENCE(); __builtin_amdgcn_s_barrier(); FENCE();   // BARRIER2: t+1 visible block-wide
    __builtin_amdgcn_s_setprio(1);
#pragma unroll
    for (int m = 0; m < 4; ++m)
#pragma unroll
      for (int n = 0; n < 2; ++n)
        acc[m][n] = __builtin_amdgcn_mfma_f32_16x16x32_f16(a[m], b[n], acc[m][n], 0, 0, 0);
    __builtin_amdgcn_s_setprio(0);
    if (t < 23) {                    // b[0,1] fully consumed -> reload for t+1
#pragma unroll
      for (int n = 0; n < 2; ++n) b[n] = ldB(nb, wc * 64 + n * 16 + m16);
    }
    __builtin_amdgcn_s_setprio(1);
#pragma unroll
    for (int m = 0; m < 4; ++m)
#pragma unroll
      for (int n = 2; n < 4; ++n)
        acc[m][n] = __builtin_amdgcn_mfma_f32_16x16x32_f16(a[m], b[n], acc[m][n], 0, 0, 0);
    __builtin_amdgcn_s_setprio(0);
    if (t < 23) {                    // a[*], b[2,3] consumed -> reload for t+1
#pragma unroll
      for (int m = 0; m < 4; ++m) a[m] = ldA(nb, wr * 64 + m * 16 + m16);
#pragma unroll
      for (int n = 2; n < 4; ++n) b[n] = ldB(nb, wc * 64 + n * 16 + m16);
    }
  }

  // ---- epilogue (C/D layout: col=lane&15, row=quad*4+reg) ----
#pragma unroll
  for (int m = 0; m < 4; ++m) {
    const int row0 = bm0 + wr * 64 + m * 16 + quad * 4;
#pragma unroll
    for (int n = 0; n < 4; ++n) {
      const int col = bn0 + wc * 64 + n * 16 + m16;
      if (col < 3072) {
#pragma unroll
        for (int r = 0; r < 4; ++r)
          QH[(size_t)(row0 + r) * QST_ + col] = (_Float16)acc[m][n][r];
      } else if (col < 3264) {
        const int jj = col - 3072;
#pragma unroll
        for (int r = 0; r < 4; ++r)
          YH[(size_t)(row0 + r) * 192 + jj] = (_Float16)acc[m][n][r];
      } else if (col < 3276) {
        const int kk = col - 3264;
#pragma unroll
        for (int r = 0; r < 4; ++r)
          GL[(size_t)(row0 + r) * K_ + kk] = acc[m][n][r];
      } else if (col < 3276 + ZC_) {
        const int wz = col - ZOFF_;
#pragma unroll
        for (int r = 0; r < 4; ++r)
          C[(size_t)(row0 + r) * ZC_ + wz] = acc[m][n][r];
      }
    }
  }
}

// ---------------------------------------------------------------------------
// 256x256-tile out-projection GEMM: out = y @ out_W.
// Split-K=4 via partial buffers (no atomics); 2-barrier counted-vmcnt.
// ---------------------------------------------------------------------------
__global__ __launch_bounds__(512, 2)
void outproj256_kernel(const _Float16* __restrict__ Ah, const _Float16* __restrict__ Bh,
                       float* __restrict__ out, float* __restrict__ part) {
  __shared__ __align__(16) _Float16 sA[2][2][2][128][32];
  __shared__ __align__(16) _Float16 sB[2][2][2][128][32];

  const int bid = blockIdx.x;
  const int xcd = bid & 7, s = bid >> 3;        // s in [0,24)
  const int g = xcd * 24 + s;                   // contiguous per XCD
  const int by = g & 15;
  const int c = g >> 4;                         // 0..11 ; c = kz*3 + bx
  const int kz_ = c / 3, bx = c - kz_ * 3;
  const int bm0 = by * 256, bn0 = bx * 256;
  const int kt0 = kz_ * 9;                      // first BK-tile for this split

  const int tid = threadIdx.x;
  const int lane = tid & 63;
  const int wave = tid >> 6;
  const int m16 = lane & 15, quad = lane >> 4;
  const int wr = wave >> 2;
  const int wc = wave & 3;
  const int bhalf = wc >> 1;
  const int brow0 = (wc & 1) * 64;

  f32x4 acc[8][4];
#pragma unroll
  for (int i = 0; i < 8; ++i)
#pragma unroll
    for (int j = 0; j < 4; ++j) acc[i][j] = (f32x4){0.f, 0.f, 0.f, 0.f};

  const int sr = tid >> 2;
  const int lbk = tid & 3;
  const int ssw = (sr >> 1) & 3;

  auto stageA = [&](int lt, int h) {
    const int bb = lt & 1;
    const _Float16* gp = Ah + (size_t)(bm0 + h * 128 + sr) * 2304 + (kt0 + lt) * 64
                         + ((lbk ^ ssw) << 3);
    async16(gp,      &sA[bb][h][0][0][0] + (size_t)tid * 8);
    async16(gp + 32, &sA[bb][h][1][0][0] + (size_t)tid * 8);
  };
  auto stageB = [&](int lt, int h) {
    const int bb = lt & 1;
    const _Float16* gp = Bh + (size_t)(bn0 + h * 128 + sr) * 2304 + (kt0 + lt) * 64
                         + ((lbk ^ ssw) << 3);
    async16(gp,      &sB[bb][h][0][0][0] + (size_t)tid * 8);
    async16(gp + 32, &sB[bb][h][1][0][0] + (size_t)tid * 8);
  };

  auto ldA = [&](int bb, int r, int kk) -> half8 {
    return *(const half8*)&sA[bb][wr][kk][r][(quad ^ ((r >> 1) & 3)) << 3];
  };
  auto ldB = [&](int bb, int r, int kk) -> half8 {
    return *(const half8*)&sB[bb][bhalf][kk][r][(quad ^ ((r >> 1) & 3)) << 3];
  };

  half8 aLo[8], aHi[8], bLo[4], bHi[4];

  stageB(0, 0); stageB(0, 1); stageA(0, 0); stageA(0, 1);
  stageB(1, 0); stageB(1, 1); stageA(1, 0); stageA(1, 1);
  __builtin_amdgcn_s_waitcnt(0x0F78);   // vmcnt(8)
  FENCE(); __builtin_amdgcn_s_barrier(); FENCE();
#pragma unroll
  for (int m = 0; m < 4; ++m)
#pragma unroll
    for (int kk = 0; kk < 2; ++kk) aLo[m * 2 + kk] = ldA(0, m * 16 + m16, kk);
#pragma unroll
  for (int n = 0; n < 2; ++n)
#pragma unroll
    for (int kk = 0; kk < 2; ++kk) bLo[n * 2 + kk] = ldB(0, brow0 + n * 16 + m16, kk);

  for (int t = 0; t < 9; ++t) {
    const int bb = t & 1;
    const int nb = bb ^ 1;
    // R1
#pragma unroll
    for (int n = 0; n < 2; ++n)
#pragma unroll
      for (int kk = 0; kk < 2; ++kk)
        bHi[n * 2 + kk] = ldB(bb, brow0 + (n + 2) * 16 + m16, kk);
#pragma unroll
    for (int m = 0; m < 4; ++m)
#pragma unroll
      for (int kk = 0; kk < 2; ++kk)
        aHi[m * 2 + kk] = ldA(bb, 64 + m * 16 + m16, kk);
    FENCE(); __builtin_amdgcn_s_barrier(); FENCE();   // BARRIER1
    if (t < 7) { stageB(t + 2, 0); stageB(t + 2, 1); stageA(t + 2, 0); stageA(t + 2, 1); }
    FENCE();
    if (t < 7)
      __builtin_amdgcn_s_waitcnt(0x0F78);   // vmcnt(8)
    else
      __builtin_amdgcn_s_waitcnt(0x0F70);   // tail: drain
    FENCE(); __builtin_amdgcn_s_barrier(); FENCE();   // BARRIER2
    __builtin_amdgcn_s_setprio(1);
#pragma unroll
    for (int kk = 0; kk < 2; ++kk)
#pragma unroll
      for (int m = 0; m < 4; ++m)
#pragma unroll
        for (int n = 0; n < 2; ++n)
          acc[m][n] = __builtin_amdgcn_mfma_f32_16x16x32_f16(aLo[m * 2 + kk], bLo[n * 2 + kk],
                                                             acc[m][n], 0, 0, 0);
#pragma unroll
    for (int kk = 0; kk < 2; ++kk)
#pragma unroll
      for (int m = 0; m < 4; ++m)
#pragma unroll
        for (int n = 2; n < 4; ++n)
          acc[m][n] = __builtin_amdgcn_mfma_f32_16x16x32_f16(aLo[m * 2 + kk], bHi[(n - 2) * 2 + kk],
                                                             acc[m][n], 0, 0, 0);
    __builtin_amdgcn_s_setprio(0);
    if (t < 8) {
#pragma unroll
      for (int m = 0; m < 4; ++m)
#pragma unroll
        for (int kk = 0; kk < 2; ++kk)
          aLo[m * 2 + kk] = ldA(nb, m * 16 + m16, kk);
    }
    __builtin_amdgcn_s_setprio(1);
#pragma unroll
    for (int kk = 0; kk < 2; ++kk)
#pragma unroll
      for (int m = 0; m < 4; ++m)
#pragma unroll
        for (int n = 0; n < 2; ++n)
          acc[m + 4][n] = __builtin_amdgcn_mfma_f32_16x16x32_f16(aHi[m * 2 + kk], bLo[n * 2 + kk],
                                                                 acc[m + 4][n], 0, 0, 0);
    __builtin_amdgcn_s_setprio(0);
    if (t < 8) {
#pragma unroll
      for (int n = 0; n < 2; ++n)
#pragma unroll
        for (int kk = 0; kk < 2; ++kk)
          bLo[n * 2 + kk] = ldB(nb, brow0 + n * 16 + m16, kk);
    }
    __builtin_amdgcn_s_setprio(1);
#pragma unroll
    for (int kk = 0; kk < 2; ++kk)
#pragma unroll
      for (int m = 0; m < 4; ++m)
#pragma unroll
        for (int n = 2; n < 4; ++n)
          acc[m + 4][n] = __builtin_amdgcn_mfma_f32_16x16x32_f16(aHi[m * 2 + kk], bHi[(n - 2) * 2 + kk],
                                                                 acc[m + 4][n], 0, 0, 0);
    __builtin_amdgcn_s_setprio(0);
  }

  // ---- epilogue: plain f32 stores (no atomics) ----
  float* dst = (kz_ == 0) ? out : part + (size_t)(kz_ - 1) * NTOK_ * 768;
#pragma unroll
  for (int m = 0; m < 8; ++m) {
    const int row0 = bm0 + wr * 128 + m * 16 + quad * 4;
#pragma unroll
    for (int n = 0; n < 4; ++n) {
      const int col = bn0 + wc * 64 + n * 16 + m16;
#pragma unroll
      for (int r = 0; r < 4; ++r)
        dst[(size_t)(row0 + r) * 768 + col] = acc[m][n][r];
    }
  }
}

// ---------------------------------------------------------------------------
// Fold the 3 split-K partials into out (float4 vectorized, one pass).
// ---------------------------------------------------------------------------
__global__ __launch_bounds__(256)
void redout_kernel(float* __restrict__ o, const float* __restrict__ p) {
  const size_t i = (size_t)blockIdx.x * 256 + threadIdx.x;
  const f32x4* pv = (const f32x4*)p;
  f32x4 v = ((const f32x4*)o)[i];
  v += pv[i];
  v += pv[i + 786432];
  v += pv[i + 2 * 786432];
  ((f32x4*)o)[i] = v;
}

// ---------------------------------------------------------------------------
// MFMA fp16 GEMM (128x128, 2-phase): spec GEMM.
// A from split source (asp per-k 128-stride k<128, lat shared 192-stride);
// fused val/gate SiLU -> YH; XCD-chunked 1D grid (3bx x 32by x 12kz).
// ---------------------------------------------------------------------------
__global__ __launch_bounds__(256)
void spec_gemm_kernel(const _Float16* __restrict__ Ah, const _Float16* __restrict__ Bh,
                      const _Float16* __restrict__ A2, _Float16* __restrict__ YH) {
  __shared__ __align__(16) _Float16 sA[2][128 * 32];
  __shared__ __align__(16) _Float16 sB[2][128 * 32];
  const int Kd = 320;
  int bid = blockIdx.x;
  int xcd = bid & 7, s = bid >> 3;        // s in [0,144)
  int kz = s / 12;
  int w = s % 12;
  int bx = w % 3;
  int by = (xcd << 2) + w / 3;
  const _Float16* A0 = Ah + (size_t)kz * ((size_t)NTOK_ * 128);
  const _Float16* B0 = Bh + (size_t)kz * (384L * 320);
  const int bm0 = by * 128;
  const int bn0 = bx * 128;
  const int tid = threadIdx.x;
  const int wave = tid >> 6, lane = tid & 63;
  const int m16 = lane & 15, quad = lane >> 4;
  const int wr = (wave & 1) * 64, wc = (wave >> 1) * 64;

  f32x4 acc[4][4];
#pragma unroll
  for (int i = 0; i < 4; ++i)
#pragma unroll
    for (int j = 0; j < 4; ++j) acc[i][j] = (f32x4){0.f, 0.f, 0.f, 0.f};

  const int lin = tid * 8;
  const int lrow = lin >> 5;
  const int lblk = (lin >> 3) & 3;
  const int csw = ((lblk ^ ((lrow >> 1) & 3)) << 3);

  auto stage = [&](int k0, int kb) {
    if (k0 < 128) {
      const _Float16* gA = A0 + (size_t)(bm0 + lrow) * 128 + (k0 + csw);
      async16(gA, &sA[kb][lin]);
      async16(gA + (size_t)64 * 128, &sA[kb][lin + 2048]);
    } else {
      const _Float16* gA = A2 + (size_t)(bm0 + lrow) * 192 + (k0 - 128 + csw);
      async16(gA, &sA[kb][lin]);
      async16(gA + (size_t)64 * 192, &sA[kb][lin + 2048]);
    }
    const _Float16* gB = B0 + (size_t)(bn0 + lrow) * Kd + (k0 + csw);
    async16(gB, &sB[kb][lin]);
    async16(gB + (size_t)64 * Kd, &sB[kb][lin + 2048]);
  };

  const int niter = Kd / 32;
  stage(0, 0);
  stage(32, 1);

  for (int it = 0; it < niter; ++it) {
    if (it == niter - 1)
      __builtin_amdgcn_s_waitcnt(0x0F70);   // vmcnt(0)
    else
      __builtin_amdgcn_s_waitcnt(0x0F74);   // vmcnt(4)
    __builtin_amdgcn_s_barrier();
    asm volatile("" ::: "memory");
    const int kb = it & 1;
    half8 a0[4], b0[4];
#pragma unroll
    for (int i = 0; i < 4; ++i) {
      const int rA = wr + i * 16 + m16;
      a0[i] = *(const half8*)&sA[kb][rA * 32 + ((quad ^ ((rA >> 1) & 3)) << 3)];
    }
#pragma unroll
    for (int j = 0; j < 4; ++j) {
      const int rB = wc + j * 16 + m16;
      b0[j] = *(const half8*)&sB[kb][rB * 32 + ((quad ^ ((rB >> 1) & 3)) << 3)];
    }
#pragma unroll
    for (int i = 0; i < 4; ++i)
#pragma unroll
      for (int j = 0; j < 4; ++j)
        acc[i][j] = __builtin_amdgcn_mfma_f32_16x16x32_f16(a0[i], b0[j], acc[i][j], 0, 0, 0);
    asm volatile("" ::: "memory");
    __builtin_amdgcn_s_barrier();
    asm volatile("" ::: "memory");
    if (it + 2 < niter) stage((it + 2) * 32, kb);
  }

#pragma unroll
  for (int i = 0; i < 4; ++i) {
    const int row0 = bm0 + wr + i * 16 + quad * 4;
#pragma unroll
    for (int j = 0; j < 4; j += 2) {
      const int colv = bn0 + wc + j * 16 + m16;
      const int jout = (colv >> 5) * 16 + m16;
#pragma unroll
      for (int r = 0; r < 4; ++r) {
        float val = acc[i][j][r];
        float gg = acc[i][j + 1][r];
        float sg = gg / (1.f + __expf(-gg));
        YH[(size_t)(row0 + r) * 2304 + kz * 192 + jout] = (_Float16)(val * sg);
      }
    }
  }
}

// ---------------------------------------------------------------------------
// Scan pass A, wave-cooperative dedup:
//  phase A (lanes 0-31): sraw conv -> pw[l]; tree-sum -> dacc
//  phase B (all 256):    kv conv + tanh for 2048 (l,h) pairs -> LDS
//  phase C (all 256):    per-(h,m) irreducible cos/sin + accumulate
// ---------------------------------------------------------------------------
__global__ __launch_bounds__(256)
void pass_a_kernel(const float* __restrict__ zp,
                   const float* __restrict__ ck,
                   const float* __restrict__ theta_tab,
                   const float* __restrict__ score_scale,
                   const float* __restrict__ tanh_scale,
                   const float* __restrict__ slopes_sp,
                   float* __restrict__ csums) {
  const int c = blockIdx.x, k = blockIdx.y, b = blockIdx.z;
  const int tid = threadIdx.x;
  const int m = tid & 3, h = tid >> 2;
  const int l0 = c * LC_;
  const size_t base = (((size_t)b * K_ + k) * NC_ + c) * 513;

  __shared__ float s_pw[LC_];
  __shared__ float s_kv[LC_][H_];
  __shared__ float s_th[LC_][H_];

  // ---- phase A: pw per token (lanes 0-31) ----
  if (tid < 32) {
    const int chs = 768 + k;
    const float ss = score_scale[k], slope = slopes_sp[k];
    float cks[4];
#pragma unroll
    for (int w = 0; w < 4; ++w) cks[w] = ck[w * ZC_ + chs];
    float sraw = 0.f;
#pragma unroll
    for (int j = 0; j < 4; ++j) {
      int lp_ = l0 + tid - 3 + j;
      float zs = (lp_ >= 0) ? zp[((size_t)b * L_ + lp_) * ZC_ + chs] : 0.f;
      sraw += zs * cks[j];
    }
    float lp = fminf(fmaxf(ss * sraw, -20.f), 20.f);
    int l = l0 + tid;
    float pw = __expf(lp - slope * (float)(L_ - 1 - l));
    s_pw[tid] = pw;
    float tot = pw;
    tot += __shfl_xor(tot, 1);
    tot += __shfl_xor(tot, 2);
    tot += __shfl_xor(tot, 4);
    tot += __shfl_xor(tot, 8);
    tot += __shfl_xor(tot, 16);
    if (tid == 0) csums[base] = tot;   // dacc
  }

  // ---- phase B: kv + tanh, 8 (l) per thread for one h ----
  {
    const int hh = tid >> 2, g = tid & 3;
    const int chkh = k * H_ + hh;
    const float ts = tanh_scale[k];
    float ckv[4];
#pragma unroll
    for (int w = 0; w < 4; ++w) ckv[w] = ck[w * ZC_ + chkh];
    const int lbase = l0 + g * 8;
    float z3 = 0.f, z2 = 0.f, z1 = 0.f;
#pragma unroll
    for (int p = 0; p < 3; ++p) {
      int lp_ = lbase - 3 + p;
      if (lp_ >= 0) {
        float z = zp[((size_t)b * L_ + lp_) * ZC_ + chkh];
        if (p == 0) z3 = z; else if (p == 1) z2 = z; else z1 = z;
      }
    }
#pragma unroll
    for (int j = 0; j < 8; ++j) {
      float z0 = zp[((size_t)b * L_ + lbase + j) * ZC_ + chkh];
      float kv = z3 * ckv[0] + z2 * ckv[1] + z1 * ckv[2] + z0 * ckv[3];
      z3 = z2; z2 = z1; z1 = z0;
      s_kv[g * 8 + j][hh] = kv;
      s_th[g * 8 + j][hh] = fast_tanh(ts * kv);
    }
  }
  __syncthreads();

  // ---- phase C: irreducible per-(h,m) work ----
  const int chk = k * H_ + h;
  const float theta_v = theta_tab[chk * M_ + m];
  float sre = 0.f, sim = 0.f;
#pragma unroll 8
  for (int ll = 0; ll < LC_; ++ll) {
    float kvp = s_kv[ll][h] * s_pw[ll];
    float ph = s_th[ll][h] * theta_v;
    sre += kvp * __cosf(ph);
    sim += kvp * __sinf(ph);
  }
  csums[base + 1 + h * 4 + m] = sre;
  csums[base + 1 + 256 + h * 4 + m] = sim;
}

// ---------------------------------------------------------------------------
__global__ void pass_b_kernel(const float* __restrict__ csums,
                              float* __restrict__ cpre) {
  int bk = blockIdx.y;
  int comp = blockIdx.x * 64 + threadIdx.x;
  if (comp >= 513) return;
  float run = 0.f;
  size_t base = (size_t)bk * NC_ * 513 + comp;
#pragma unroll 4
  for (int c = 0; c < NC_; ++c) {
    cpre[base + (size_t)c * 513] = run;
    run += csums[base + (size_t)c * 513];
  }
}

// ---------------------------------------------------------------------------
// Scan pass C, wave-cooperative dedup (phases as pass_a) + den prefix,
// sigmoid gate, q contract, gated fp16 store.
// ---------------------------------------------------------------------------
__global__ __launch_bounds__(256)
void pass_c_kernel(const float* __restrict__ zp,
                   const float* __restrict__ ck,
                   const _Float16* __restrict__ qh,
                   const float* __restrict__ theta_tab,
                   const float* __restrict__ w_tab,
                   const float* __restrict__ score_scale,
                   const float* __restrict__ tanh_scale,
                   const float* __restrict__ slopes_sp,
                   const float* __restrict__ cpre,
                   const float* __restrict__ gatelin,
                   const float* __restrict__ gate_b,
                   const float* __restrict__ ns,
                   _Float16* __restrict__ asp) {
  const int c = blockIdx.x, k = blockIdx.y, b = blockIdx.z;
  const int tid = threadIdx.x;
  const int m = tid & 3, h = tid >> 2;
  const int l0 = c * LC_;
  const size_t base = (((size_t)b * K_ + k) * NC_ + c) * 513;

  __shared__ float s_pw[LC_];
  __shared__ float s_inv[LC_];
  __shared__ float s_sg[LC_];
  __shared__ float s_kv[LC_][H_];
  __shared__ float s_th[LC_][H_];

  // ---- phase A: pw, den-prefix inv, sigmoid gate (lanes 0-31) ----
  if (tid < 32) {
    const int chs = 768 + k;
    const float ss = score_scale[k], slope = slopes_sp[k];
    const float gb = gate_b[k];
    float cks[4];
#pragma unroll
    for (int w = 0; w < 4; ++w) cks[w] = ck[w * ZC_ + chs];
    float sraw = 0.f;
#pragma unroll
    for (int j = 0; j < 4; ++j) {
      int lp_ = l0 + tid - 3 + j;
      float zs = (lp_ >= 0) ? zp[((size_t)b * L_ + lp_) * ZC_ + chs] : 0.f;
      sraw += zs * cks[j];
    }
    float lp = fminf(fmaxf(ss * sraw, -20.f), 20.f);
    int l = l0 + tid;
    float pw = __expf(lp - slope * (float)(L_ - 1 - l));
    s_pw[tid] = pw;
    // inclusive prefix of pw across lanes 0..31
    float pref = pw;
#pragma unroll
    for (int off = 1; off < 32; off <<= 1) {
      float nv = __shfl_up(pref, off);
      if (tid >= off) pref += nv;
    }
    float den = cpre[base] + pref;
    s_inv[tid] = 1.f / fmaxf(den, 1e-4f);
    float gl = gatelin[((size_t)b * L_ + l) * K_ + k];
    s_sg[tid] = 1.f / (1.f + __expf(-(gl + gb)));
  }

  // ---- phase B: kv + tanh, 8 (l) per thread for one h ----
  {
    const int hh = tid >> 2, g = tid & 3;
    const int chkh = k * H_ + hh;
    const float ts = tanh_scale[k];
    float ckv[4];
#pragma unroll
    for (int w = 0; w < 4; ++w) ckv[w] = ck[w * ZC_ + chkh];
    const int lbase = l0 + g * 8;
    float z3 = 0.f, z2 = 0.f, z1 = 0.f;
#pragma unroll
    for (int p = 0; p < 3; ++p) {
      int lp_ = lbase - 3 + p;
      if (lp_ >= 0) {
        float z = zp[((size_t)b * L_ + lp_) * ZC_ + chkh];
        if (p == 0) z3 = z; else if (p == 1) z2 = z; else z1 = z;
      }
    }
#pragma unroll
    for (int j = 0; j < 8; ++j) {
      float z0 = zp[((size_t)b * L_ + lbase + j) * ZC_ + chkh];
      float kv = z3 * ckv[0] + z2 * ckv[1] + z1 * ckv[2] + z0 * ckv[3];
      z3 = z2; z2 = z1; z1 = z0;
      s_kv[g * 8 + j][hh] = kv;
      s_th[g * 8 + j][hh] = fast_tanh(ts * kv);
    }
  }
  __syncthreads();

  // ---- phase C: accumulate + contract with q ----
  const int chk = k * H_ + h;
  const float theta_v = theta_tab[chk * M_ + m];
  const float w = w_tab[chk * M_ + m];
  const float nsv = ns[chk];
  const int kq = k >> 1;   // NREP = 2
  const int qidx = ((kq * H_ + h) * M_ + m) * 2;
  float sre = cpre[base + 1 + h * 4 + m];
  float sim = cpre[base + 1 + 256 + h * 4 + m];
#pragma unroll 4
  for (int ll = 0; ll < LC_; ++ll) {
    float kvp = s_kv[ll][h] * s_pw[ll];
    float ph = s_th[ll][h] * theta_v;
    sre += kvp * __cosf(ph);
    sim += kvp * __sinf(ph);
    float inv = s_inv[ll];
    float s_re = sre * inv, s_im = sim * inv;
    size_t t = (size_t)b * L_ + l0 + ll;
    size_t qb = t * QST_ + qidx;
    float qr = (float)qh[qb], qi = (float)qh[qb + 1];
    float tr = (s_re * qr + s_im * qi) * w;
    float ti = (s_im * qr - s_re * qi) * w;
    tr += __shfl_xor(tr, 1); tr += __shfl_xor(tr, 2);
    ti += __shfl_xor(ti, 1); ti += __shfl_xor(ti, 2);
    if (m == 0) {
      float g = s_sg[ll] * nsv;
      size_t ab = ((size_t)k * NTOK_ + t) * 128;
      asp[ab + h] = (_Float16)(tr * g);
      asp[ab + 64 + h] = (_Float16)(ti * g);
    }
  }
}

// ---------------------------------------------------------------------------
extern "C" void kernel_launch(void* const* d_in, const int* in_sizes, int n_in,
                              void* d_out, int out_size, void* d_ws, size_t ws_size,
                              hipStream_t stream) {
  const float* x            = (const float*)d_in[0];
  const float* W_mem        = (const float*)d_in[1];
  const float* conv_k       = (const float*)d_in[2];
  const float* W_q          = (const float*)d_in[3];
  const float* theta_d_raw  = (const float*)d_in[4];
  const float* decay_slopes = (const float*)d_in[5];
  const float* score_scale  = (const float*)d_in[6];
  const float* tanh_scale   = (const float*)d_in[7];
  const float* W_re         = (const float*)d_in[8];
  const float* W_im         = (const float*)d_in[9];
  const float* norm_scale   = (const float*)d_in[10];
  const float* gate_W       = (const float*)d_in[11];
  const float* gate_b       = (const float*)d_in[12];
  const float* skip_down_W  = (const float*)d_in[13];
  const float* skip_up_W    = (const float*)d_in[14];
  const float* highway_scale= (const float*)d_in[15];
  const float* out_W        = (const float*)d_in[16];
  float* out = (float*)d_out;
  float* ws = (float*)d_ws;

  // ---- f32 region ----
  float* theta_tab = ws;                                  // 3072
  float* w_tab     = theta_tab + 3072;                    // 3072
  float* slopes_sp = w_tab + 3072;                        // 16
  float* z_pre     = slopes_sp + 16;                      // 3,194,880
  float* gatelin   = z_pre + (size_t)NTOK_ * ZC_;         // 49,152
  float* csums     = gatelin + (size_t)NTOK_ * K_;        // 787,968
  float* cpre      = csums + (size_t)B_ * K_ * NC_ * 513; // 787,968
  _Float16* q_h    = (_Float16*)(cpre + (size_t)B_ * K_ * NC_ * 513); // 4096x3072
  _Float16* y_h    = q_h + (size_t)NTOK_ * QST_;          // 4096x2304
  float* f32_end   = (float*)(y_h + (size_t)NTOK_ * 2304);

  // split-K partials (3 x 4096 x 768 f32 = 9.44M floats) OVERLAY the dead
  // scan workspace (z_pre..q_h = 11.1M floats, consumed before outproj runs)
  float* part = z_pre;

  // ---- fp16 region ----
  _Float16* fp = (_Float16*)f32_end;
  _Float16* x_h    = fp;                fp += (size_t)NTOK_ * D_;
  _Float16* xpb_h  = fp;                fp += (size_t)XPN_ * 768;   // merged proj B (4096 rows)
  _Float16* outw_h = fp;                fp += (size_t)768 * 2304;
  _Float16* asp2_h = fp;                fp += (size_t)K_ * NTOK_ * 128;
  _Float16* bsp_h  = fp;                fp += (size_t)K_ * 384 * 320;
  _Float16* lat_h  = fp;                fp += (size_t)NTOK_ * 192;

  // fused prologue: precomp + all weight conversions (incl gate_W) + x->fp16
  prep_kernel<<<18651, 256, 0, stream>>>(x, W_mem, W_q, skip_down_W, out_W, W_re, W_im,
                                         skip_up_W, highway_scale, gate_W,
                                         theta_d_raw, decay_slopes,
                                         x_h, xpb_h, outw_h, bsp_h,
                                         theta_tab, w_tab, slopes_sp);

  // merged x-projection (256x128 tile, BK=32, 2 blocks/CU): q + lat + gate + z_pre
  xprojk_kernel<<<512, 512, 0, stream>>>(x_h, xpb_h, z_pre, lat_h, q_h, gatelin);

  // chunked scan (f32), wave-cooperative dedup
  pass_a_kernel<<<dim3(NC_, K_, B_), 256, 0, stream>>>(z_pre, conv_k, theta_tab, score_scale,
                                                       tanh_scale, slopes_sp, csums);
  pass_b_kernel<<<dim3(9, B_ * K_), 64, 0, stream>>>(csums, cpre);
  pass_c_kernel<<<dim3(NC_, K_, B_), 256, 0, stream>>>(z_pre, conv_k, q_h, theta_tab, w_tab,
                                                       score_scale, tanh_scale, slopes_sp, cpre,
                                                       gatelin, gate_b, norm_scale, asp2_h);

  // batched spec GEMM (A = [asp2 per-k | lat_h shared], hs folded into bsp)
  // with fused SiLU -> y_h fp16; XCD-chunked 1D grid (3x32x12 blocks)
  spec_gemm_kernel<<<1152, 256, 0, stream>>>(asp2_h, bsp_h, lat_h, y_h);

  // out = y @ out_W: 256-tile 2-barrier counted-vmcnt, split-K=4 partials (no atomics)
  outproj256_kernel<<<192, 512, 0, stream>>>(y_h, outw_h, out, part);
  // fold partials into out
  redout_kernel<<<3072, 256, 0, stream>>>(out, part);
}

// Round 9
// 245.370 us; speedup vs baseline: 1.1624x; 1.0160x over previous
//
#include <hip/hip_runtime.h>
#include <math.h>

#define B_    2
#define L_    2048
#define D_    768
#define K_    12
#define KQ_   6
#define M_    4
#define H_    64
#define ZC_   780      // MEM + K
#define NTOK_ 4096     // B*L
#define NC_   64       // scan chunks per batch
#define LC_   32       // chunk length (L/NC)
#define QST_  3072     // q fp16 row stride
#define XPN_  4096     // merged projection N
#define ZOFF_ 3276     // z_pre column base in xpb

typedef __attribute__((ext_vector_type(8))) _Float16 half8;
typedef __attribute__((ext_vector_type(4))) float f32x4;

__device__ __forceinline__ float softplus_f(float x) {
  return (x > 20.f) ? x : log1pf(expf(x));
}

__device__ __forceinline__ float fast_tanh(float x) {
  float xx = fminf(fmaxf(x, -10.f), 10.f);
  float e = __expf(2.f * xx);
  return (e - 1.f) / (e + 1.f);
}

// async global->LDS 16B per lane (dest = wave-uniform base + lane*16)
__device__ __forceinline__ void async16(const _Float16* g, _Float16* l) {
  __builtin_amdgcn_global_load_lds(
      (const __attribute__((address_space(1))) unsigned int*)g,
      (__attribute__((address_space(3))) unsigned int*)l, 16, 0, 0);
}

// val/gate 16-interleave permutation for spec-B columns
__device__ __forceinline__ int permcol(int n) {
  int isg = (n >= 192) ? 1 : 0;
  int j = n - 192 * isg;
  return (j >> 4) * 32 + (isg << 4) + (j & 15);
}

#define FENCE() asm volatile("" ::: "memory")

// ---------------------------------------------------------------------------
// Transpose+convert body; optional perm + scale. Nst = store-row limit.
// ---------------------------------------------------------------------------
__device__ __forceinline__ void cvt_t_body(float (*tile)[33], int bx, int by, int kz,
                                           const float* src, long sKs, int srs,
                                           _Float16* dh, long dKs, int dst, int doff,
                                           int R, int Nact, int Nst, bool perm, float scale) {
  const float* s = src + (size_t)kz * sKs;
  _Float16* dhh = dh + (size_t)kz * dKs;
  const int kb = bx * 32;
  const int nb = by * 32;
  const int tx = threadIdx.x & 31, ty = threadIdx.x >> 5;
  for (int i = ty; i < 32; i += 8) {
    int kk = kb + i, n = nb + tx;
    tile[i][tx] = (kk < R && n < Nact) ? s[(size_t)kk * srs + n] : 0.f;
  }
  __syncthreads();
  for (int i = ty; i < 32; i += 8) {
    int n = nb + i, kk = kb + tx;
    if (kk < R && n < Nst) {
      float v = tile[tx][i] * scale;
      int dn = perm ? permcol(n) : n;
      dhh[(size_t)dn * dst + doff + kk] = (_Float16)v;
    }
  }
}

// ---------------------------------------------------------------------------
// Fused prologue, ONE dispatch:
//   blocks [0,3):          precomp (theta/w tables, slopes)
//   blocks [3,6363):       all weight conversions (incl. gate_W -> xpb cols)
//   blocks [6363,18651):   x f32->fp16
// xpb layout (rows x 768): [W_q^T 0:3072 | skd^T 3072:3264 | gate^T 3264:3276 |
//                           W_mem^T 3276:4056 | dead 4056:4096]
// ---------------------------------------------------------------------------
__global__ __launch_bounds__(256)
void prep_kernel(const float* __restrict__ x,
                 const float* __restrict__ W_mem, const float* __restrict__ W_q,
                 const float* __restrict__ skip_down_W, const float* __restrict__ out_W,
                 const float* __restrict__ W_re, const float* __restrict__ W_im,
                 const float* __restrict__ skip_up_W, const float* __restrict__ hs,
                 const float* __restrict__ gate_W,
                 const float* __restrict__ theta_d_raw, const float* __restrict__ decay,
                 _Float16* __restrict__ x_h,
                 _Float16* __restrict__ xpb_h, _Float16* __restrict__ outw_h,
                 _Float16* __restrict__ bsp_h,
                 float* __restrict__ theta_tab, float* __restrict__ w_tab,
                 float* __restrict__ slopes_sp) {
  __shared__ float tile[32][33];
  int b = blockIdx.x;
  if (b < 3) {
    int idx = b * 256 + threadIdx.x;
    if (idx < K_) slopes_sp[idx] = softplus_f(decay[idx]);
    if (idx >= K_ * H_) return;
    float td[M_], ta[M_];
#pragma unroll
    for (int m = 0; m < M_; ++m) td[m] = softplus_f(theta_d_raw[idx * M_ + m]) + 1e-4f;
    ta[0] = td[0];
#pragma unroll
    for (int m = 1; m < M_; ++m) ta[m] = ta[m - 1] + td[m];
    float total = ta[M_ - 1];
    float rs = 2.999f / total;
#pragma unroll
    for (int m = 0; m < M_; ++m) theta_tab[idx * M_ + m] = 0.001f + ta[m] * rs;
    float d0 = (ta[1] - ta[0]) * rs;
    float d1 = (ta[2] - ta[1]) * rs;
    float d2 = (ta[3] - ta[2]) * rs;
    w_tab[idx * M_ + 0] = 0.5f * d0;
    w_tab[idx * M_ + 1] = 0.5f * (d0 + d1);
    w_tab[idx * M_ + 2] = 0.5f * (d1 + d2);
    w_tab[idx * M_ + 3] = 0.5f * d2;
    return;
  }
  b -= 3;
  if (b < 6360) {
    if (b < 672) {           // W_mem -> xpb rows [3276,4056), 24x28
      cvt_t_body(tile, b % 24, b / 24, 0, W_mem, 0, ZC_, xpb_h + (size_t)ZOFF_ * 768,
                 0, 768, 0, 768, ZC_, ZC_, false, 1.f);
      return;
    }
    b -= 672;
    if (b < 2304) {          // W_q -> xpb rows [0,3072), 24x96
      cvt_t_body(tile, b % 24, b / 24, 0, W_q, 0, 3072, xpb_h, 0, 768, 0, 768,
                 3072, 3072, false, 1.f);
      return;
    }
    b -= 2304;
    if (b < 192) {           // skip_down -> xpb rows [3072,3264), 24x8
      cvt_t_body(tile, b % 24, b / 24, 0, skip_down_W, 0, 192, xpb_h + (size_t)3072 * 768,
                 0, 768, 0, 768, 192, 192, false, 1.f);
      return;
    }
    b -= 192;
    if (b < 1728) {          // out_W -> outw, 72x24
      cvt_t_body(tile, b % 72, b / 72, 0, out_W, 0, 768, outw_h, 0, 2304, 0, 2304,
                 768, 768, false, 1.f);
      return;
    }
    b -= 1728;
    if (b < 288) {           // W_re -> bsp[k][perm(n)][0:64], 2x12x12
      cvt_t_body(tile, b % 2, (b / 2) % 12, b / 24, W_re, 64L * 384, 384, bsp_h,
                 384L * 320, 320, 0, 64, 384, 384, true, 1.f);
      return;
    }
    b -= 288;
    if (b < 288) {           // W_im -> bsp[k][perm(n)][64:128]
      cvt_t_body(tile, b % 2, (b / 2) % 12, b / 24, W_im, 64L * 384, 384, bsp_h,
                 384L * 320, 320, 64, 64, 384, 384, true, 1.f);
      return;
    }
    b -= 288;
    if (b < 864) {           // skip_up slice -> bsp[k][perm(n)][128:320] scaled by hs[k]
      int kz = b / 72;
      cvt_t_body(tile, b % 6, (b / 6) % 12, kz, skip_up_W, 384, 4608, bsp_h,
                 384L * 320, 320, 128, 192, 384, 384, true, hs[kz]);
      return;
    }
    b -= 864;
    // gate_W (768x12) -> xpb rows [3264,3276), 24 blocks; store-limited to 12 rows
    cvt_t_body(tile, b, 0, 0, gate_W, 0, K_, xpb_h + (size_t)3264 * 768,
               0, 768, 0, 768, K_, K_, false, 1.f);
    return;
  }
  b -= 6360;
  size_t i = (size_t)b * 256 + threadIdx.x;
  if (i < (size_t)NTOK_ * D_) {
    x_h[i] = (_Float16)x[i];         // x -> fp16
  }
}

// ---------------------------------------------------------------------------
// x-projection GEMM, 256x128 tile, BK=32, 48 KiB LDS -> 2 blocks/CU
// co-resident (grid 512 = one round). 2-barrier/K-tile counted-vmcnt.
// ---------------------------------------------------------------------------
__global__ __launch_bounds__(512, 4)
void xprojk_kernel(const _Float16* __restrict__ Ah, const _Float16* __restrict__ Bh,
                   float* __restrict__ C, _Float16* __restrict__ YH,
                   _Float16* __restrict__ QH, float* __restrict__ GL) {
  __shared__ __align__(16) _Float16 sA[2][2][128][32];   // [dbuf][Mhalf][row][32]
  __shared__ __align__(16) _Float16 sB[2][128][32];      // [dbuf][row][32]

  // XCD chunking: 512 = 8 xcd x 64; xcd owns by in {2x,2x+1} for all 32 bx
  const int bid = blockIdx.x;
  const int xcd = bid & 7, s = bid >> 3;    // s in [0,64)
  const int by = xcd * 2 + (s & 1);         // 0..15
  const int bx = s >> 1;                    // 0..31
  const int bm0 = by * 256, bn0 = bx * 128;

  const int tid = threadIdx.x;
  const int lane = tid & 63;
  const int wave = tid >> 6;
  const int m16 = lane & 15, quad = lane >> 4;
  const int wr = wave >> 1;     // 0..3 (64-row group)
  const int wc = wave & 1;      // 0..1 (64-col group)

  f32x4 acc[4][4];
#pragma unroll
  for (int i = 0; i < 4; ++i)
#pragma unroll
    for (int j = 0; j < 4; ++j) acc[i][j] = (f32x4){0.f, 0.f, 0.f, 0.f};

  const int sr4 = tid >> 2;        // 0..127 staging row
  const int lb = tid & 3;          // 16B block within 32-half row
  const int ssw = (sr4 >> 1) & 3;  // row swizzle term

  auto stageA = [&](int t) {       // 2 async16: both M-halves
    const int bb = t & 1;
    const _Float16* g = Ah + (size_t)(bm0 + sr4) * 768 + t * 32 + ((lb ^ ssw) << 3);
    async16(g,                     &sA[bb][0][0][0] + (size_t)tid * 8);
    async16(g + (size_t)128 * 768, &sA[bb][1][0][0] + (size_t)tid * 8);
  };
  auto stageB = [&](int t) {       // 1 async16
    const int bb = t & 1;
    const _Float16* g = Bh + (size_t)(bn0 + sr4) * 768 + t * 32 + ((lb ^ ssw) << 3);
    async16(g, &sB[bb][0][0] + (size_t)tid * 8);
  };

  auto ldA = [&](int bb, int r) -> half8 {   // r in [0,256)
    return *(const half8*)&sA[bb][r >> 7][r & 127][(quad ^ ((r >> 1) & 3)) << 3];
  };
  auto ldB = [&](int bb, int r) -> half8 {   // r in [0,128)
    return *(const half8*)&sB[bb][r][(quad ^ ((r >> 1) & 3)) << 3];
  };

  half8 a[4], b[4];

  stageB(0); stageA(0);
  stageB(1); stageA(1);
  __builtin_amdgcn_s_waitcnt(0x0F73);   // vmcnt(3): tile0 landed, tile1 in flight
  FENCE(); __builtin_amdgcn_s_barrier(); FENCE();
#pragma unroll
  for (int m = 0; m < 4; ++m) a[m] = ldA(0, wr * 64 + m * 16 + m16);
#pragma unroll
  for (int n = 0; n < 4; ++n) b[n] = ldB(0, wc * 64 + n * 16 + m16);

  for (int t = 0; t < 24; ++t) {
    const int nb = (t & 1) ^ 1;
    FENCE(); __builtin_amdgcn_s_barrier(); FENCE();   // BARRIER1: bb reads done
    if (t < 22) { stageB(t + 2); stageA(t + 2); }
    FENCE();
    if (t < 22)
      __builtin_amdgcn_s_waitcnt(0x0F73);   // vmcnt(3): tile t+1 landed
    else
      __builtin_amdgcn_s_waitcnt(0x0F70);   // tail: drain
    FENCE(); __builtin_amdgcn_s_barrier(); FENCE();   // BARRIER2
    __builtin_amdgcn_s_setprio(1);
#pragma unroll
    for (int m = 0; m < 4; ++m)
#pragma unroll
      for (int n = 0; n < 2; ++n)
        acc[m][n] = __builtin_amdgcn_mfma_f32_16x16x32_f16(a[m], b[n], acc[m][n], 0, 0, 0);
    __builtin_amdgcn_s_setprio(0);
    if (t < 23) {
#pragma unroll
      for (int n = 0; n < 2; ++n) b[n] = ldB(nb, wc * 64 + n * 16 + m16);
    }
    __builtin_amdgcn_s_setprio(1);
#pragma unroll
    for (int m = 0; m < 4; ++m)
#pragma unroll
      for (int n = 2; n < 4; ++n)
        acc[m][n] = __builtin_amdgcn_mfma_f32_16x16x32_f16(a[m], b[n], acc[m][n], 0, 0, 0);
    __builtin_amdgcn_s_setprio(0);
    if (t < 23) {
#pragma unroll
      for (int m = 0; m < 4; ++m) a[m] = ldA(nb, wr * 64 + m * 16 + m16);
#pragma unroll
      for (int n = 2; n < 4; ++n) b[n] = ldB(nb, wc * 64 + n * 16 + m16);
    }
  }

  // ---- epilogue (C/D layout: col=lane&15, row=quad*4+reg) ----
#pragma unroll
  for (int m = 0; m < 4; ++m) {
    const int row0 = bm0 + wr * 64 + m * 16 + quad * 4;
#pragma unroll
    for (int n = 0; n < 4; ++n) {
      const int col = bn0 + wc * 64 + n * 16 + m16;
      if (col < 3072) {
#pragma unroll
        for (int r = 0; r < 4; ++r)
          QH[(size_t)(row0 + r) * QST_ + col] = (_Float16)acc[m][n][r];
      } else if (col < 3264) {
        const int jj = col - 3072;
#pragma unroll
        for (int r = 0; r < 4; ++r)
          YH[(size_t)(row0 + r) * 192 + jj] = (_Float16)acc[m][n][r];
      } else if (col < 3276) {
        const int kk = col - 3264;
#pragma unroll
        for (int r = 0; r < 4; ++r)
          GL[(size_t)(row0 + r) * K_ + kk] = acc[m][n][r];
      } else if (col < 3276 + ZC_) {
        const int wz = col - ZOFF_;
#pragma unroll
        for (int r = 0; r < 4; ++r)
          C[(size_t)(row0 + r) * ZC_ + wz] = acc[m][n][r];
      }
    }
  }
}

// ---------------------------------------------------------------------------
// out-projection GEMM, xprojk-style: 256x128 tile, BK=32, 48 KiB LDS,
// split-K=4 (K=2304 -> 576/split = 18 tiles). Grid 384 = 8 xcd x 48, ALL
// co-resident (2 blocks/CU x 256 CU = 512 slots). NO atomics: kz 0 -> out,
// kz 1-3 -> partial buffers folded by redout. 2-barrier counted-vmcnt.
// ---------------------------------------------------------------------------
__global__ __launch_bounds__(512, 4)
void outprojk_kernel(const _Float16* __restrict__ Ah, const _Float16* __restrict__ Bh,
                     float* __restrict__ out, float* __restrict__ part) {
  __shared__ __align__(16) _Float16 sA[2][2][128][32];   // [dbuf][Mhalf][row][32]
  __shared__ __align__(16) _Float16 sB[2][128][32];

  // 384 = 8 xcd x 48; xcd owns by in {2x,2x+1} for all (bx,kz)
  const int bid = blockIdx.x;
  const int xcd = bid & 7, s = bid >> 3;    // s in [0,48)
  const int by = xcd * 2 + (s & 1);         // 0..15
  const int rest = s >> 1;                  // 0..23
  const int bx = rest % 6;                  // 0..5
  const int kz = rest / 6;                  // 0..3
  const int bm0 = by * 256, bn0 = bx * 128;
  const int kt0 = kz * 18;                  // first BK32-tile of this split

  const int tid = threadIdx.x;
  const int lane = tid & 63;
  const int wave = tid >> 6;
  const int m16 = lane & 15, quad = lane >> 4;
  const int wr = wave >> 1;     // 0..3
  const int wc = wave & 1;      // 0..1

  f32x4 acc[4][4];
#pragma unroll
  for (int i = 0; i < 4; ++i)
#pragma unroll
    for (int j = 0; j < 4; ++j) acc[i][j] = (f32x4){0.f, 0.f, 0.f, 0.f};

  const int sr4 = tid >> 2;
  const int lb = tid & 3;
  const int ssw = (sr4 >> 1) & 3;

  auto stageA = [&](int t) {
    const int bb = t & 1;
    const _Float16* g = Ah + (size_t)(bm0 + sr4) * 2304 + (kt0 + t) * 32 + ((lb ^ ssw) << 3);
    async16(g,                      &sA[bb][0][0][0] + (size_t)tid * 8);
    async16(g + (size_t)128 * 2304, &sA[bb][1][0][0] + (size_t)tid * 8);
  };
  auto stageB = [&](int t) {
    const int bb = t & 1;
    const _Float16* g = Bh + (size_t)(bn0 + sr4) * 2304 + (kt0 + t) * 32 + ((lb ^ ssw) << 3);
    async16(g, &sB[bb][0][0] + (size_t)tid * 8);
  };

  auto ldA = [&](int bb, int r) -> half8 {
    return *(const half8*)&sA[bb][r >> 7][r & 127][(quad ^ ((r >> 1) & 3)) << 3];
  };
  auto ldB = [&](int bb, int r) -> half8 {
    return *(const half8*)&sB[bb][r][(quad ^ ((r >> 1) & 3)) << 3];
  };

  half8 a[4], b[4];

  stageB(0); stageA(0);
  stageB(1); stageA(1);
  __builtin_amdgcn_s_waitcnt(0x0F73);   // vmcnt(3)
  FENCE(); __builtin_amdgcn_s_barrier(); FENCE();
#pragma unroll
  for (int m = 0; m < 4; ++m) a[m] = ldA(0, wr * 64 + m * 16 + m16);
#pragma unroll
  for (int n = 0; n < 4; ++n) b[n] = ldB(0, wc * 64 + n * 16 + m16);

  for (int t = 0; t < 18; ++t) {
    const int nb = (t & 1) ^ 1;
    FENCE(); __builtin_amdgcn_s_barrier(); FENCE();   // BARRIER1
    if (t < 16) { stageB(t + 2); stageA(t + 2); }
    FENCE();
    if (t < 16)
      __builtin_amdgcn_s_waitcnt(0x0F73);   // vmcnt(3)
    else
      __builtin_amdgcn_s_waitcnt(0x0F70);   // tail: drain
    FENCE(); __builtin_amdgcn_s_barrier(); FENCE();   // BARRIER2
    __builtin_amdgcn_s_setprio(1);
#pragma unroll
    for (int m = 0; m < 4; ++m)
#pragma unroll
      for (int n = 0; n < 2; ++n)
        acc[m][n] = __builtin_amdgcn_mfma_f32_16x16x32_f16(a[m], b[n], acc[m][n], 0, 0, 0);
    __builtin_amdgcn_s_setprio(0);
    if (t < 17) {
#pragma unroll
      for (int n = 0; n < 2; ++n) b[n] = ldB(nb, wc * 64 + n * 16 + m16);
    }
    __builtin_amdgcn_s_setprio(1);
#pragma unroll
    for (int m = 0; m < 4; ++m)
#pragma unroll
      for (int n = 2; n < 4; ++n)
        acc[m][n] = __builtin_amdgcn_mfma_f32_16x16x32_f16(a[m], b[n], acc[m][n], 0, 0, 0);
    __builtin_amdgcn_s_setprio(0);
    if (t < 17) {
#pragma unroll
      for (int m = 0; m < 4; ++m) a[m] = ldA(nb, wr * 64 + m * 16 + m16);
#pragma unroll
      for (int n = 2; n < 4; ++n) b[n] = ldB(nb, wc * 64 + n * 16 + m16);
    }
  }

  // ---- epilogue: plain f32 stores (no atomics) ----
  float* dst = (kz == 0) ? out : part + (size_t)(kz - 1) * NTOK_ * 768;
#pragma unroll
  for (int m = 0; m < 4; ++m) {
    const int row0 = bm0 + wr * 64 + m * 16 + quad * 4;
#pragma unroll
    for (int n = 0; n < 4; ++n) {
      const int col = bn0 + wc * 64 + n * 16 + m16;
#pragma unroll
      for (int r = 0; r < 4; ++r)
        dst[(size_t)(row0 + r) * 768 + col] = acc[m][n][r];
    }
  }
}

// ---------------------------------------------------------------------------
// Fold the 3 split-K partials into out (float4 vectorized, one pass).
// ---------------------------------------------------------------------------
__global__ __launch_bounds__(256)
void redout_kernel(float* __restrict__ o, const float* __restrict__ p) {
  const size_t i = (size_t)blockIdx.x * 256 + threadIdx.x;
  const f32x4* pv = (const f32x4*)p;
  f32x4 v = ((const f32x4*)o)[i];
  v += pv[i];
  v += pv[i + 786432];
  v += pv[i + 2 * 786432];
  ((f32x4*)o)[i] = v;
}

// ---------------------------------------------------------------------------
// spec GEMM (128x128, BK=32, K=320): 2-barrier counted-vmcnt schedule.
// A from split source (asp per-k 128-stride k<128, lat shared 192-stride);
// fused val/gate SiLU -> YH; XCD-chunked 1D grid (3bx x 32by x 12kz).
// Per tile: BARRIER1 -> stage(t+2) (4 async16) -> vmcnt(4) -> BARRIER2 ->
// 16 MFMA with consume-then-overwrite frag reloads of t+1.
// ---------------------------------------------------------------------------
__global__ __launch_bounds__(256)
void spec_gemm_kernel(const _Float16* __restrict__ Ah, const _Float16* __restrict__ Bh,
                      const _Float16* __restrict__ A2, _Float16* __restrict__ YH) {
  __shared__ __align__(16) _Float16 sA[2][128 * 32];
  __shared__ __align__(16) _Float16 sB[2][128 * 32];
  const int Kd = 320;
  int bid = blockIdx.x;
  int xcd = bid & 7, s = bid >> 3;        // s in [0,144)
  int kz = s / 12;
  int w = s % 12;
  int bx = w % 3;
  int by = (xcd << 2) + w / 3;
  const _Float16* A0 = Ah + (size_t)kz * ((size_t)NTOK_ * 128);
  const _Float16* B0 = Bh + (size_t)kz * (384L * 320);
  const int bm0 = by * 128;
  const int bn0 = bx * 128;
  const int tid = threadIdx.x;
  const int wave = tid >> 6, lane = tid & 63;
  const int m16 = lane & 15, quad = lane >> 4;
  const int wr = (wave & 1) * 64, wc = (wave >> 1) * 64;

  f32x4 acc[4][4];
#pragma unroll
  for (int i = 0; i < 4; ++i)
#pragma unroll
    for (int j = 0; j < 4; ++j) acc[i][j] = (f32x4){0.f, 0.f, 0.f, 0.f};

  const int lin = tid * 8;
  const int lrow = lin >> 5;               // 0..63
  const int lblk = (lin >> 3) & 3;
  const int csw = ((lblk ^ ((lrow >> 1) & 3)) << 3);

  auto stage = [&](int t) {                // tile index; 4 async16
    const int k0 = t * 32;
    const int kb = t & 1;
    if (k0 < 128) {
      const _Float16* gA = A0 + (size_t)(bm0 + lrow) * 128 + (k0 + csw);
      async16(gA, &sA[kb][lin]);
      async16(gA + (size_t)64 * 128, &sA[kb][lin + 2048]);
    } else {
      const _Float16* gA = A2 + (size_t)(bm0 + lrow) * 192 + (k0 - 128 + csw);
      async16(gA, &sA[kb][lin]);
      async16(gA + (size_t)64 * 192, &sA[kb][lin + 2048]);
    }
    const _Float16* gB = B0 + (size_t)(bn0 + lrow) * Kd + (k0 + csw);
    async16(gB, &sB[kb][lin]);
    async16(gB + (size_t)64 * Kd, &sB[kb][lin + 2048]);
  };

  auto ldA = [&](int bb, int r) -> half8 {
    return *(const half8*)&sA[bb][r * 32 + ((quad ^ ((r >> 1) & 3)) << 3)];
  };
  auto ldB = [&](int bb, int r) -> half8 {
    return *(const half8*)&sB[bb][r * 32 + ((quad ^ ((r >> 1) & 3)) << 3)];
  };

  half8 a0[4], b0[4];

  stage(0);
  stage(1);
  __builtin_amdgcn_s_waitcnt(0x0F74);   // vmcnt(4): tile 0 landed, tile 1 in flight
  FENCE(); __builtin_amdgcn_s_barrier(); FENCE();
#pragma unroll
  for (int i = 0; i < 4; ++i) a0[i] = ldA(0, wr + i * 16 + m16);
#pragma unroll
  for (int j = 0; j < 4; ++j) b0[j] = ldB(0, wc + j * 16 + m16);

  for (int t = 0; t < 10; ++t) {
    const int nb = (t & 1) ^ 1;
    FENCE(); __builtin_amdgcn_s_barrier(); FENCE();   // BARRIER1: bb reads done
    if (t < 8) stage(t + 2);
    FENCE();
    if (t < 8)
      __builtin_amdgcn_s_waitcnt(0x0F74);   // vmcnt(4): tile t+1 landed
    else
      __builtin_amdgcn_s_waitcnt(0x0F70);   // tail: drain
    FENCE(); __builtin_amdgcn_s_barrier(); FENCE();   // BARRIER2
    __builtin_amdgcn_s_setprio(1);
#pragma unroll
    for (int i = 0; i < 4; ++i)
#pragma unroll
      for (int j = 0; j < 2; ++j)
        acc[i][j] = __builtin_amdgcn_mfma_f32_16x16x32_f16(a0[i], b0[j], acc[i][j], 0, 0, 0);
    __builtin_amdgcn_s_setprio(0);
    if (t < 9) {
#pragma unroll
      for (int j = 0; j < 2; ++j) b0[j] = ldB(nb, wc + j * 16 + m16);
    }
    __builtin_amdgcn_s_setprio(1);
#pragma unroll
    for (int i = 0; i < 4; ++i)
#pragma unroll
      for (int j = 2; j < 4; ++j)
        acc[i][j] = __builtin_amdgcn_mfma_f32_16x16x32_f16(a0[i], b0[j], acc[i][j], 0, 0, 0);
    __builtin_amdgcn_s_setprio(0);
    if (t < 9) {
#pragma unroll
      for (int i = 0; i < 4; ++i) a0[i] = ldA(nb, wr + i * 16 + m16);
#pragma unroll
      for (int j = 2; j < 4; ++j) b0[j] = ldB(nb, wc + j * 16 + m16);
    }
  }

#pragma unroll
  for (int i = 0; i < 4; ++i) {
    const int row0 = bm0 + wr + i * 16 + quad * 4;
#pragma unroll
    for (int j = 0; j < 4; j += 2) {
      const int colv = bn0 + wc + j * 16 + m16;
      const int jout = (colv >> 5) * 16 + m16;
#pragma unroll
      for (int r = 0; r < 4; ++r) {
        float val = acc[i][j][r];
        float gg = acc[i][j + 1][r];
        float sg = gg / (1.f + __expf(-gg));
        YH[(size_t)(row0 + r) * 2304 + kz * 192 + jout] = (_Float16)(val * sg);
      }
    }
  }
}

// ---------------------------------------------------------------------------
// Scan pass A, wave-cooperative dedup.
// ---------------------------------------------------------------------------
__global__ __launch_bounds__(256)
void pass_a_kernel(const float* __restrict__ zp,
                   const float* __restrict__ ck,
                   const float* __restrict__ theta_tab,
                   const float* __restrict__ score_scale,
                   const float* __restrict__ tanh_scale,
                   const float* __restrict__ slopes_sp,
                   float* __restrict__ csums) {
  const int c = blockIdx.x, k = blockIdx.y, b = blockIdx.z;
  const int tid = threadIdx.x;
  const int m = tid & 3, h = tid >> 2;
  const int l0 = c * LC_;
  const size_t base = (((size_t)b * K_ + k) * NC_ + c) * 513;

  __shared__ float s_pw[LC_];
  __shared__ float s_kv[LC_][H_];
  __shared__ float s_th[LC_][H_];

  if (tid < 32) {
    const int chs = 768 + k;
    const float ss = score_scale[k], slope = slopes_sp[k];
    float cks[4];
#pragma unroll
    for (int w = 0; w < 4; ++w) cks[w] = ck[w * ZC_ + chs];
    float sraw = 0.f;
#pragma unroll
    for (int j = 0; j < 4; ++j) {
      int lp_ = l0 + tid - 3 + j;
      float zs = (lp_ >= 0) ? zp[((size_t)b * L_ + lp_) * ZC_ + chs] : 0.f;
      sraw += zs * cks[j];
    }
    float lp = fminf(fmaxf(ss * sraw, -20.f), 20.f);
    int l = l0 + tid;
    float pw = __expf(lp - slope * (float)(L_ - 1 - l));
    s_pw[tid] = pw;
    float tot = pw;
    tot += __shfl_xor(tot, 1);
    tot += __shfl_xor(tot, 2);
    tot += __shfl_xor(tot, 4);
    tot += __shfl_xor(tot, 8);
    tot += __shfl_xor(tot, 16);
    if (tid == 0) csums[base] = tot;   // dacc
  }

  {
    const int hh = tid >> 2, g = tid & 3;
    const int chkh = k * H_ + hh;
    const float ts = tanh_scale[k];
    float ckv[4];
#pragma unroll
    for (int w = 0; w < 4; ++w) ckv[w] = ck[w * ZC_ + chkh];
    const int lbase = l0 + g * 8;
    float z3 = 0.f, z2 = 0.f, z1 = 0.f;
#pragma unroll
    for (int p = 0; p < 3; ++p) {
      int lp_ = lbase - 3 + p;
      if (lp_ >= 0) {
        float z = zp[((size_t)b * L_ + lp_) * ZC_ + chkh];
        if (p == 0) z3 = z; else if (p == 1) z2 = z; else z1 = z;
      }
    }
#pragma unroll
    for (int j = 0; j < 8; ++j) {
      float z0 = zp[((size_t)b * L_ + lbase + j) * ZC_ + chkh];
      float kv = z3 * ckv[0] + z2 * ckv[1] + z1 * ckv[2] + z0 * ckv[3];
      z3 = z2; z2 = z1; z1 = z0;
      s_kv[g * 8 + j][hh] = kv;
      s_th[g * 8 + j][hh] = fast_tanh(ts * kv);
    }
  }
  __syncthreads();

  const int chk = k * H_ + h;
  const float theta_v = theta_tab[chk * M_ + m];
  float sre = 0.f, sim = 0.f;
#pragma unroll 8
  for (int ll = 0; ll < LC_; ++ll) {
    float kvp = s_kv[ll][h] * s_pw[ll];
    float ph = s_th[ll][h] * theta_v;
    sre += kvp * __cosf(ph);
    sim += kvp * __sinf(ph);
  }
  csums[base + 1 + h * 4 + m] = sre;
  csums[base + 1 + 256 + h * 4 + m] = sim;
}

// ---------------------------------------------------------------------------
__global__ void pass_b_kernel(const float* __restrict__ csums,
                              float* __restrict__ cpre) {
  int bk = blockIdx.y;
  int comp = blockIdx.x * 64 + threadIdx.x;
  if (comp >= 513) return;
  float run = 0.f;
  size_t base = (size_t)bk * NC_ * 513 + comp;
#pragma unroll 4
  for (int c = 0; c < NC_; ++c) {
    cpre[base + (size_t)c * 513] = run;
    run += csums[base + (size_t)c * 513];
  }
}

// ---------------------------------------------------------------------------
// Scan pass C, wave-cooperative dedup + den prefix, sigmoid gate, q contract.
// ---------------------------------------------------------------------------
__global__ __launch_bounds__(256)
void pass_c_kernel(const float* __restrict__ zp,
                   const float* __restrict__ ck,
                   const _Float16* __restrict__ qh,
                   const float* __restrict__ theta_tab,
                   const float* __restrict__ w_tab,
                   const float* __restrict__ score_scale,
                   const float* __restrict__ tanh_scale,
                   const float* __restrict__ slopes_sp,
                   const float* __restrict__ cpre,
                   const float* __restrict__ gatelin,
                   const float* __restrict__ gate_b,
                   const float* __restrict__ ns,
                   _Float16* __restrict__ asp) {
  const int c = blockIdx.x, k = blockIdx.y, b = blockIdx.z;
  const int tid = threadIdx.x;
  const int m = tid & 3, h = tid >> 2;
  const int l0 = c * LC_;
  const size_t base = (((size_t)b * K_ + k) * NC_ + c) * 513;

  __shared__ float s_pw[LC_];
  __shared__ float s_inv[LC_];
  __shared__ float s_sg[LC_];
  __shared__ float s_kv[LC_][H_];
  __shared__ float s_th[LC_][H_];

  if (tid < 32) {
    const int chs = 768 + k;
    const float ss = score_scale[k], slope = slopes_sp[k];
    const float gb = gate_b[k];
    float cks[4];
#pragma unroll
    for (int w = 0; w < 4; ++w) cks[w] = ck[w * ZC_ + chs];
    float sraw = 0.f;
#pragma unroll
    for (int j = 0; j < 4; ++j) {
      int lp_ = l0 + tid - 3 + j;
      float zs = (lp_ >= 0) ? zp[((size_t)b * L_ + lp_) * ZC_ + chs] : 0.f;
      sraw += zs * cks[j];
    }
    float lp = fminf(fmaxf(ss * sraw, -20.f), 20.f);
    int l = l0 + tid;
    float pw = __expf(lp - slope * (float)(L_ - 1 - l));
    s_pw[tid] = pw;
    float pref = pw;
#pragma unroll
    for (int off = 1; off < 32; off <<= 1) {
      float nv = __shfl_up(pref, off);
      if (tid >= off) pref += nv;
    }
    float den = cpre[base] + pref;
    s_inv[tid] = 1.f / fmaxf(den, 1e-4f);
    float gl = gatelin[((size_t)b * L_ + l) * K_ + k];
    s_sg[tid] = 1.f / (1.f + __expf(-(gl + gb)));
  }

  {
    const int hh = tid >> 2, g = tid & 3;
    const int chkh = k * H_ + hh;
    const float ts = tanh_scale[k];
    float ckv[4];
#pragma unroll
    for (int w = 0; w < 4; ++w) ckv[w] = ck[w * ZC_ + chkh];
    const int lbase = l0 + g * 8;
    float z3 = 0.f, z2 = 0.f, z1 = 0.f;
#pragma unroll
    for (int p = 0; p < 3; ++p) {
      int lp_ = lbase - 3 + p;
      if (lp_ >= 0) {
        float z = zp[((size_t)b * L_ + lp_) * ZC_ + chkh];
        if (p == 0) z3 = z; else if (p == 1) z2 = z; else z1 = z;
      }
    }
#pragma unroll
    for (int j = 0; j < 8; ++j) {
      float z0 = zp[((size_t)b * L_ + lbase + j) * ZC_ + chkh];
      float kv = z3 * ckv[0] + z2 * ckv[1] + z1 * ckv[2] + z0 * ckv[3];
      z3 = z2; z2 = z1; z1 = z0;
      s_kv[g * 8 + j][hh] = kv;
      s_th[g * 8 + j][hh] = fast_tanh(ts * kv);
    }
  }
  __syncthreads();

  const int chk = k * H_ + h;
  const float theta_v = theta_tab[chk * M_ + m];
  const float w = w_tab[chk * M_ + m];
  const float nsv = ns[chk];
  const int kq = k >> 1;   // NREP = 2
  const int qidx = ((kq * H_ + h) * M_ + m) * 2;
  float sre = cpre[base + 1 + h * 4 + m];
  float sim = cpre[base + 1 + 256 + h * 4 + m];
#pragma unroll 4
  for (int ll = 0; ll < LC_; ++ll) {
    float kvp = s_kv[ll][h] * s_pw[ll];
    float ph = s_th[ll][h] * theta_v;
    sre += kvp * __cosf(ph);
    sim += kvp * __sinf(ph);
    float inv = s_inv[ll];
    float s_re = sre * inv, s_im = sim * inv;
    size_t t = (size_t)b * L_ + l0 + ll;
    size_t qb = t * QST_ + qidx;
    float qr = (float)qh[qb], qi = (float)qh[qb + 1];
    float tr = (s_re * qr + s_im * qi) * w;
    float ti = (s_im * qr - s_re * qi) * w;
    tr += __shfl_xor(tr, 1); tr += __shfl_xor(tr, 2);
    ti += __shfl_xor(ti, 1); ti += __shfl_xor(ti, 2);
    if (m == 0) {
      float g = s_sg[ll] * nsv;
      size_t ab = ((size_t)k * NTOK_ + t) * 128;
      asp[ab + h] = (_Float16)(tr * g);
      asp[ab + 64 + h] = (_Float16)(ti * g);
    }
  }
}

// ---------------------------------------------------------------------------
extern "C" void kernel_launch(void* const* d_in, const int* in_sizes, int n_in,
                              void* d_out, int out_size, void* d_ws, size_t ws_size,
                              hipStream_t stream) {
  const float* x            = (const float*)d_in[0];
  const float* W_mem        = (const float*)d_in[1];
  const float* conv_k       = (const float*)d_in[2];
  const float* W_q          = (const float*)d_in[3];
  const float* theta_d_raw  = (const float*)d_in[4];
  const float* decay_slopes = (const float*)d_in[5];
  const float* score_scale  = (const float*)d_in[6];
  const float* tanh_scale   = (const float*)d_in[7];
  const float* W_re         = (const float*)d_in[8];
  const float* W_im         = (const float*)d_in[9];
  const float* norm_scale   = (const float*)d_in[10];
  const float* gate_W       = (const float*)d_in[11];
  const float* gate_b       = (const float*)d_in[12];
  const float* skip_down_W  = (const float*)d_in[13];
  const float* skip_up_W    = (const float*)d_in[14];
  const float* highway_scale= (const float*)d_in[15];
  const float* out_W        = (const float*)d_in[16];
  float* out = (float*)d_out;
  float* ws = (float*)d_ws;

  // ---- f32 region ----
  float* theta_tab = ws;                                  // 3072
  float* w_tab     = theta_tab + 3072;                    // 3072
  float* slopes_sp = w_tab + 3072;                        // 16
  float* z_pre     = slopes_sp + 16;                      // 3,194,880
  float* gatelin   = z_pre + (size_t)NTOK_ * ZC_;         // 49,152
  float* csums     = gatelin + (size_t)NTOK_ * K_;        // 787,968
  float* cpre      = csums + (size_t)B_ * K_ * NC_ * 513; // 787,968
  _Float16* q_h    = (_Float16*)(cpre + (size_t)B_ * K_ * NC_ * 513); // 4096x3072
  _Float16* y_h    = q_h + (size_t)NTOK_ * QST_;          // 4096x2304
  float* f32_end   = (float*)(y_h + (size_t)NTOK_ * 2304);

  // split-K partials (3 x 4096 x 768 f32) OVERLAY dead scan workspace
  float* part = z_pre;

  // ---- fp16 region ----
  _Float16* fp = (_Float16*)f32_end;
  _Float16* x_h    = fp;                fp += (size_t)NTOK_ * D_;
  _Float16* xpb_h  = fp;                fp += (size_t)XPN_ * 768;   // merged proj B (4096 rows)
  _Float16* outw_h = fp;                fp += (size_t)768 * 2304;
  _Float16* asp2_h = fp;                fp += (size_t)K_ * NTOK_ * 128;
  _Float16* bsp_h  = fp;                fp += (size_t)K_ * 384 * 320;
  _Float16* lat_h  = fp;                fp += (size_t)NTOK_ * 192;

  // fused prologue: precomp + all weight conversions (incl gate_W) + x->fp16
  prep_kernel<<<18651, 256, 0, stream>>>(x, W_mem, W_q, skip_down_W, out_W, W_re, W_im,
                                         skip_up_W, highway_scale, gate_W,
                                         theta_d_raw, decay_slopes,
                                         x_h, xpb_h, outw_h, bsp_h,
                                         theta_tab, w_tab, slopes_sp);

  // merged x-projection (256x128 tile, BK=32, 2 blocks/CU): q + lat + gate + z_pre
  xprojk_kernel<<<512, 512, 0, stream>>>(x_h, xpb_h, z_pre, lat_h, q_h, gatelin);

  // chunked scan (f32), wave-cooperative dedup
  pass_a_kernel<<<dim3(NC_, K_, B_), 256, 0, stream>>>(z_pre, conv_k, theta_tab, score_scale,
                                                       tanh_scale, slopes_sp, csums);
  pass_b_kernel<<<dim3(9, B_ * K_), 64, 0, stream>>>(csums, cpre);
  pass_c_kernel<<<dim3(NC_, K_, B_), 256, 0, stream>>>(z_pre, conv_k, q_h, theta_tab, w_tab,
                                                       score_scale, tanh_scale, slopes_sp, cpre,
                                                       gatelin, gate_b, norm_scale, asp2_h);

  // batched spec GEMM (2-barrier counted-vmcnt) with fused SiLU -> y_h fp16
  spec_gemm_kernel<<<1152, 256, 0, stream>>>(asp2_h, bsp_h, lat_h, y_h);

  // out = y @ out_W: 256x128/BK=32 xprojk-style, split-K=4, all-co-resident grid
  outprojk_kernel<<<384, 512, 0, stream>>>(y_h, outw_h, out, part);
  // fold partials into out
  redout_kernel<<<3072, 256, 0, stream>>>(out, part);
}

// Round 11
// 234.635 us; speedup vs baseline: 1.2156x; 1.0458x over previous
//
#include <hip/hip_runtime.h>
#include <math.h>

#define B_    2
#define L_    2048
#define D_    768
#define K_    12
#define KQ_   6
#define M_    4
#define H_    64
#define ZC_   780      // MEM + K
#define NTOK_ 4096     // B*L
#define NC_   64       // scan chunks per batch
#define LC_   32       // chunk length (L/NC)
#define QST_  3072     // q fp16 row stride
#define XPN_  4096     // merged projection N
#define ZOFF_ 3276     // z_pre column base in xpb

typedef __attribute__((ext_vector_type(8))) _Float16 half8;
typedef __attribute__((ext_vector_type(4))) float f32x4;

__device__ __forceinline__ float softplus_f(float x) {
  return (x > 20.f) ? x : log1pf(expf(x));
}

__device__ __forceinline__ float fast_tanh(float x) {
  float xx = fminf(fmaxf(x, -10.f), 10.f);
  float e = __expf(2.f * xx);
  return (e - 1.f) / (e + 1.f);
}

// async global->LDS 16B per lane (dest = wave-uniform base + lane*16)
__device__ __forceinline__ void async16(const _Float16* g, _Float16* l) {
  __builtin_amdgcn_global_load_lds(
      (const __attribute__((address_space(1))) unsigned int*)g,
      (__attribute__((address_space(3))) unsigned int*)l, 16, 0, 0);
}

// val/gate 16-interleave permutation for spec-B columns
__device__ __forceinline__ int permcol(int n) {
  int isg = (n >= 192) ? 1 : 0;
  int j = n - 192 * isg;
  return (j >> 4) * 32 + (isg << 4) + (j & 15);
}

#define FENCE() asm volatile("" ::: "memory")

// ---------------------------------------------------------------------------
// Transpose+convert body; optional perm + scale. Nst = store-row limit.
// ---------------------------------------------------------------------------
__device__ __forceinline__ void cvt_t_body(float (*tile)[33], int bx, int by, int kz,
                                           const float* src, long sKs, int srs,
                                           _Float16* dh, long dKs, int dst, int doff,
                                           int R, int Nact, int Nst, bool perm, float scale) {
  const float* s = src + (size_t)kz * sKs;
  _Float16* dhh = dh + (size_t)kz * dKs;
  const int kb = bx * 32;
  const int nb = by * 32;
  const int tx = threadIdx.x & 31, ty = threadIdx.x >> 5;
  for (int i = ty; i < 32; i += 8) {
    int kk = kb + i, n = nb + tx;
    tile[i][tx] = (kk < R && n < Nact) ? s[(size_t)kk * srs + n] : 0.f;
  }
  __syncthreads();
  for (int i = ty; i < 32; i += 8) {
    int n = nb + i, kk = kb + tx;
    if (kk < R && n < Nst) {
      float v = tile[tx][i] * scale;
      int dn = perm ? permcol(n) : n;
      dhh[(size_t)dn * dst + doff + kk] = (_Float16)v;
    }
  }
}

// ---------------------------------------------------------------------------
// Fused prologue, ONE dispatch:
//   blocks [0,3):          precomp (theta/w tables, slopes)
//   blocks [3,6363):       all weight conversions (incl. gate_W -> xpb cols)
//   blocks [6363,9435):    x f32->fp16 (vectorized: f32x4 load, 8B packed store)
// xpb layout (rows x 768): [W_q^T 0:3072 | skd^T 3072:3264 | gate^T 3264:3276 |
//                           W_mem^T 3276:4056 | dead 4056:4096]
// ---------------------------------------------------------------------------
__global__ __launch_bounds__(256)
void prep_kernel(const float* __restrict__ x,
                 const float* __restrict__ W_mem, const float* __restrict__ W_q,
                 const float* __restrict__ skip_down_W, const float* __restrict__ out_W,
                 const float* __restrict__ W_re, const float* __restrict__ W_im,
                 const float* __restrict__ skip_up_W, const float* __restrict__ hs,
                 const float* __restrict__ gate_W,
                 const float* __restrict__ theta_d_raw, const float* __restrict__ decay,
                 _Float16* __restrict__ x_h,
                 _Float16* __restrict__ xpb_h, _Float16* __restrict__ outw_h,
                 _Float16* __restrict__ bsp_h,
                 float* __restrict__ theta_tab, float* __restrict__ w_tab,
                 float* __restrict__ slopes_sp) {
  __shared__ float tile[32][33];
  int b = blockIdx.x;
  if (b < 3) {
    int idx = b * 256 + threadIdx.x;
    if (idx < K_) slopes_sp[idx] = softplus_f(decay[idx]);
    if (idx >= K_ * H_) return;
    float td[M_], ta[M_];
#pragma unroll
    for (int m = 0; m < M_; ++m) td[m] = softplus_f(theta_d_raw[idx * M_ + m]) + 1e-4f;
    ta[0] = td[0];
#pragma unroll
    for (int m = 1; m < M_; ++m) ta[m] = ta[m - 1] + td[m];
    float total = ta[M_ - 1];
    float rs = 2.999f / total;
#pragma unroll
    for (int m = 0; m < M_; ++m) theta_tab[idx * M_ + m] = 0.001f + ta[m] * rs;
    float d0 = (ta[1] - ta[0]) * rs;
    float d1 = (ta[2] - ta[1]) * rs;
    float d2 = (ta[3] - ta[2]) * rs;
    w_tab[idx * M_ + 0] = 0.5f * d0;
    w_tab[idx * M_ + 1] = 0.5f * (d0 + d1);
    w_tab[idx * M_ + 2] = 0.5f * (d1 + d2);
    w_tab[idx * M_ + 3] = 0.5f * d2;
    return;
  }
  b -= 3;
  if (b < 6360) {
    if (b < 672) {           // W_mem -> xpb rows [3276,4056), 24x28
      cvt_t_body(tile, b % 24, b / 24, 0, W_mem, 0, ZC_, xpb_h + (size_t)ZOFF_ * 768,
                 0, 768, 0, 768, ZC_, ZC_, false, 1.f);
      return;
    }
    b -= 672;
    if (b < 2304) {          // W_q -> xpb rows [0,3072), 24x96
      cvt_t_body(tile, b % 24, b / 24, 0, W_q, 0, 3072, xpb_h, 0, 768, 0, 768,
                 3072, 3072, false, 1.f);
      return;
    }
    b -= 2304;
    if (b < 192) {           // skip_down -> xpb rows [3072,3264), 24x8
      cvt_t_body(tile, b % 24, b / 24, 0, skip_down_W, 0, 192, xpb_h + (size_t)3072 * 768,
                 0, 768, 0, 768, 192, 192, false, 1.f);
      return;
    }
    b -= 192;
    if (b < 1728) {          // out_W -> outw, 72x24
      cvt_t_body(tile, b % 72, b / 72, 0, out_W, 0, 768, outw_h, 0, 2304, 0, 2304,
                 768, 768, false, 1.f);
      return;
    }
    b -= 1728;
    if (b < 288) {           // W_re -> bsp[k][perm(n)][0:64], 2x12x12
      cvt_t_body(tile, b % 2, (b / 2) % 12, b / 24, W_re, 64L * 384, 384, bsp_h,
                 384L * 320, 320, 0, 64, 384, 384, true, 1.f);
      return;
    }
    b -= 288;
    if (b < 288) {           // W_im -> bsp[k][perm(n)][64:128]
      cvt_t_body(tile, b % 2, (b / 2) % 12, b / 24, W_im, 64L * 384, 384, bsp_h,
                 384L * 320, 320, 64, 64, 384, 384, true, 1.f);
      return;
    }
    b -= 288;
    if (b < 864) {           // skip_up slice -> bsp[k][perm(n)][128:320] scaled by hs[k]
      int kz = b / 72;
      cvt_t_body(tile, b % 6, (b / 6) % 12, kz, skip_up_W, 384, 4608, bsp_h,
                 384L * 320, 320, 128, 192, 384, 384, true, hs[kz]);
      return;
    }
    b -= 864;
    // gate_W (768x12) -> xpb rows [3264,3276), 24 blocks; store-limited to 12 rows
    cvt_t_body(tile, b, 0, 0, gate_W, 0, K_, xpb_h + (size_t)3264 * 768,
               0, 768, 0, 768, K_, K_, false, 1.f);
    return;
  }
  b -= 6360;
  // x -> fp16, 4 elems/thread (f32x4 load, 8B packed store)
  size_t i4 = ((size_t)b * 256 + threadIdx.x) * 4;
  if (i4 < (size_t)NTOK_ * D_) {
    f32x4 v = *(const f32x4*)&x[i4];
    union { _Float16 h[4]; unsigned long long u; } o;
    o.h[0] = (_Float16)v[0];
    o.h[1] = (_Float16)v[1];
    o.h[2] = (_Float16)v[2];
    o.h[3] = (_Float16)v[3];
    *(unsigned long long*)&x_h[i4] = o.u;
  }
}

// ---------------------------------------------------------------------------
// x-projection GEMM, 256x128 tile, BK=32, 48 KiB LDS -> 2 blocks/CU
// co-resident (grid 512 = one round). 2-barrier/K-tile counted-vmcnt.
// Plateaued at ~43 us: per-tile pipe-sum (MFMA 614 + ds_read 768 + DMA 192 cy)
// ~73% utilized -- near structural floor for this shape (K=768, fused epilogue).
// ---------------------------------------------------------------------------
__global__ __launch_bounds__(512, 4)
void xprojk_kernel(const _Float16* __restrict__ Ah, const _Float16* __restrict__ Bh,
                   float* __restrict__ C, _Float16* __restrict__ YH,
                   _Float16* __restrict__ QH, float* __restrict__ GL) {
  __shared__ __align__(16) _Float16 sA[2][2][128][32];   // [dbuf][Mhalf][row][32]
  __shared__ __align__(16) _Float16 sB[2][128][32];      // [dbuf][row][32]

  // XCD chunking: 512 = 8 xcd x 64; xcd owns by in {2x,2x+1} for all 32 bx
  const int bid = blockIdx.x;
  const int xcd = bid & 7, s = bid >> 3;    // s in [0,64)
  const int by = xcd * 2 + (s & 1);         // 0..15
  const int bx = s >> 1;                    // 0..31
  const int bm0 = by * 256, bn0 = bx * 128;

  const int tid = threadIdx.x;
  const int lane = tid & 63;
  const int wave = tid >> 6;
  const int m16 = lane & 15, quad = lane >> 4;
  const int wr = wave >> 1;     // 0..3 (64-row group)
  const int wc = wave & 1;      // 0..1 (64-col group)

  f32x4 acc[4][4];
#pragma unroll
  for (int i = 0; i < 4; ++i)
#pragma unroll
    for (int j = 0; j < 4; ++j) acc[i][j] = (f32x4){0.f, 0.f, 0.f, 0.f};

  const int sr4 = tid >> 2;        // 0..127 staging row
  const int lb = tid & 3;          // 16B block within 32-half row
  const int ssw = (sr4 >> 1) & 3;  // row swizzle term

  auto stageA = [&](int t) {       // 2 async16: both M-halves
    const int bb = t & 1;
    const _Float16* g = Ah + (size_t)(bm0 + sr4) * 768 + t * 32 + ((lb ^ ssw) << 3);
    async16(g,                     &sA[bb][0][0][0] + (size_t)tid * 8);
    async16(g + (size_t)128 * 768, &sA[bb][1][0][0] + (size_t)tid * 8);
  };
  auto stageB = [&](int t) {       // 1 async16
    const int bb = t & 1;
    const _Float16* g = Bh + (size_t)(bn0 + sr4) * 768 + t * 32 + ((lb ^ ssw) << 3);
    async16(g, &sB[bb][0][0] + (size_t)tid * 8);
  };

  auto ldA = [&](int bb, int r) -> half8 {   // r in [0,256)
    return *(const half8*)&sA[bb][r >> 7][r & 127][(quad ^ ((r >> 1) & 3)) << 3];
  };
  auto ldB = [&](int bb, int r) -> half8 {   // r in [0,128)
    return *(const half8*)&sB[bb][r][(quad ^ ((r >> 1) & 3)) << 3];
  };

  half8 a[4], b[4];

  stageB(0); stageA(0);
  stageB(1); stageA(1);
  __builtin_amdgcn_s_waitcnt(0x0F73);   // vmcnt(3): tile0 landed, tile1 in flight
  FENCE(); __builtin_amdgcn_s_barrier(); FENCE();
#pragma unroll
  for (int m = 0; m < 4; ++m) a[m] = ldA(0, wr * 64 + m * 16 + m16);
#pragma unroll
  for (int n = 0; n < 4; ++n) b[n] = ldB(0, wc * 64 + n * 16 + m16);

  for (int t = 0; t < 24; ++t) {
    const int nb = (t & 1) ^ 1;
    FENCE(); __builtin_amdgcn_s_barrier(); FENCE();   // BARRIER1: bb reads done
    if (t < 22) { stageB(t + 2); stageA(t + 2); }
    FENCE();
    if (t < 22)
      __builtin_amdgcn_s_waitcnt(0x0F73);   // vmcnt(3): tile t+1 landed
    else
      __builtin_amdgcn_s_waitcnt(0x0F70);   // tail: drain
    FENCE(); __builtin_amdgcn_s_barrier(); FENCE();   // BARRIER2
    __builtin_amdgcn_s_setprio(1);
#pragma unroll
    for (int m = 0; m < 4; ++m)
#pragma unroll
      for (int n = 0; n < 2; ++n)
        acc[m][n] = __builtin_amdgcn_mfma_f32_16x16x32_f16(a[m], b[n], acc[m][n], 0, 0, 0);
    __builtin_amdgcn_s_setprio(0);
    if (t < 23) {
#pragma unroll
      for (int n = 0; n < 2; ++n) b[n] = ldB(nb, wc * 64 + n * 16 + m16);
    }
    __builtin_amdgcn_s_setprio(1);
#pragma unroll
    for (int m = 0; m < 4; ++m)
#pragma unroll
      for (int n = 2; n < 4; ++n)
        acc[m][n] = __builtin_amdgcn_mfma_f32_16x16x32_f16(a[m], b[n], acc[m][n], 0, 0, 0);
    __builtin_amdgcn_s_setprio(0);
    if (t < 23) {
#pragma unroll
      for (int m = 0; m < 4; ++m) a[m] = ldA(nb, wr * 64 + m * 16 + m16);
#pragma unroll
      for (int n = 2; n < 4; ++n) b[n] = ldB(nb, wc * 64 + n * 16 + m16);
    }
  }

  // ---- epilogue (C/D layout: col=lane&15, row=quad*4+reg) ----
#pragma unroll
  for (int m = 0; m < 4; ++m) {
    const int row0 = bm0 + wr * 64 + m * 16 + quad * 4;
#pragma unroll
    for (int n = 0; n < 4; ++n) {
      const int col = bn0 + wc * 64 + n * 16 + m16;
      if (col < 3072) {
#pragma unroll
        for (int r = 0; r < 4; ++r)
          QH[(size_t)(row0 + r) * QST_ + col] = (_Float16)acc[m][n][r];
      } else if (col < 3264) {
        const int jj = col - 3072;
#pragma unroll
        for (int r = 0; r < 4; ++r)
          YH[(size_t)(row0 + r) * 192 + jj] = (_Float16)acc[m][n][r];
      } else if (col < 3276) {
        const int kk = col - 3264;
#pragma unroll
        for (int r = 0; r < 4; ++r)
          GL[(size_t)(row0 + r) * K_ + kk] = acc[m][n][r];
      } else if (col < 3276 + ZC_) {
        const int wz = col - ZOFF_;
#pragma unroll
        for (int r = 0; r < 4; ++r)
          C[(size_t)(row0 + r) * ZC_ + wz] = acc[m][n][r];
      }
    }
  }
}

// ---------------------------------------------------------------------------
// out-projection GEMM, xprojk-style: 256x128 tile, BK=32, 48 KiB LDS,
// split-K=4 (K=2304 -> 576/split = 18 tiles). Grid 384 = 8 xcd x 48, ALL
// co-resident. NO atomics: kz 0 -> out, kz 1-3 -> partials folded by redout.
// ---------------------------------------------------------------------------
__global__ __launch_bounds__(512, 4)
void outprojk_kernel(const _Float16* __restrict__ Ah, const _Float16* __restrict__ Bh,
                     float* __restrict__ out, float* __restrict__ part) {
  __shared__ __align__(16) _Float16 sA[2][2][128][32];   // [dbuf][Mhalf][row][32]
  __shared__ __align__(16) _Float16 sB[2][128][32];

  // 384 = 8 xcd x 48; xcd owns by in {2x,2x+1} for all (bx,kz)
  const int bid = blockIdx.x;
  const int xcd = bid & 7, s = bid >> 3;    // s in [0,48)
  const int by = xcd * 2 + (s & 1);         // 0..15
  const int rest = s >> 1;                  // 0..23
  const int bx = rest % 6;                  // 0..5
  const int kz = rest / 6;                  // 0..3
  const int bm0 = by * 256, bn0 = bx * 128;
  const int kt0 = kz * 18;                  // first BK32-tile of this split

  const int tid = threadIdx.x;
  const int lane = tid & 63;
  const int wave = tid >> 6;
  const int m16 = lane & 15, quad = lane >> 4;
  const int wr = wave >> 1;     // 0..3
  const int wc = wave & 1;      // 0..1

  f32x4 acc[4][4];
#pragma unroll
  for (int i = 0; i < 4; ++i)
#pragma unroll
    for (int j = 0; j < 4; ++j) acc[i][j] = (f32x4){0.f, 0.f, 0.f, 0.f};

  const int sr4 = tid >> 2;
  const int lb = tid & 3;
  const int ssw = (sr4 >> 1) & 3;

  auto stageA = [&](int t) {
    const int bb = t & 1;
    const _Float16* g = Ah + (size_t)(bm0 + sr4) * 2304 + (kt0 + t) * 32 + ((lb ^ ssw) << 3);
    async16(g,                      &sA[bb][0][0][0] + (size_t)tid * 8);
    async16(g + (size_t)128 * 2304, &sA[bb][1][0][0] + (size_t)tid * 8);
  };
  auto stageB = [&](int t) {
    const int bb = t & 1;
    const _Float16* g = Bh + (size_t)(bn0 + sr4) * 2304 + (kt0 + t) * 32 + ((lb ^ ssw) << 3);
    async16(g, &sB[bb][0][0] + (size_t)tid * 8);
  };

  auto ldA = [&](int bb, int r) -> half8 {
    return *(const half8*)&sA[bb][r >> 7][r & 127][(quad ^ ((r >> 1) & 3)) << 3];
  };
  auto ldB = [&](int bb, int r) -> half8 {
    return *(const half8*)&sB[bb][r][(quad ^ ((r >> 1) & 3)) << 3];
  };

  half8 a[4], b[4];

  stageB(0); stageA(0);
  stageB(1); stageA(1);
  __builtin_amdgcn_s_waitcnt(0x0F73);   // vmcnt(3)
  FENCE(); __builtin_amdgcn_s_barrier(); FENCE();
#pragma unroll
  for (int m = 0; m < 4; ++m) a[m] = ldA(0, wr * 64 + m * 16 + m16);
#pragma unroll
  for (int n = 0; n < 4; ++n) b[n] = ldB(0, wc * 64 + n * 16 + m16);

  for (int t = 0; t < 18; ++t) {
    const int nb = (t & 1) ^ 1;
    FENCE(); __builtin_amdgcn_s_barrier(); FENCE();   // BARRIER1
    if (t < 16) { stageB(t + 2); stageA(t + 2); }
    FENCE();
    if (t < 16)
      __builtin_amdgcn_s_waitcnt(0x0F73);   // vmcnt(3)
    else
      __builtin_amdgcn_s_waitcnt(0x0F70);   // tail: drain
    FENCE(); __builtin_amdgcn_s_barrier(); FENCE();   // BARRIER2
    __builtin_amdgcn_s_setprio(1);
#pragma unroll
    for (int m = 0; m < 4; ++m)
#pragma unroll
      for (int n = 0; n < 2; ++n)
        acc[m][n] = __builtin_amdgcn_mfma_f32_16x16x32_f16(a[m], b[n], acc[m][n], 0, 0, 0);
    __builtin_amdgcn_s_setprio(0);
    if (t < 17) {
#pragma unroll
      for (int n = 0; n < 2; ++n) b[n] = ldB(nb, wc * 64 + n * 16 + m16);
    }
    __builtin_amdgcn_s_setprio(1);
#pragma unroll
    for (int m = 0; m < 4; ++m)
#pragma unroll
      for (int n = 2; n < 4; ++n)
        acc[m][n] = __builtin_amdgcn_mfma_f32_16x16x32_f16(a[m], b[n], acc[m][n], 0, 0, 0);
    __builtin_amdgcn_s_setprio(0);
    if (t < 17) {
#pragma unroll
      for (int m = 0; m < 4; ++m) a[m] = ldA(nb, wr * 64 + m * 16 + m16);
#pragma unroll
      for (int n = 2; n < 4; ++n) b[n] = ldB(nb, wc * 64 + n * 16 + m16);
    }
  }

  // ---- epilogue: plain f32 stores (no atomics) ----
  float* dst = (kz == 0) ? out : part + (size_t)(kz - 1) * NTOK_ * 768;
#pragma unroll
  for (int m = 0; m < 4; ++m) {
    const int row0 = bm0 + wr * 64 + m * 16 + quad * 4;
#pragma unroll
    for (int n = 0; n < 4; ++n) {
      const int col = bn0 + wc * 64 + n * 16 + m16;
#pragma unroll
      for (int r = 0; r < 4; ++r)
        dst[(size_t)(row0 + r) * 768 + col] = acc[m][n][r];
    }
  }
}

// ---------------------------------------------------------------------------
// Fold the 3 split-K partials into out (float4 vectorized, one pass).
// ---------------------------------------------------------------------------
__global__ __launch_bounds__(256)
void redout_kernel(float* __restrict__ o, const float* __restrict__ p) {
  const size_t i = (size_t)blockIdx.x * 256 + threadIdx.x;
  const f32x4* pv = (const f32x4*)p;
  f32x4 v = ((const f32x4*)o)[i];
  v += pv[i];
  v += pv[i + 786432];
  v += pv[i + 2 * 786432];
  ((f32x4*)o)[i] = v;
}

// ---------------------------------------------------------------------------
// spec GEMM (128x128, BK=32, K=320): 2-barrier counted-vmcnt schedule.
// A from split source (asp per-k 128-stride k<128, lat shared 192-stride);
// fused val/gate SiLU -> YH; XCD-chunked 1D grid (3bx x 32by x 12kz).
// ---------------------------------------------------------------------------
__global__ __launch_bounds__(256)
void spec_gemm_kernel(const _Float16* __restrict__ Ah, const _Float16* __restrict__ Bh,
                      const _Float16* __restrict__ A2, _Float16* __restrict__ YH) {
  __shared__ __align__(16) _Float16 sA[2][128 * 32];
  __shared__ __align__(16) _Float16 sB[2][128 * 32];
  const int Kd = 320;
  int bid = blockIdx.x;
  int xcd = bid & 7, s = bid >> 3;        // s in [0,144)
  int kz = s / 12;
  int w = s % 12;
  int bx = w % 3;
  int by = (xcd << 2) + w / 3;
  const _Float16* A0 = Ah + (size_t)kz * ((size_t)NTOK_ * 128);
  const _Float16* B0 = Bh + (size_t)kz * (384L * 320);
  const int bm0 = by * 128;
  const int bn0 = bx * 128;
  const int tid = threadIdx.x;
  const int wave = tid >> 6, lane = tid & 63;
  const int m16 = lane & 15, quad = lane >> 4;
  const int wr = (wave & 1) * 64, wc = (wave >> 1) * 64;

  f32x4 acc[4][4];
#pragma unroll
  for (int i = 0; i < 4; ++i)
#pragma unroll
    for (int j = 0; j < 4; ++j) acc[i][j] = (f32x4){0.f, 0.f, 0.f, 0.f};

  const int lin = tid * 8;
  const int lrow = lin >> 5;               // 0..63
  const int lblk = (lin >> 3) & 3;
  const int csw = ((lblk ^ ((lrow >> 1) & 3)) << 3);

  auto stage = [&](int t) {                // tile index; 4 async16
    const int k0 = t * 32;
    const int kb = t & 1;
    if (k0 < 128) {
      const _Float16* gA = A0 + (size_t)(bm0 + lrow) * 128 + (k0 + csw);
      async16(gA, &sA[kb][lin]);
      async16(gA + (size_t)64 * 128, &sA[kb][lin + 2048]);
    } else {
      const _Float16* gA = A2 + (size_t)(bm0 + lrow) * 192 + (k0 - 128 + csw);
      async16(gA, &sA[kb][lin]);
      async16(gA + (size_t)64 * 192, &sA[kb][lin + 2048]);
    }
    const _Float16* gB = B0 + (size_t)(bn0 + lrow) * Kd + (k0 + csw);
    async16(gB, &sB[kb][lin]);
    async16(gB + (size_t)64 * Kd, &sB[kb][lin + 2048]);
  };

  auto ldA = [&](int bb, int r) -> half8 {
    return *(const half8*)&sA[bb][r * 32 + ((quad ^ ((r >> 1) & 3)) << 3)];
  };
  auto ldB = [&](int bb, int r) -> half8 {
    return *(const half8*)&sB[bb][r * 32 + ((quad ^ ((r >> 1) & 3)) << 3)];
  };

  half8 a0[4], b0[4];

  stage(0);
  stage(1);
  __builtin_amdgcn_s_waitcnt(0x0F74);   // vmcnt(4): tile 0 landed, tile 1 in flight
  FENCE(); __builtin_amdgcn_s_barrier(); FENCE();
#pragma unroll
  for (int i = 0; i < 4; ++i) a0[i] = ldA(0, wr + i * 16 + m16);
#pragma unroll
  for (int j = 0; j < 4; ++j) b0[j] = ldB(0, wc + j * 16 + m16);

  for (int t = 0; t < 10; ++t) {
    const int nb = (t & 1) ^ 1;
    FENCE(); __builtin_amdgcn_s_barrier(); FENCE();   // BARRIER1: bb reads done
    if (t < 8) stage(t + 2);
    FENCE();
    if (t < 8)
      __builtin_amdgcn_s_waitcnt(0x0F74);   // vmcnt(4): tile t+1 landed
    else
      __builtin_amdgcn_s_waitcnt(0x0F70);   // tail: drain
    FENCE(); __builtin_amdgcn_s_barrier(); FENCE();   // BARRIER2
    __builtin_amdgcn_s_setprio(1);
#pragma unroll
    for (int i = 0; i < 4; ++i)
#pragma unroll
      for (int j = 0; j < 2; ++j)
        acc[i][j] = __builtin_amdgcn_mfma_f32_16x16x32_f16(a0[i], b0[j], acc[i][j], 0, 0, 0);
    __builtin_amdgcn_s_setprio(0);
    if (t < 9) {
#pragma unroll
      for (int j = 0; j < 2; ++j) b0[j] = ldB(nb, wc + j * 16 + m16);
    }
    __builtin_amdgcn_s_setprio(1);
#pragma unroll
    for (int i = 0; i < 4; ++i)
#pragma unroll
      for (int j = 2; j < 4; ++j)
        acc[i][j] = __builtin_amdgcn_mfma_f32_16x16x32_f16(a0[i], b0[j], acc[i][j], 0, 0, 0);
    __builtin_amdgcn_s_setprio(0);
    if (t < 9) {
#pragma unroll
      for (int i = 0; i < 4; ++i) a0[i] = ldA(nb, wr + i * 16 + m16);
#pragma unroll
      for (int j = 2; j < 4; ++j) b0[j] = ldB(nb, wc + j * 16 + m16);
    }
  }

#pragma unroll
  for (int i = 0; i < 4; ++i) {
    const int row0 = bm0 + wr + i * 16 + quad * 4;
#pragma unroll
    for (int j = 0; j < 4; j += 2) {
      const int colv = bn0 + wc + j * 16 + m16;
      const int jout = (colv >> 5) * 16 + m16;
#pragma unroll
      for (int r = 0; r < 4; ++r) {
        float val = acc[i][j][r];
        float gg = acc[i][j + 1][r];
        float sg = gg / (1.f + __expf(-gg));
        YH[(size_t)(row0 + r) * 2304 + kz * 192 + jout] = (_Float16)(val * sg);
      }
    }
  }
}

// ---------------------------------------------------------------------------
// Scan pass A, wave-cooperative dedup.
// ---------------------------------------------------------------------------
__global__ __launch_bounds__(256)
void pass_a_kernel(const float* __restrict__ zp,
                   const float* __restrict__ ck,
                   const float* __restrict__ theta_tab,
                   const float* __restrict__ score_scale,
                   const float* __restrict__ tanh_scale,
                   const float* __restrict__ slopes_sp,
                   float* __restrict__ csums) {
  const int c = blockIdx.x, k = blockIdx.y, b = blockIdx.z;
  const int tid = threadIdx.x;
  const int m = tid & 3, h = tid >> 2;
  const int l0 = c * LC_;
  const size_t base = (((size_t)b * K_ + k) * NC_ + c) * 513;

  __shared__ float s_pw[LC_];
  __shared__ float s_kv[LC_][H_];
  __shared__ float s_th[LC_][H_];

  if (tid < 32) {
    const int chs = 768 + k;
    const float ss = score_scale[k], slope = slopes_sp[k];
    float cks[4];
#pragma unroll
    for (int w = 0; w < 4; ++w) cks[w] = ck[w * ZC_ + chs];
    float sraw = 0.f;
#pragma unroll
    for (int j = 0; j < 4; ++j) {
      int lp_ = l0 + tid - 3 + j;
      float zs = (lp_ >= 0) ? zp[((size_t)b * L_ + lp_) * ZC_ + chs] : 0.f;
      sraw += zs * cks[j];
    }
    float lp = fminf(fmaxf(ss * sraw, -20.f), 20.f);
    int l = l0 + tid;
    float pw = __expf(lp - slope * (float)(L_ - 1 - l));
    s_pw[tid] = pw;
    float tot = pw;
    tot += __shfl_xor(tot, 1);
    tot += __shfl_xor(tot, 2);
    tot += __shfl_xor(tot, 4);
    tot += __shfl_xor(tot, 8);
    tot += __shfl_xor(tot, 16);
    if (tid == 0) csums[base] = tot;   // dacc
  }

  {
    const int hh = tid >> 2, g = tid & 3;
    const int chkh = k * H_ + hh;
    const float ts = tanh_scale[k];
    float ckv[4];
#pragma unroll
    for (int w = 0; w < 4; ++w) ckv[w] = ck[w * ZC_ + chkh];
    const int lbase = l0 + g * 8;
    float z3 = 0.f, z2 = 0.f, z1 = 0.f;
#pragma unroll
    for (int p = 0; p < 3; ++p) {
      int lp_ = lbase - 3 + p;
      if (lp_ >= 0) {
        float z = zp[((size_t)b * L_ + lp_) * ZC_ + chkh];
        if (p == 0) z3 = z; else if (p == 1) z2 = z; else z1 = z;
      }
    }
#pragma unroll
    for (int j = 0; j < 8; ++j) {
      float z0 = zp[((size_t)b * L_ + lbase + j) * ZC_ + chkh];
      float kv = z3 * ckv[0] + z2 * ckv[1] + z1 * ckv[2] + z0 * ckv[3];
      z3 = z2; z2 = z1; z1 = z0;
      s_kv[g * 8 + j][hh] = kv;
      s_th[g * 8 + j][hh] = fast_tanh(ts * kv);
    }
  }
  __syncthreads();

  const int chk = k * H_ + h;
  const float theta_v = theta_tab[chk * M_ + m];
  float sre = 0.f, sim = 0.f;
#pragma unroll 8
  for (int ll = 0; ll < LC_; ++ll) {
    float kvp = s_kv[ll][h] * s_pw[ll];
    float ph = s_th[ll][h] * theta_v;
    sre += kvp * __cosf(ph);
    sim += kvp * __sinf(ph);
  }
  csums[base + 1 + h * 4 + m] = sre;
  csums[base + 1 + 256 + h * 4 + m] = sim;
}

// ---------------------------------------------------------------------------
// Cross-chunk prefix: loads along c are independent of the running sum;
// unroll 16 keeps ~16 loads in flight (latency-bound otherwise).
// ---------------------------------------------------------------------------
__global__ void pass_b_kernel(const float* __restrict__ csums,
                              float* __restrict__ cpre) {
  int bk = blockIdx.y;
  int comp = blockIdx.x * 64 + threadIdx.x;
  if (comp >= 513) return;
  float run = 0.f;
  size_t base = (size_t)bk * NC_ * 513 + comp;
#pragma unroll 16
  for (int c = 0; c < NC_; ++c) {
    cpre[base + (size_t)c * 513] = run;
    run += csums[base + (size_t)c * 513];
  }
}

// ---------------------------------------------------------------------------
// Scan pass C, wave-cooperative dedup + den prefix, sigmoid gate, q contract.
// ---------------------------------------------------------------------------
__global__ __launch_bounds__(256)
void pass_c_kernel(const float* __restrict__ zp,
                   const float* __restrict__ ck,
                   const _Float16* __restrict__ qh,
                   const float* __restrict__ theta_tab,
                   const float* __restrict__ w_tab,
                   const float* __restrict__ score_scale,
                   const float* __restrict__ tanh_scale,
                   const float* __restrict__ slopes_sp,
                   const float* __restrict__ cpre,
                   const float* __restrict__ gatelin,
                   const float* __restrict__ gate_b,
                   const float* __restrict__ ns,
                   _Float16* __restrict__ asp) {
  const int c = blockIdx.x, k = blockIdx.y, b = blockIdx.z;
  const int tid = threadIdx.x;
  const int m = tid & 3, h = tid >> 2;
  const int l0 = c * LC_;
  const size_t base = (((size_t)b * K_ + k) * NC_ + c) * 513;

  __shared__ float s_pw[LC_];
  __shared__ float s_inv[LC_];
  __shared__ float s_sg[LC_];
  __shared__ float s_kv[LC_][H_];
  __shared__ float s_th[LC_][H_];

  if (tid < 32) {
    const int chs = 768 + k;
    const float ss = score_scale[k], slope = slopes_sp[k];
    const float gb = gate_b[k];
    float cks[4];
#pragma unroll
    for (int w = 0; w < 4; ++w) cks[w] = ck[w * ZC_ + chs];
    float sraw = 0.f;
#pragma unroll
    for (int j = 0; j < 4; ++j) {
      int lp_ = l0 + tid - 3 + j;
      float zs = (lp_ >= 0) ? zp[((size_t)b * L_ + lp_) * ZC_ + chs] : 0.f;
      sraw += zs * cks[j];
    }
    float lp = fminf(fmaxf(ss * sraw, -20.f), 20.f);
    int l = l0 + tid;
    float pw = __expf(lp - slope * (float)(L_ - 1 - l));
    s_pw[tid] = pw;
    float pref = pw;
#pragma unroll
    for (int off = 1; off < 32; off <<= 1) {
      float nv = __shfl_up(pref, off);
      if (tid >= off) pref += nv;
    }
    float den = cpre[base] + pref;
    s_inv[tid] = 1.f / fmaxf(den, 1e-4f);
    float gl = gatelin[((size_t)b * L_ + l) * K_ + k];
    s_sg[tid] = 1.f / (1.f + __expf(-(gl + gb)));
  }

  {
    const int hh = tid >> 2, g = tid & 3;
    const int chkh = k * H_ + hh;
    const float ts = tanh_scale[k];
    float ckv[4];
#pragma unroll
    for (int w = 0; w < 4; ++w) ckv[w] = ck[w * ZC_ + chkh];
    const int lbase = l0 + g * 8;
    float z3 = 0.f, z2 = 0.f, z1 = 0.f;
#pragma unroll
    for (int p = 0; p < 3; ++p) {
      int lp_ = lbase - 3 + p;
      if (lp_ >= 0) {
        float z = zp[((size_t)b * L_ + lp_) * ZC_ + chkh];
        if (p == 0) z3 = z; else if (p == 1) z2 = z; else z1 = z;
      }
    }
#pragma unroll
    for (int j = 0; j < 8; ++j) {
      float z0 = zp[((size_t)b * L_ + lbase + j) * ZC_ + chkh];
      float kv = z3 * ckv[0] + z2 * ckv[1] + z1 * ckv[2] + z0 * ckv[3];
      z3 = z2; z2 = z1; z1 = z0;
      s_kv[g * 8 + j][hh] = kv;
      s_th[g * 8 + j][hh] = fast_tanh(ts * kv);
    }
  }
  __syncthreads();

  const int chk = k * H_ + h;
  const float theta_v = theta_tab[chk * M_ + m];
  const float w = w_tab[chk * M_ + m];
  const float nsv = ns[chk];
  const int kq = k >> 1;   // NREP = 2
  const int qidx = ((kq * H_ + h) * M_ + m) * 2;
  float sre = cpre[base + 1 + h * 4 + m];
  float sim = cpre[base + 1 + 256 + h * 4 + m];
#pragma unroll 4
  for (int ll = 0; ll < LC_; ++ll) {
    float kvp = s_kv[ll][h] * s_pw[ll];
    float ph = s_th[ll][h] * theta_v;
    sre += kvp * __cosf(ph);
    sim += kvp * __sinf(ph);
    float inv = s_inv[ll];
    float s_re = sre * inv, s_im = sim * inv;
    size_t t = (size_t)b * L_ + l0 + ll;
    size_t qb = t * QST_ + qidx;
    float qr = (float)qh[qb], qi = (float)qh[qb + 1];
    float tr = (s_re * qr + s_im * qi) * w;
    float ti = (s_im * qr - s_re * qi) * w;
    tr += __shfl_xor(tr, 1); tr += __shfl_xor(tr, 2);
    ti += __shfl_xor(ti, 1); ti += __shfl_xor(ti, 2);
    if (m == 0) {
      float g = s_sg[ll] * nsv;
      size_t ab = ((size_t)k * NTOK_ + t) * 128;
      asp[ab + h] = (_Float16)(tr * g);
      asp[ab + 64 + h] = (_Float16)(ti * g);
    }
  }
}

// ---------------------------------------------------------------------------
extern "C" void kernel_launch(void* const* d_in, const int* in_sizes, int n_in,
                              void* d_out, int out_size, void* d_ws, size_t ws_size,
                              hipStream_t stream) {
  const float* x            = (const float*)d_in[0];
  const float* W_mem        = (const float*)d_in[1];
  const float* conv_k       = (const float*)d_in[2];
  const float* W_q          = (const float*)d_in[3];
  const float* theta_d_raw  = (const float*)d_in[4];
  const float* decay_slopes = (const float*)d_in[5];
  const float* score_scale  = (const float*)d_in[6];
  const float* tanh_scale   = (const float*)d_in[7];
  const float* W_re         = (const float*)d_in[8];
  const float* W_im         = (const float*)d_in[9];
  const float* norm_scale   = (const float*)d_in[10];
  const float* gate_W       = (const float*)d_in[11];
  const float* gate_b       = (const float*)d_in[12];
  const float* skip_down_W  = (const float*)d_in[13];
  const float* skip_up_W    = (const float*)d_in[14];
  const float* highway_scale= (const float*)d_in[15];
  const float* out_W        = (const float*)d_in[16];
  float* out = (float*)d_out;
  float* ws = (float*)d_ws;

  // ---- f32 region ----
  float* theta_tab = ws;                                  // 3072
  float* w_tab     = theta_tab + 3072;                    // 3072
  float* slopes_sp = w_tab + 3072;                        // 16
  float* z_pre     = slopes_sp + 16;                      // 3,194,880
  float* gatelin   = z_pre + (size_t)NTOK_ * ZC_;         // 49,152
  float* csums     = gatelin + (size_t)NTOK_ * K_;        // 787,968
  float* cpre      = csums + (size_t)B_ * K_ * NC_ * 513; // 787,968
  _Float16* q_h    = (_Float16*)(cpre + (size_t)B_ * K_ * NC_ * 513); // 4096x3072
  _Float16* y_h    = q_h + (size_t)NTOK_ * QST_;          // 4096x2304
  float* f32_end   = (float*)(y_h + (size_t)NTOK_ * 2304);

  // split-K partials (3 x 4096 x 768 f32) OVERLAY dead scan workspace
  float* part = z_pre;

  // ---- fp16 region ----
  _Float16* fp = (_Float16*)f32_end;
  _Float16* x_h    = fp;                fp += (size_t)NTOK_ * D_;
  _Float16* xpb_h  = fp;                fp += (size_t)XPN_ * 768;   // merged proj B (4096 rows)
  _Float16* outw_h = fp;                fp += (size_t)768 * 2304;
  _Float16* asp2_h = fp;                fp += (size_t)K_ * NTOK_ * 128;
  _Float16* bsp_h  = fp;                fp += (size_t)K_ * 384 * 320;
  _Float16* lat_h  = fp;                fp += (size_t)NTOK_ * 192;

  // fused prologue: precomp + all weight conversions (incl gate_W) + x->fp16 (vec)
  prep_kernel<<<9435, 256, 0, stream>>>(x, W_mem, W_q, skip_down_W, out_W, W_re, W_im,
                                        skip_up_W, highway_scale, gate_W,
                                        theta_d_raw, decay_slopes,
                                        x_h, xpb_h, outw_h, bsp_h,
                                        theta_tab, w_tab, slopes_sp);

  // merged x-projection (256x128 tile, BK=32, 2 blocks/CU): q + lat + gate + z_pre
  xprojk_kernel<<<512, 512, 0, stream>>>(x_h, xpb_h, z_pre, lat_h, q_h, gatelin);

  // chunked scan (f32), wave-cooperative dedup
  pass_a_kernel<<<dim3(NC_, K_, B_), 256, 0, stream>>>(z_pre, conv_k, theta_tab, score_scale,
                                                       tanh_scale, slopes_sp, csums);
  pass_b_kernel<<<dim3(9, B_ * K_), 64, 0, stream>>>(csums, cpre);
  pass_c_kernel<<<dim3(NC_, K_, B_), 256, 0, stream>>>(z_pre, conv_k, q_h, theta_tab, w_tab,
                                                       score_scale, tanh_scale, slopes_sp, cpre,
                                                       gatelin, gate_b, norm_scale, asp2_h);

  // batched spec GEMM (2-barrier counted-vmcnt) with fused SiLU -> y_h fp16
  spec_gemm_kernel<<<1152, 256, 0, stream>>>(asp2_h, bsp_h, lat_h, y_h);

  // out = y @ out_W: 256x128/BK=32 xprojk-style, split-K=4, all-co-resident grid
  outprojk_kernel<<<384, 512, 0, stream>>>(y_h, outw_h, out, part);
  // fold partials into out
  redout_kernel<<<3072, 256, 0, stream>>>(out, part);
}